// Round 1
// baseline (1184.365 us; speedup 1.0000x reference)
//
#include <hip/hip_runtime.h>
#include <hip/hip_bf16.h>
#include <math.h>

// Problem constants
constexpr int NN  = 16000;          // nodes
constexpr int NE  = 256000;         // edges (original)
constexpr int NET = NE + NN;        // edges incl. self loops
constexpr int NK  = 4000;           // top-k
constexpr int NH  = 4;              // heads
constexpr int ND  = 128;            // dim
constexpr int NCL = 16;             // clusters

// acc buffer sub-offsets (floats)
constexpr int A_ADJ    = 0;     // 256  raw s^T adj s
constexpr int A_SS     = 256;   // 256  s^T s
constexpr int A_CSUM   = 512;   // 16   sum_n s[n,c]
constexpr int A_V      = 528;   // 16   sum_n s[n,c]*deg[n]
constexpr int A_DEGSUM = 544;   // 1
constexpr int A_OUTX   = 560;   // 2048 s^T xp (later selu'd in place)
constexpr int A_ADJN   = 2608;  // 256  normalized adjacency
constexpr int ACC_FLOATS = 3072;

__device__ inline unsigned fkey(float f){
  unsigned u = __float_as_uint(f);
  return (u & 0x80000000u) ? ~u : (u | 0x80000000u);
}

// ---------------- init ----------------
__global__ void k_init(int* cnt, int* node2k, int* hist, int* state,
                       float* tbuf, float* deg, float* acc){
  int i = blockIdx.x*blockDim.x + threadIdx.x;
  int stride = gridDim.x*blockDim.x;
  for (int j=i; j<NN; j+=stride){ cnt[j]=0; node2k[j]=-1; }
  for (int j=i; j<256; j+=stride) hist[j]=0;
  for (int j=i; j<64; j+=stride) state[j]=0;
  if (i==0) state[0]=NK;
  for (int j=i; j<NK*NCL; j+=stride) tbuf[j]=0.f;
  for (int j=i; j<NK; j+=stride) deg[j]=0.f;
  for (int j=i; j<ACC_FLOATS; j+=stride) acc[j]=0.f;
}

// ---------------- CSR build ----------------
__global__ void k_count(const int* __restrict__ ei, int* __restrict__ cnt){
  int e = blockIdx.x*blockDim.x + threadIdx.x;
  if (e >= NET) return;
  int d = (e < NE) ? ei[NE+e] : (e-NE);
  atomicAdd(&cnt[d], 1);
}

__global__ void k_scan(int* cnt, int* ptr, int* fill){
  __shared__ int buf[1024];
  __shared__ int carry;
  int t = threadIdx.x;
  if (t==0) carry=0;
  __syncthreads();
  for (int base=0; base<NN; base+=1024){
    int i = base+t;
    int v = (i<NN)? cnt[i] : 0;
    buf[t]=v; __syncthreads();
    for (int o=1;o<1024;o<<=1){
      int tv = (t>=o)? buf[t-o] : 0;
      __syncthreads();
      buf[t] += tv;
      __syncthreads();
    }
    if (i<NN){ int ex = carry + buf[t] - v; ptr[i]=ex; fill[i]=ex; }
    __syncthreads();
    if (t==0) carry += buf[1023];
    __syncthreads();
  }
  if (t==0) ptr[NN]=carry;
}

__global__ void k_fill(const int* __restrict__ ei, int* cur, int* csrc){
  int e = blockIdx.x*blockDim.x + threadIdx.x;
  if (e >= NET) return;
  int s, d;
  if (e < NE){ s = ei[e]; d = ei[NE+e]; } else { s = e-NE; d = e-NE; }
  int pos = atomicAdd(&cur[d], 1);
  csrc[pos] = s;
}

// ---------------- embedding ----------------
__global__ void k_embed(const int* __restrict__ x, const float* __restrict__ emb,
                        float4* __restrict__ h){
  int i = blockIdx.x*blockDim.x + threadIdx.x;
  if (i >= NN*32) return;
  int n = i >> 5, q = i & 31;
  h[i] = ((const float4*)emb)[(size_t)x[n]*32 + q];
}

// ---------------- fp32 GEMM: C[M,512] = A[M,128] @ B[512,128]^T ----------------
// 64x64 tile, 256 threads, 4x4 micro-tile with cyclic (stride-16) assignment
// => conflict-free b128 LDS reads. K staged in two 64-chunks (LDS 2*17KB).
__global__ __launch_bounds__(256) void k_gemm(const float* __restrict__ A,
                                              const float* __restrict__ B,
                                              float* __restrict__ C){
  __shared__ float As[64*68];
  __shared__ float Bs[64*68];
  int tid = threadIdx.x;
  int m0 = blockIdx.x*64, n0 = blockIdx.y*64;
  int ty = tid>>4, tx = tid&15;
  float cacc[4][4] = {};
  for (int kk=0; kk<128; kk+=64){
    #pragma unroll
    for (int i=0;i<4;i++){
      int idx = tid + i*256;       // 0..1023
      int r = idx>>4, q = idx&15;  // row, float4-col
      float4 av = *(const float4*)&A[(size_t)(m0+r)*128 + kk + q*4];
      float* da = &As[r*68 + q*4];
      da[0]=av.x; da[1]=av.y; da[2]=av.z; da[3]=av.w;
      float4 bv = *(const float4*)&B[(size_t)(n0+r)*128 + kk + q*4];
      float* db = &Bs[r*68 + q*4];
      db[0]=bv.x; db[1]=bv.y; db[2]=bv.z; db[3]=bv.w;
    }
    __syncthreads();
    #pragma unroll 4
    for (int k=0;k<64;k+=4){
      float4 b0 = *(const float4*)&Bs[(tx    )*68 + k];
      float4 b1 = *(const float4*)&Bs[(tx+16 )*68 + k];
      float4 b2 = *(const float4*)&Bs[(tx+32 )*68 + k];
      float4 b3 = *(const float4*)&Bs[(tx+48 )*68 + k];
      #pragma unroll
      for (int i=0;i<4;i++){
        float4 a = *(const float4*)&As[(ty+16*i)*68 + k];
        cacc[i][0] += a.x*b0.x + a.y*b0.y + a.z*b0.z + a.w*b0.w;
        cacc[i][1] += a.x*b1.x + a.y*b1.y + a.z*b1.z + a.w*b1.w;
        cacc[i][2] += a.x*b2.x + a.y*b2.y + a.z*b2.z + a.w*b2.w;
        cacc[i][3] += a.x*b3.x + a.y*b3.y + a.z*b3.z + a.w*b3.w;
      }
    }
    __syncthreads();
  }
  #pragma unroll
  for (int i=0;i<4;i++)
    #pragma unroll
    for (int j=0;j<4;j++)
      C[(size_t)(m0+ty+16*i)*512 + n0+tx+16*j] = cacc[i][j];
}

// ---------------- attention per-node sums ----------------
__global__ void k_attnsum(const float* __restrict__ hf, const float* __restrict__ as_,
                          const float* __restrict__ ad_, float* __restrict__ sum_s,
                          float* __restrict__ sum_d){
  int n = blockIdx.x, lane = threadIdx.x;   // 64 threads
  const float* row = hf + (size_t)n*512;
  for (int h=0;h<4;h++){
    float x0 = row[h*128+lane], x1 = row[h*128+64+lane];
    float ps = x0*as_[h*128+lane] + x1*as_[h*128+64+lane];
    float pd = x0*ad_[h*128+lane] + x1*ad_[h*128+64+lane];
    #pragma unroll
    for (int off=32; off>0; off>>=1){ ps += __shfl_down(ps,off); pd += __shfl_down(pd,off); }
    if (lane==0){ sum_s[n*4+h]=ps; sum_d[n*4+h]=pd; }
  }
}

// ---------------- edge softmax (per dst,head) ----------------
__global__ void k_edges(const int* __restrict__ ptr, const int* __restrict__ csrc,
                        const float* __restrict__ sum_s, const float* __restrict__ sum_d,
                        float* __restrict__ alpha){
  int idx = blockIdx.x*blockDim.x + threadIdx.x;
  if (idx >= NN*NH) return;
  int n = idx >> 2, h = idx & 3;
  int b0 = ptr[n], b1 = ptr[n+1];
  float sd = sum_d[n*4+h];
  float mx = -1e30f;
  for (int j=b0;j<b1;j++){
    float v = sum_s[csrc[j]*4+h] + sd;
    v = v > 0.f ? v : 0.2f*v;
    alpha[(size_t)j*4+h] = v;
    mx = fmaxf(mx, v);
  }
  float den = 0.f;
  for (int j=b0;j<b1;j++){
    float e = __expf(alpha[(size_t)j*4+h] - mx);
    alpha[(size_t)j*4+h] = e;
    den += e;
  }
  float inv = 1.f/(den + 1e-16f);
  for (int j=b0;j<b1;j++) alpha[(size_t)j*4+h] *= inv;
}

// ---------------- weighted aggregation + head-mean + bias + relu ----------------
__global__ void k_agg(const int* __restrict__ ptr, const int* __restrict__ csrc,
                      const float* __restrict__ alpha, const float* __restrict__ hf,
                      const float* __restrict__ bias, float* __restrict__ hout){
  int n = blockIdx.x; int t = threadIdx.x;  // 128 threads
  int b0 = ptr[n], b1 = ptr[n+1];
  float acc = 0.f;
  for (int j=b0;j<b1;j++){
    int s = csrc[j];
    float4 al = *(const float4*)&alpha[(size_t)j*4];
    const float* hr = hf + (size_t)s*512;
    acc += al.x*hr[t] + al.y*hr[128+t] + al.z*hr[256+t] + al.w*hr[384+t];
  }
  hout[(size_t)n*128+t] = fmaxf(0.25f*acc + bias[t], 0.f);
}

// ---------------- SAG score ----------------
__global__ void k_sag(const int* __restrict__ ptr, const int* __restrict__ csrc,
                      const float* __restrict__ h, const float* __restrict__ wrel,
                      const float* __restrict__ brel, const float* __restrict__ wroot,
                      float* __restrict__ score){
  int n = blockIdx.x; int t = threadIdx.x; // 128
  int b0 = ptr[n], b1 = ptr[n+1];
  float agg = 0.f;
  for (int j=b0;j<b1;j++){
    int s = csrc[j];
    if (s != n) agg += h[(size_t)s*128 + t];   // skip the added self loop
  }
  float part = agg*wrel[t] + h[(size_t)n*128+t]*wroot[t];
  #pragma unroll
  for (int o=32;o>0;o>>=1) part += __shfl_down(part, o);
  __shared__ float r2[2];
  if ((t&63)==0) r2[t>>6]=part;
  __syncthreads();
  if (t==0) score[n] = r2[0]+r2[1]+brel[0];
}

// ---------------- radix select (K-th largest) ----------------
__global__ void k_hist(const float* __restrict__ score, const int* __restrict__ state,
                       int* __restrict__ hist, int shift){
  int i = blockIdx.x*blockDim.x + threadIdx.x;
  if (i >= NN) return;
  unsigned u = fkey(score[i]);
  unsigned prefix = (unsigned)state[1];
  bool ok = (shift==24) || ((u >> (shift+8)) == (prefix >> (shift+8)));
  if (ok) atomicAdd(&hist[(u>>shift)&255], 1);
}

__global__ void k_rscan(int* hist, int* state, int shift){
  int t = threadIdx.x;
  if (t==0){
    int rem = state[0];
    unsigned prefix = (unsigned)state[1];
    for (int b=255;b>=0;b--){
      int c = hist[b];
      if (rem > c) rem -= c;
      else { prefix |= ((unsigned)b) << shift; break; }
    }
    state[0]=rem; state[1]=(int)prefix;
  }
  __syncthreads();
  if (t<256) hist[t]=0;
}

__global__ void k_select(const float* __restrict__ score, int* state,
                         int* sel, int* ties){
  int i = blockIdx.x*blockDim.x + threadIdx.x;
  if (i >= NN) return;
  unsigned Tu = (unsigned)state[1];
  unsigned u = fkey(score[i]);
  if (u > Tu){ int p = atomicAdd(&state[2],1); sel[p]=i; }
  else if (u == Tu){ int p = atomicAdd(&state[3],1); ties[p]=i; }
}

__global__ void k_tiefill(int* state, int* sel, int* ties){
  if (threadIdx.x==0 && blockIdx.x==0){
    int cgt = state[2]; int rem = state[0]; int nt = state[3];
    for (int r=0;r<rem;r++){
      int best = 0x7fffffff, bi = -1;
      for (int t2=0;t2<nt;t2++){
        int v = ties[t2];
        if (v >= 0 && v < best){ best=v; bi=t2; }
      }
      sel[cgt+r] = (bi>=0)? best : 0;
      if (bi>=0) ties[bi] = -1;
    }
  }
}

// ---------------- xp gather + node2k ----------------
__global__ void k_gatherx(const int* __restrict__ sel, const float* __restrict__ score,
                          const float* __restrict__ h, float* __restrict__ xp,
                          int* __restrict__ node2k){
  int k = blockIdx.x; int t = threadIdx.x; // 128
  int n = sel[k];
  if (t==0) node2k[n] = k;
  float g = tanhf(score[n]);
  xp[(size_t)k*128+t] = h[(size_t)n*128+t]*g;
}

// ---------------- DMoN assignment softmax ----------------
__global__ void k_assign(const float* __restrict__ xp, const float* __restrict__ dw,
                         const float* __restrict__ db, float* __restrict__ sA){
  int k = blockIdx.x; int lane = threadIdx.x; // 64
  __shared__ float logits[16];
  float x0 = xp[(size_t)k*128+lane], x1 = xp[(size_t)k*128+64+lane];
  for (int c=0;c<16;c++){
    float p = x0*dw[c*128+lane] + x1*dw[c*128+64+lane];
    #pragma unroll
    for (int off=32;off>0;off>>=1) p += __shfl_down(p,off);
    if (lane==0) logits[c] = p + db[c];
  }
  __syncthreads();
  if (lane<16){
    float mx=-1e30f;
    for (int c=0;c<16;c++) mx = fmaxf(mx, logits[c]);
    float s=0.f;
    for (int c=0;c<16;c++) s += __expf(logits[c]-mx);
    sA[(size_t)k*16+lane] = __expf(logits[lane]-mx)/s;
  }
}

// ---------------- pooled adjacency: t[ni,:] += s[nj,:], deg[nj]+=1 ----------------
__global__ void k_edgepool(const int* __restrict__ ei, const int* __restrict__ node2k,
                           const float* __restrict__ sA, float* __restrict__ tbuf,
                           float* __restrict__ deg){
  int e = blockIdx.x*blockDim.x + threadIdx.x;
  if (e >= NE) return;
  int ni = node2k[ei[e]];
  int nj = node2k[ei[NE+e]];
  if (ni >= 0 && nj >= 0){
    atomicAdd(&deg[nj], 1.f);
    const float* sr = &sA[(size_t)nj*16];
    float* tr = &tbuf[(size_t)ni*16];
    #pragma unroll
    for (int c=0;c<16;c++) atomicAdd(&tr[c], sr[c]);
  }
}

// ---------------- out_x = s^T xp (raw, selu later) ----------------
__global__ void k_outx(const float* __restrict__ sA, const float* __restrict__ xp,
                       float* __restrict__ acc){
  __shared__ float loc[2048];
  __shared__ float sv[16];
  __shared__ float xv[128];
  int t = threadIdx.x;
  for (int j=t;j<2048;j+=256) loc[j]=0.f;
  int i0 = blockIdx.x*(NK/16), i1 = i0 + NK/16;
  __syncthreads();
  for (int i=i0;i<i1;i++){
    if (t<16) sv[t]=sA[(size_t)i*16+t];
    else if (t>=128) xv[t-128]=xp[(size_t)i*128+(t-128)];
    __syncthreads();
    #pragma unroll
    for (int j=0;j<8;j++){ int o=t+j*256; loc[o] += sv[o>>7]*xv[o&127]; }
    __syncthreads();
  }
  for (int j=t;j<2048;j+=256) atomicAdd(&acc[A_OUTX+j], loc[j]);
}

// ---------------- DMoN reductions ----------------
__global__ void k_dmred(const float* __restrict__ sA, const float* __restrict__ tb,
                        const float* __restrict__ deg, float* __restrict__ acc){
  __shared__ float sv[16], tv[16];
  __shared__ float dsh;
  int t = threadIdx.x; int c=t>>4, d=t&15;
  float a_adj=0.f, a_ss=0.f, a_cs=0.f, a_v=0.f, a_dg=0.f;
  int i0 = blockIdx.x*(NK/16), i1 = i0 + NK/16;
  for (int i=i0;i<i1;i++){
    if (t<16) sv[t]=sA[(size_t)i*16+t];
    else if (t<32) tv[t-16]=tb[(size_t)i*16+(t-16)];
    else if (t==32) dsh = deg[i];
    __syncthreads();
    float sc = sv[c];
    a_adj += sc*tv[d];
    a_ss  += sc*sv[d];
    if (d==0){ a_cs += sc; a_v += sc*dsh; }
    if (t==0) a_dg += dsh;
    __syncthreads();
  }
  atomicAdd(&acc[A_ADJ + t], a_adj);
  atomicAdd(&acc[A_SS + t], a_ss);
  if (d==0){ atomicAdd(&acc[A_CSUM+c], a_cs); atomicAdd(&acc[A_V+c], a_v); }
  if (t==0) atomicAdd(&acc[A_DEGSUM], a_dg);
}

__device__ float block_sum_256(float v, float* red){
  int t = threadIdx.x;
  red[t]=v; __syncthreads();
  #pragma unroll
  for (int o=128;o>0;o>>=1){ if (t<o) red[t]+=red[t+o]; __syncthreads(); }
  float r = red[0]; __syncthreads();
  return r;
}

// ---------------- losses + normalized adjacency ----------------
__global__ __launch_bounds__(256) void k_finloss(float* __restrict__ acc, float* __restrict__ dout){
  __shared__ float red[256];
  __shared__ float dsv[16];
  int t = threadIdx.x;
  int c = t>>4, dcol = t&15;
  float m = 0.5f*acc[A_DEGSUM];
  float ssv = acc[A_SS+t];
  float tr    = block_sum_256((t<16)? acc[A_ADJ + t*16 + t] : 0.f, red);
  float sumv2 = block_sum_256((t<16)? acc[A_V+t]*acc[A_V+t] : 0.f, red);
  float ss2   = block_sum_256(ssv*ssv, red);
  float cs2   = block_sum_256((t<16)? acc[A_CSUM+t]*acc[A_CSUM+t] : 0.f, red);
  float ssn = sqrtf(ss2);
  float term = ssv/ssn - ((c==dcol)? 0.25f : 0.f);
  float ortho2 = block_sum_256(term*term, red);
  if (t==0){
    float spectral = -(tr - sumv2/(2.f*m))/(2.f*m);
    float ortho = sqrtf(ortho2);
    float cluster = sqrtf(cs2)/(float)NK*4.f - 1.f;
    dout[1] = spectral + ortho + cluster;
  }
  // normalized adjacency
  float z = (c==dcol)? 0.f : acc[A_ADJ+t];
  red[t]=z; __syncthreads();
  for (int o=8;o>0;o>>=1){ if (dcol<o) red[t]+=red[t+o]; __syncthreads(); }
  if (dcol==0) dsv[c]=sqrtf(red[c*16])+1e-15f;
  __syncthreads();
  acc[A_ADJN+t] = z/(dsv[c]*dsv[dcol]);
}

// ---------------- selu on out_x ----------------
__global__ void k_selu(float* __restrict__ acc){
  int i = blockIdx.x*blockDim.x + threadIdx.x;
  if (i >= 2048) return;
  float x = acc[A_OUTX+i];
  float s = (x > 0.f)? x : 1.6732632423543772f*expm1f(x);
  acc[A_OUTX+i] = 1.0507009873554805f*s;
}

// ---------------- hh = selu(out_x) @ Wt^T ----------------
__global__ void k_hh(const float* __restrict__ acc, const float* __restrict__ Wt,
                     float* __restrict__ hh){
  int of = blockIdx.x*256 + threadIdx.x; // 0..8191
  int c = of >> 9, o = of & 511;
  const float* sx = acc + A_OUTX + c*128;
  const float* w = Wt + (size_t)o*128;
  float s=0.f;
  for (int k=0;k<128;k++) s += sx[k]*w[k];
  hh[of] = s;
}

// ---------------- dense GAT head + readout ----------------
__global__ __launch_bounds__(256) void k_head(
    const float* __restrict__ hh_g, const float* __restrict__ acc,
    const float* __restrict__ att_s, const float* __restrict__ att_d,
    const float* __restrict__ bt, const float* __restrict__ gate_w,
    const float* __restrict__ gate_b, const float* __restrict__ trans_w,
    const float* __restrict__ trans_b, const int* __restrict__ task,
    const float* __restrict__ task_emb, const float* __restrict__ task_w,
    const float* __restrict__ task_b, const float* __restrict__ fuse_w,
    const float* __restrict__ fuse_b, const float* __restrict__ out_w,
    const float* __restrict__ out_b, float* __restrict__ dout){
  __shared__ float hh[8192];
  __shared__ float al[1024];     // [i][j][h] = [(i*16+j)*4+h]
  __shared__ float asrc[64], adst[64];
  __shared__ float dg[2048];
  __shared__ float gate[16];
  __shared__ float gvec[128];
  __shared__ float ro[128], te[128], fu[128];
  __shared__ float red[256];
  int t = threadIdx.x;
  for (int i=t;i<8192;i+=256) hh[i]=hh_g[i];
  __syncthreads();
  if (t<128){
    int j = t>>3; int h = (t>>1)&3; int w = t&1;
    const float* hr = &hh[j*512 + h*128];
    const float* a = (w? att_d : att_s) + h*128;
    float s=0.f;
    for (int k2=0;k2<128;k2++) s += hr[k2]*a[k2];
    if (w) adst[j*4+h]=s; else asrc[j*4+h]=s;
  }
  __syncthreads();
  for (int idx=t; idx<1024; idx+=256){
    int h = idx&3, j=(idx>>2)&15, i=idx>>6;
    float v = asrc[j*4+h] + adst[i*4+h];
    v = v>0.f? v : 0.2f*v;
    float adjl = (i==j)? 1.f : acc[A_ADJN + i*16+j];
    al[idx] = (adjl==0.f)? -1e30f : v;
  }
  __syncthreads();
  if (t<64){
    int i=t>>2, h=t&3;
    float mx=-1e30f;
    for (int j=0;j<16;j++) mx = fmaxf(mx, al[(i*16+j)*4+h]);
    float sum=0.f;
    for (int j=0;j<16;j++){ float e=__expf(al[(i*16+j)*4+h]-mx); al[(i*16+j)*4+h]=e; sum+=e; }
    float inv = 1.f/sum;
    for (int j=0;j<16;j++) al[(i*16+j)*4+h]*=inv;
  }
  __syncthreads();
  for (int idx=t; idx<2048; idx+=256){
    int i=idx>>7, d=idx&127;
    float s=0.f;
    for (int h=0;h<4;h++)
      for (int j=0;j<16;j++)
        s += al[(i*16+j)*4+h]*hh[j*512+h*128+d];
    dg[idx] = fmaxf(0.25f*s + bt[d], 0.f);
  }
  __syncthreads();
  if (t<16){
    float s=0.f;
    for (int d2=0;d2<128;d2++) s += dg[t*128+d2]*gate_w[d2];
    red[t] = s + gate_b[0];
  }
  __syncthreads();
  if (t<16){
    float mx=-1e30f; for (int i=0;i<16;i++) mx=fmaxf(mx,red[i]);
    float s=0.f; for (int i=0;i<16;i++) s+=__expf(red[i]-mx);
    gate[t]=__expf(red[t]-mx)/s;
  }
  __syncthreads();
  if (t<128){
    float s=0.f;
    for (int i=0;i<16;i++) s += gate[i]*dg[i*128+t];
    gvec[t]=s;
  }
  __syncthreads();
  if (t<128){
    float s=0.f;
    for (int k2=0;k2<128;k2++) s += gvec[k2]*trans_w[t*128+k2];
    ro[t]=s+trans_b[t];
    int tk = task[0];
    float s2=0.f;
    for (int k2=0;k2<128;k2++) s2 += task_emb[(size_t)tk*128+k2]*task_w[t*128+k2];
    te[t]=fmaxf(s2+task_b[t],0.f);
  }
  __syncthreads();
  if (t<128){
    float s=0.f;
    for (int k2=0;k2<128;k2++) s += ro[k2]*fuse_w[t*256+k2] + te[k2]*fuse_w[t*256+128+k2];
    fu[t]=fmaxf(s+fuse_b[t],0.f);
  }
  __syncthreads();
  float v = (t<128)? fu[t]*out_w[t] : 0.f;
  red[t]=v; __syncthreads();
  for (int o=128;o>0;o>>=1){ if (t<o) red[t]+=red[t+o]; __syncthreads(); }
  if (t==0) dout[0]=red[0]+out_b[0];
}

// ================= launcher =================
extern "C" void kernel_launch(void* const* d_in, const int* in_sizes, int n_in,
                              void* d_out, int out_size, void* d_ws, size_t ws_size,
                              hipStream_t stream){
  const int* x        = (const int*)d_in[0];
  const int* ei       = (const int*)d_in[1];
  const int* task     = (const int*)d_in[3];
  const float* node_emb = (const float*)d_in[4];
  const float* task_emb = (const float*)d_in[5];
  const float* W[3]  = {(const float*)d_in[6],  (const float*)d_in[10], (const float*)d_in[14]};
  const float* As_[3]= {(const float*)d_in[7],  (const float*)d_in[11], (const float*)d_in[15]};
  const float* Ad_[3]= {(const float*)d_in[8],  (const float*)d_in[12], (const float*)d_in[16]};
  const float* Bb[3] = {(const float*)d_in[9],  (const float*)d_in[13], (const float*)d_in[17]};
  const float* wrel  = (const float*)d_in[18];
  const float* brel  = (const float*)d_in[19];
  const float* wroot = (const float*)d_in[20];
  const float* dmon_w= (const float*)d_in[21];
  const float* dmon_b= (const float*)d_in[22];
  const float* Wt    = (const float*)d_in[23];
  const float* att_s = (const float*)d_in[24];
  const float* att_d = (const float*)d_in[25];
  const float* btb   = (const float*)d_in[26];
  const float* gate_w= (const float*)d_in[27];
  const float* gate_b= (const float*)d_in[28];
  const float* trans_w=(const float*)d_in[29];
  const float* trans_b=(const float*)d_in[30];
  const float* task_w= (const float*)d_in[31];
  const float* task_b= (const float*)d_in[32];
  const float* fuse_w= (const float*)d_in[33];
  const float* fuse_b= (const float*)d_in[34];
  const float* out_w = (const float*)d_in[35];
  const float* out_b = (const float*)d_in[36];
  float* dout = (float*)d_out;
  (void)in_sizes; (void)n_in; (void)out_size; (void)ws_size;

  char* base = (char*)d_ws;
  size_t off = 0;
  auto alloc = [&](size_t bytes)->char*{
    off = (off + 255) & ~(size_t)255;
    char* r = base + off; off += bytes; return r;
  };
  int* csr_ptr  = (int*)alloc((size_t)(NN+1)*4);
  int* csr_fill = (int*)alloc((size_t)NN*4);
  int* csr_src  = (int*)alloc((size_t)NET*4);
  int* sel      = (int*)alloc((size_t)NK*4);
  int* node2k   = (int*)alloc((size_t)NN*4);
  int* ties     = (int*)alloc((size_t)NN*4);
  int* hist     = (int*)alloc(256*4);
  int* state    = (int*)alloc(64*4);
  float* score  = (float*)alloc((size_t)NN*4);
  float* h_a    = (float*)alloc((size_t)NN*128*4);
  float* h_b    = (float*)alloc((size_t)NN*128*4);
  float* hfeat  = (float*)alloc((size_t)NN*512*4);
  float* sum_s  = (float*)alloc((size_t)NN*4*4);
  float* sum_d  = (float*)alloc((size_t)NN*4*4);
  float* alpha  = (float*)alloc((size_t)NET*4*4);
  float* xp     = (float*)alloc((size_t)NK*128*4);
  float* sA     = (float*)alloc((size_t)NK*16*4);
  float* tbuf   = (float*)alloc((size_t)NK*16*4);
  float* deg    = (float*)alloc((size_t)NK*4);
  float* acc    = (float*)alloc((size_t)ACC_FLOATS*4);
  float* hh_g   = (float*)alloc((size_t)8192*4);

  k_init<<<256, 256, 0, stream>>>(csr_fill, node2k, hist, state, tbuf, deg, acc);
  k_count<<<(NET+255)/256, 256, 0, stream>>>(ei, csr_fill);
  k_scan<<<1, 1024, 0, stream>>>(csr_fill, csr_ptr, csr_fill);
  k_fill<<<(NET+255)/256, 256, 0, stream>>>(ei, csr_fill, csr_src);
  k_embed<<<(NN*32+255)/256, 256, 0, stream>>>(x, node_emb, (float4*)h_a);

  float* hin = h_a; float* hout = h_b;
  for (int l=0;l<3;l++){
    k_gemm<<<dim3(NN/64, 512/64), 256, 0, stream>>>(hin, W[l], hfeat);
    k_attnsum<<<NN, 64, 0, stream>>>(hfeat, As_[l], Ad_[l], sum_s, sum_d);
    k_edges<<<(NN*NH+255)/256, 256, 0, stream>>>(csr_ptr, csr_src, sum_s, sum_d, alpha);
    k_agg<<<NN, 128, 0, stream>>>(csr_ptr, csr_src, alpha, hfeat, Bb[l], hout);
    float* tmp=hin; hin=hout; hout=tmp;
  }
  // hin = final node features
  k_sag<<<NN, 128, 0, stream>>>(csr_ptr, csr_src, hin, wrel, brel, wroot, score);
  for (int p=0;p<4;p++){
    int shift = 24-8*p;
    k_hist<<<(NN+255)/256, 256, 0, stream>>>(score, state, hist, shift);
    k_rscan<<<1, 256, 0, stream>>>(hist, state, shift);
  }
  k_select<<<(NN+255)/256, 256, 0, stream>>>(score, state, sel, ties);
  k_tiefill<<<1, 1, 0, stream>>>(state, sel, ties);
  k_gatherx<<<NK, 128, 0, stream>>>(sel, score, hin, xp, node2k);
  k_assign<<<NK, 64, 0, stream>>>(xp, dmon_w, dmon_b, sA);
  k_edgepool<<<(NE+255)/256, 256, 0, stream>>>(ei, node2k, sA, tbuf, deg);
  k_outx<<<16, 256, 0, stream>>>(sA, xp, acc);
  k_dmred<<<16, 256, 0, stream>>>(sA, tbuf, deg, acc);
  k_finloss<<<1, 256, 0, stream>>>(acc, dout);
  k_selu<<<8, 256, 0, stream>>>(acc);
  k_hh<<<32, 256, 0, stream>>>(acc, Wt, hh_g);
  k_head<<<1, 256, 0, stream>>>(hh_g, acc, att_s, att_d, btb, gate_w, gate_b,
                                trans_w, trans_b, task, task_emb, task_w, task_b,
                                fuse_w, fuse_b, out_w, out_b, dout);
}

// Round 2
// 985.878 us; speedup vs baseline: 1.2013x; 1.2013x over previous
//
#include <hip/hip_runtime.h>
#include <hip/hip_bf16.h>
#include <math.h>

// Problem constants
constexpr int NN  = 16000;          // nodes
constexpr int NE  = 256000;         // edges (original)
constexpr int NET = NE + NN;        // edges incl. self loops
constexpr int NK  = 4000;           // top-k
constexpr int NH  = 4;              // heads
constexpr int ND  = 128;            // dim
constexpr int NCL = 16;             // clusters

// acc buffer sub-offsets (floats)
constexpr int A_ADJ    = 0;     // 256  raw s^T adj s
constexpr int A_SS     = 256;   // 256  s^T s
constexpr int A_CSUM   = 512;   // 16   sum_n s[n,c]
constexpr int A_V      = 528;   // 16   sum_n s[n,c]*deg[n]
constexpr int A_DEGSUM = 544;   // 1
constexpr int A_OUTX   = 560;   // 2048 s^T xp (later selu'd in place)
constexpr int A_ADJN   = 2608;  // 256  normalized adjacency
constexpr int ACC_FLOATS = 3072;

__device__ inline unsigned fkey(float f){
  unsigned u = __float_as_uint(f);
  return (u & 0x80000000u) ? ~u : (u | 0x80000000u);
}

// ---------------- init ----------------
__global__ void k_init(int* cnt, int* node2k, float* tbuf, float* deg, float* acc){
  int i = blockIdx.x*blockDim.x + threadIdx.x;
  int stride = gridDim.x*blockDim.x;
  for (int j=i; j<NN; j+=stride){ cnt[j]=0; node2k[j]=-1; }
  for (int j=i; j<NK*NCL; j+=stride) tbuf[j]=0.f;
  for (int j=i; j<NK; j+=stride) deg[j]=0.f;
  for (int j=i; j<ACC_FLOATS; j+=stride) acc[j]=0.f;
}

// ---------------- CSR build ----------------
__global__ void k_count(const int* __restrict__ ei, int* __restrict__ cnt){
  int e = blockIdx.x*blockDim.x + threadIdx.x;
  if (e >= NET) return;
  int d = (e < NE) ? ei[NE+e] : (e-NE);
  atomicAdd(&cnt[d], 1);
}

__global__ void k_scan(int* cnt, int* ptr, int* fill){
  __shared__ int buf[1024];
  __shared__ int carry;
  int t = threadIdx.x;
  if (t==0) carry=0;
  __syncthreads();
  for (int base=0; base<NN; base+=1024){
    int i = base+t;
    int v = (i<NN)? cnt[i] : 0;
    buf[t]=v; __syncthreads();
    for (int o=1;o<1024;o<<=1){
      int tv = (t>=o)? buf[t-o] : 0;
      __syncthreads();
      buf[t] += tv;
      __syncthreads();
    }
    if (i<NN){ int ex = carry + buf[t] - v; ptr[i]=ex; fill[i]=ex; }
    __syncthreads();
    if (t==0) carry += buf[1023];
    __syncthreads();
  }
  if (t==0) ptr[NN]=carry;
}

__global__ void k_fill(const int* __restrict__ ei, int* cur, int* csrc){
  int e = blockIdx.x*blockDim.x + threadIdx.x;
  if (e >= NET) return;
  int s, d;
  if (e < NE){ s = ei[e]; d = ei[NE+e]; } else { s = e-NE; d = e-NE; }
  int pos = atomicAdd(&cur[d], 1);
  csrc[pos] = s;
}

// ---------------- embedding ----------------
__global__ void k_embed(const int* __restrict__ x, const float* __restrict__ emb,
                        float4* __restrict__ h){
  int i = blockIdx.x*blockDim.x + threadIdx.x;
  if (i >= NN*32) return;
  int n = i >> 5, q = i & 31;
  h[i] = ((const float4*)emb)[(size_t)x[n]*32 + q];
}

// ---------------- fp32 GEMM: C[M,512] = A[M,128] @ B[512,128]^T ----------------
__global__ __launch_bounds__(256) void k_gemm(const float* __restrict__ A,
                                              const float* __restrict__ B,
                                              float* __restrict__ C){
  __shared__ float As[64*68];
  __shared__ float Bs[64*68];
  int tid = threadIdx.x;
  int m0 = blockIdx.x*64, n0 = blockIdx.y*64;
  int ty = tid>>4, tx = tid&15;
  float cacc[4][4] = {};
  for (int kk=0; kk<128; kk+=64){
    #pragma unroll
    for (int i=0;i<4;i++){
      int idx = tid + i*256;       // 0..1023
      int r = idx>>4, q = idx&15;  // row, float4-col
      float4 av = *(const float4*)&A[(size_t)(m0+r)*128 + kk + q*4];
      float* da = &As[r*68 + q*4];
      da[0]=av.x; da[1]=av.y; da[2]=av.z; da[3]=av.w;
      float4 bv = *(const float4*)&B[(size_t)(n0+r)*128 + kk + q*4];
      float* db = &Bs[r*68 + q*4];
      db[0]=bv.x; db[1]=bv.y; db[2]=bv.z; db[3]=bv.w;
    }
    __syncthreads();
    #pragma unroll 4
    for (int k=0;k<64;k+=4){
      float4 b0 = *(const float4*)&Bs[(tx    )*68 + k];
      float4 b1 = *(const float4*)&Bs[(tx+16 )*68 + k];
      float4 b2 = *(const float4*)&Bs[(tx+32 )*68 + k];
      float4 b3 = *(const float4*)&Bs[(tx+48 )*68 + k];
      #pragma unroll
      for (int i=0;i<4;i++){
        float4 a = *(const float4*)&As[(ty+16*i)*68 + k];
        cacc[i][0] += a.x*b0.x + a.y*b0.y + a.z*b0.z + a.w*b0.w;
        cacc[i][1] += a.x*b1.x + a.y*b1.y + a.z*b1.z + a.w*b1.w;
        cacc[i][2] += a.x*b2.x + a.y*b2.y + a.z*b2.z + a.w*b2.w;
        cacc[i][3] += a.x*b3.x + a.y*b3.y + a.z*b3.z + a.w*b3.w;
      }
    }
    __syncthreads();
  }
  #pragma unroll
  for (int i=0;i<4;i++)
    #pragma unroll
    for (int j=0;j<4;j++)
      C[(size_t)(m0+ty+16*i)*512 + n0+tx+16*j] = cacc[i][j];
}

// ---------------- attention per-node sums ----------------
__global__ void k_attnsum(const float* __restrict__ hf, const float* __restrict__ as_,
                          const float* __restrict__ ad_, float* __restrict__ sum_s,
                          float* __restrict__ sum_d){
  int n = blockIdx.x, lane = threadIdx.x;   // 64 threads
  const float* row = hf + (size_t)n*512;
  for (int h=0;h<4;h++){
    float x0 = row[h*128+lane], x1 = row[h*128+64+lane];
    float ps = x0*as_[h*128+lane] + x1*as_[h*128+64+lane];
    float pd = x0*ad_[h*128+lane] + x1*ad_[h*128+64+lane];
    #pragma unroll
    for (int off=32; off>0; off>>=1){ ps += __shfl_down(ps,off); pd += __shfl_down(pd,off); }
    if (lane==0){ sum_s[n*4+h]=ps; sum_d[n*4+h]=pd; }
  }
}

// ---------------- edge softmax (per dst,head) ----------------
__global__ void k_edges(const int* __restrict__ ptr, const int* __restrict__ csrc,
                        const float* __restrict__ sum_s, const float* __restrict__ sum_d,
                        float* __restrict__ alpha){
  int idx = blockIdx.x*blockDim.x + threadIdx.x;
  if (idx >= NN*NH) return;
  int n = idx >> 2, h = idx & 3;
  int b0 = ptr[n], b1 = ptr[n+1];
  float sd = sum_d[n*4+h];
  float mx = -1e30f;
  for (int j=b0;j<b1;j++){
    float v = sum_s[csrc[j]*4+h] + sd;
    v = v > 0.f ? v : 0.2f*v;
    alpha[(size_t)j*4+h] = v;
    mx = fmaxf(mx, v);
  }
  float den = 0.f;
  for (int j=b0;j<b1;j++){
    float e = __expf(alpha[(size_t)j*4+h] - mx);
    alpha[(size_t)j*4+h] = e;
    den += e;
  }
  float inv = 1.f/(den + 1e-16f);
  for (int j=b0;j<b1;j++) alpha[(size_t)j*4+h] *= inv;
}

// ---------------- weighted aggregation + head-mean + bias + relu ----------------
__global__ void k_agg(const int* __restrict__ ptr, const int* __restrict__ csrc,
                      const float* __restrict__ alpha, const float* __restrict__ hf,
                      const float* __restrict__ bias, float* __restrict__ hout){
  int n = blockIdx.x; int t = threadIdx.x;  // 128 threads
  int b0 = ptr[n], b1 = ptr[n+1];
  float acc = 0.f;
  for (int j=b0;j<b1;j++){
    int s = csrc[j];
    float4 al = *(const float4*)&alpha[(size_t)j*4];
    const float* hr = hf + (size_t)s*512;
    acc += al.x*hr[t] + al.y*hr[128+t] + al.z*hr[256+t] + al.w*hr[384+t];
  }
  hout[(size_t)n*128+t] = fmaxf(0.25f*acc + bias[t], 0.f);
}

// ---------------- SAG score ----------------
__global__ void k_sag(const int* __restrict__ ptr, const int* __restrict__ csrc,
                      const float* __restrict__ h, const float* __restrict__ wrel,
                      const float* __restrict__ brel, const float* __restrict__ wroot,
                      float* __restrict__ score){
  int n = blockIdx.x; int t = threadIdx.x; // 128
  int b0 = ptr[n], b1 = ptr[n+1];
  float agg = 0.f;
  for (int j=b0;j<b1;j++){
    int s = csrc[j];
    if (s != n) agg += h[(size_t)s*128 + t];   // skip the added self loop
  }
  float part = agg*wrel[t] + h[(size_t)n*128+t]*wroot[t];
  #pragma unroll
  for (int o=32;o>0;o>>=1) part += __shfl_down(part, o);
  __shared__ float r2[2];
  if ((t&63)==0) r2[t>>6]=part;
  __syncthreads();
  if (t==0) score[n] = r2[0]+r2[1]+brel[0];
}

// ---------------- fused single-block radix top-k ----------------
// One workgroup: 4x 8-bit radix passes + selection + tie-fill, histogram and
// counters in LDS (no device-scope atomics -> no cross-XCD line ping-pong).
__global__ __launch_bounds__(1024) void k_topk(const float* __restrict__ score,
                                               int* __restrict__ sel){
  __shared__ int hist[256];
  __shared__ unsigned sh_prefix;
  __shared__ int sh_rem;
  __shared__ int cntGT, cntEQ;
  __shared__ int ties[256];
  int t = threadIdx.x;
  if (t==0){ sh_prefix=0u; sh_rem=NK; cntGT=0; cntEQ=0; }
  __syncthreads();
  for (int p=0;p<4;p++){
    int shift = 24-8*p;
    if (t<256) hist[t]=0;
    __syncthreads();
    unsigned prefix = sh_prefix;
    for (int i=t;i<NN;i+=1024){
      unsigned u = fkey(score[i]);
      bool ok = (p==0) || ((u>>(shift+8)) == (prefix>>(shift+8)));
      if (ok) atomicAdd(&hist[(u>>shift)&255],1);
    }
    __syncthreads();
    if (t==0){
      int rem = sh_rem;
      unsigned pre = sh_prefix;
      for (int b=255;b>=0;b--){
        int c=hist[b];
        if (rem>c) rem-=c; else { pre |= ((unsigned)b)<<shift; break; }
      }
      sh_rem=rem; sh_prefix=pre;
    }
    __syncthreads();
  }
  unsigned Tu = sh_prefix;
  for (int i=t;i<NN;i+=1024){
    unsigned u = fkey(score[i]);
    if (u>Tu){ int p2=atomicAdd(&cntGT,1); sel[p2]=i; }
    else if (u==Tu){ int p2=atomicAdd(&cntEQ,1); if (p2<256) ties[p2]=i; }
  }
  __syncthreads();
  if (t==0){
    int base=cntGT, rem=sh_rem, nt=min(cntEQ,256);
    for (int r=0;r<rem;r++){
      int best=0x7fffffff, bi=-1;
      for (int q=0;q<nt;q++){ int v=ties[q]; if (v>=0 && v<best){best=v;bi=q;} }
      sel[base+r] = (bi>=0)? best : 0;
      if (bi>=0) ties[bi]=-1;
    }
  }
}

// ---------------- xp gather + node2k ----------------
__global__ void k_gatherx(const int* __restrict__ sel, const float* __restrict__ score,
                          const float* __restrict__ h, float* __restrict__ xp,
                          int* __restrict__ node2k){
  int k = blockIdx.x; int t = threadIdx.x; // 128
  int n = sel[k];
  if (t==0) node2k[n] = k;
  float g = tanhf(score[n]);
  xp[(size_t)k*128+t] = h[(size_t)n*128+t]*g;
}

// ---------------- DMoN assignment softmax ----------------
__global__ void k_assign(const float* __restrict__ xp, const float* __restrict__ dw,
                         const float* __restrict__ db, float* __restrict__ sA){
  int k = blockIdx.x; int lane = threadIdx.x; // 64
  __shared__ float logits[16];
  float x0 = xp[(size_t)k*128+lane], x1 = xp[(size_t)k*128+64+lane];
  for (int c=0;c<16;c++){
    float p = x0*dw[c*128+lane] + x1*dw[c*128+64+lane];
    #pragma unroll
    for (int off=32;off>0;off>>=1) p += __shfl_down(p,off);
    if (lane==0) logits[c] = p + db[c];
  }
  __syncthreads();
  if (lane<16){
    float mx=-1e30f;
    for (int c=0;c<16;c++) mx = fmaxf(mx, logits[c]);
    float s=0.f;
    for (int c=0;c<16;c++) s += __expf(logits[c]-mx);
    sA[(size_t)k*16+lane] = __expf(logits[lane]-mx)/s;
  }
}

// ---------------- pooled adjacency: t[ni,:] += s[nj,:], deg[nj]+=1 ----------------
__global__ void k_edgepool(const int* __restrict__ ei, const int* __restrict__ node2k,
                           const float* __restrict__ sA, float* __restrict__ tbuf,
                           float* __restrict__ deg){
  int e = blockIdx.x*blockDim.x + threadIdx.x;
  if (e >= NE) return;
  int ni = node2k[ei[e]];
  int nj = node2k[ei[NE+e]];
  if (ni >= 0 && nj >= 0){
    atomicAdd(&deg[nj], 1.f);
    const float* sr = &sA[(size_t)nj*16];
    float* tr = &tbuf[(size_t)ni*16];
    #pragma unroll
    for (int c=0;c<16;c++) atomicAdd(&tr[c], sr[c]);
  }
}

// ---------------- out_x = s^T xp (raw, selu later) ----------------
__global__ void k_outx(const float* __restrict__ sA, const float* __restrict__ xp,
                       float* __restrict__ acc){
  __shared__ float loc[2048];
  __shared__ float sv[16];
  __shared__ float xv[128];
  int t = threadIdx.x;
  for (int j=t;j<2048;j+=256) loc[j]=0.f;
  int i0 = blockIdx.x*(NK/16), i1 = i0 + NK/16;
  __syncthreads();
  for (int i=i0;i<i1;i++){
    if (t<16) sv[t]=sA[(size_t)i*16+t];
    else if (t>=128) xv[t-128]=xp[(size_t)i*128+(t-128)];
    __syncthreads();
    #pragma unroll
    for (int j=0;j<8;j++){ int o=t+j*256; loc[o] += sv[o>>7]*xv[o&127]; }
    __syncthreads();
  }
  for (int j=t;j<2048;j+=256) atomicAdd(&acc[A_OUTX+j], loc[j]);
}

// ---------------- DMoN reductions ----------------
__global__ void k_dmred(const float* __restrict__ sA, const float* __restrict__ tb,
                        const float* __restrict__ deg, float* __restrict__ acc){
  __shared__ float sv[16], tv[16];
  __shared__ float dsh;
  int t = threadIdx.x; int c=t>>4, d=t&15;
  float a_adj=0.f, a_ss=0.f, a_cs=0.f, a_v=0.f, a_dg=0.f;
  int i0 = blockIdx.x*(NK/16), i1 = i0 + NK/16;
  for (int i=i0;i<i1;i++){
    if (t<16) sv[t]=sA[(size_t)i*16+t];
    else if (t<32) tv[t-16]=tb[(size_t)i*16+(t-16)];
    else if (t==32) dsh = deg[i];
    __syncthreads();
    float sc = sv[c];
    a_adj += sc*tv[d];
    a_ss  += sc*sv[d];
    if (d==0){ a_cs += sc; a_v += sc*dsh; }
    if (t==0) a_dg += dsh;
    __syncthreads();
  }
  atomicAdd(&acc[A_ADJ + t], a_adj);
  atomicAdd(&acc[A_SS + t], a_ss);
  if (d==0){ atomicAdd(&acc[A_CSUM+c], a_cs); atomicAdd(&acc[A_V+c], a_v); }
  if (t==0) atomicAdd(&acc[A_DEGSUM], a_dg);
}

__device__ float block_sum_256(float v, float* red){
  int t = threadIdx.x;
  red[t]=v; __syncthreads();
  #pragma unroll
  for (int o=128;o>0;o>>=1){ if (t<o) red[t]+=red[t+o]; __syncthreads(); }
  float r = red[0]; __syncthreads();
  return r;
}

// ---------------- losses + normalized adjacency ----------------
__global__ __launch_bounds__(256) void k_finloss(float* __restrict__ acc, float* __restrict__ dout){
  __shared__ float red[256];
  __shared__ float dsv[16];
  int t = threadIdx.x;
  int c = t>>4, dcol = t&15;
  float m = 0.5f*acc[A_DEGSUM];
  float ssv = acc[A_SS+t];
  float tr    = block_sum_256((t<16)? acc[A_ADJ + t*16 + t] : 0.f, red);
  float sumv2 = block_sum_256((t<16)? acc[A_V+t]*acc[A_V+t] : 0.f, red);
  float ss2   = block_sum_256(ssv*ssv, red);
  float cs2   = block_sum_256((t<16)? acc[A_CSUM+t]*acc[A_CSUM+t] : 0.f, red);
  float ssn = sqrtf(ss2);
  float term = ssv/ssn - ((c==dcol)? 0.25f : 0.f);
  float ortho2 = block_sum_256(term*term, red);
  if (t==0){
    float spectral = -(tr - sumv2/(2.f*m))/(2.f*m);
    float ortho = sqrtf(ortho2);
    float cluster = sqrtf(cs2)/(float)NK*4.f - 1.f;
    dout[1] = spectral + ortho + cluster;
  }
  // normalized adjacency
  float z = (c==dcol)? 0.f : acc[A_ADJ+t];
  red[t]=z; __syncthreads();
  for (int o=8;o>0;o>>=1){ if (dcol<o) red[t]+=red[t+o]; __syncthreads(); }
  if (dcol==0) dsv[c]=sqrtf(red[c*16])+1e-15f;
  __syncthreads();
  acc[A_ADJN+t] = z/(dsv[c]*dsv[dcol]);
}

// ---------------- selu on out_x ----------------
__global__ void k_selu(float* __restrict__ acc){
  int i = blockIdx.x*blockDim.x + threadIdx.x;
  if (i >= 2048) return;
  float x = acc[A_OUTX+i];
  float s = (x > 0.f)? x : 1.6732632423543772f*expm1f(x);
  acc[A_OUTX+i] = 1.0507009873554805f*s;
}

// ---------------- hh = selu(out_x) @ Wt^T ----------------
__global__ void k_hh(const float* __restrict__ acc, const float* __restrict__ Wt,
                     float* __restrict__ hh){
  int of = blockIdx.x*256 + threadIdx.x; // 0..8191
  int c = of >> 9, o = of & 511;
  const float* sx = acc + A_OUTX + c*128;
  const float* w = Wt + (size_t)o*128;
  float s=0.f;
  for (int k=0;k<128;k++) s += sx[k]*w[k];
  hh[of] = s;
}

// ---------------- dense GAT head + readout ----------------
__global__ __launch_bounds__(256) void k_head(
    const float* __restrict__ hh_g, const float* __restrict__ acc,
    const float* __restrict__ att_s, const float* __restrict__ att_d,
    const float* __restrict__ bt, const float* __restrict__ gate_w,
    const float* __restrict__ gate_b, const float* __restrict__ trans_w,
    const float* __restrict__ trans_b, const int* __restrict__ task,
    const float* __restrict__ task_emb, const float* __restrict__ task_w,
    const float* __restrict__ task_b, const float* __restrict__ fuse_w,
    const float* __restrict__ fuse_b, const float* __restrict__ out_w,
    const float* __restrict__ out_b, float* __restrict__ dout){
  __shared__ float hh[8192];
  __shared__ float al[1024];     // [i][j][h] = [(i*16+j)*4+h]
  __shared__ float asrc[64], adst[64];
  __shared__ float dg[2048];
  __shared__ float gate[16];
  __shared__ float gvec[128];
  __shared__ float ro[128], te[128], fu[128];
  __shared__ float red[256];
  int t = threadIdx.x;
  for (int i=t;i<8192;i+=256) hh[i]=hh_g[i];
  __syncthreads();
  if (t<128){
    int j = t>>3; int h = (t>>1)&3; int w = t&1;
    const float* hr = &hh[j*512 + h*128];
    const float* a = (w? att_d : att_s) + h*128;
    float s=0.f;
    for (int k2=0;k2<128;k2++) s += hr[k2]*a[k2];
    if (w) adst[j*4+h]=s; else asrc[j*4+h]=s;
  }
  __syncthreads();
  for (int idx=t; idx<1024; idx+=256){
    int h = idx&3, j=(idx>>2)&15, i=idx>>6;
    float v = asrc[j*4+h] + adst[i*4+h];
    v = v>0.f? v : 0.2f*v;
    float adjl = (i==j)? 1.f : acc[A_ADJN + i*16+j];
    al[idx] = (adjl==0.f)? -1e30f : v;
  }
  __syncthreads();
  if (t<64){
    int i=t>>2, h=t&3;
    float mx=-1e30f;
    for (int j=0;j<16;j++) mx = fmaxf(mx, al[(i*16+j)*4+h]);
    float sum=0.f;
    for (int j=0;j<16;j++){ float e=__expf(al[(i*16+j)*4+h]-mx); al[(i*16+j)*4+h]=e; sum+=e; }
    float inv = 1.f/sum;
    for (int j=0;j<16;j++) al[(i*16+j)*4+h]*=inv;
  }
  __syncthreads();
  for (int idx=t; idx<2048; idx+=256){
    int i=idx>>7, d=idx&127;
    float s=0.f;
    for (int h=0;h<4;h++)
      for (int j=0;j<16;j++)
        s += al[(i*16+j)*4+h]*hh[j*512+h*128+d];
    dg[idx] = fmaxf(0.25f*s + bt[d], 0.f);
  }
  __syncthreads();
  if (t<16){
    float s=0.f;
    for (int d2=0;d2<128;d2++) s += dg[t*128+d2]*gate_w[d2];
    red[t] = s + gate_b[0];
  }
  __syncthreads();
  if (t<16){
    float mx=-1e30f; for (int i=0;i<16;i++) mx=fmaxf(mx,red[i]);
    float s=0.f; for (int i=0;i<16;i++) s+=__expf(red[i]-mx);
    gate[t]=__expf(red[t]-mx)/s;
  }
  __syncthreads();
  if (t<128){
    float s=0.f;
    for (int i=0;i<16;i++) s += gate[i]*dg[i*128+t];
    gvec[t]=s;
  }
  __syncthreads();
  if (t<128){
    float s=0.f;
    for (int k2=0;k2<128;k2++) s += gvec[k2]*trans_w[t*128+k2];
    ro[t]=s+trans_b[t];
    int tk = task[0];
    float s2=0.f;
    for (int k2=0;k2<128;k2++) s2 += task_emb[(size_t)tk*128+k2]*task_w[t*128+k2];
    te[t]=fmaxf(s2+task_b[t],0.f);
  }
  __syncthreads();
  if (t<128){
    float s=0.f;
    for (int k2=0;k2<128;k2++) s += ro[k2]*fuse_w[t*256+k2] + te[k2]*fuse_w[t*256+128+k2];
    fu[t]=fmaxf(s+fuse_b[t],0.f);
  }
  __syncthreads();
  float v = (t<128)? fu[t]*out_w[t] : 0.f;
  red[t]=v; __syncthreads();
  for (int o=128;o>0;o>>=1){ if (t<o) red[t]+=red[t+o]; __syncthreads(); }
  if (t==0) dout[0]=red[0]+out_b[0];
}

// ================= launcher =================
extern "C" void kernel_launch(void* const* d_in, const int* in_sizes, int n_in,
                              void* d_out, int out_size, void* d_ws, size_t ws_size,
                              hipStream_t stream){
  const int* x        = (const int*)d_in[0];
  const int* ei       = (const int*)d_in[1];
  const int* task     = (const int*)d_in[3];
  const float* node_emb = (const float*)d_in[4];
  const float* task_emb = (const float*)d_in[5];
  const float* W[3]  = {(const float*)d_in[6],  (const float*)d_in[10], (const float*)d_in[14]};
  const float* As_[3]= {(const float*)d_in[7],  (const float*)d_in[11], (const float*)d_in[15]};
  const float* Ad_[3]= {(const float*)d_in[8],  (const float*)d_in[12], (const float*)d_in[16]};
  const float* Bb[3] = {(const float*)d_in[9],  (const float*)d_in[13], (const float*)d_in[17]};
  const float* wrel  = (const float*)d_in[18];
  const float* brel  = (const float*)d_in[19];
  const float* wroot = (const float*)d_in[20];
  const float* dmon_w= (const float*)d_in[21];
  const float* dmon_b= (const float*)d_in[22];
  const float* Wt    = (const float*)d_in[23];
  const float* att_s = (const float*)d_in[24];
  const float* att_d = (const float*)d_in[25];
  const float* btb   = (const float*)d_in[26];
  const float* gate_w= (const float*)d_in[27];
  const float* gate_b= (const float*)d_in[28];
  const float* trans_w=(const float*)d_in[29];
  const float* trans_b=(const float*)d_in[30];
  const float* task_w= (const float*)d_in[31];
  const float* task_b= (const float*)d_in[32];
  const float* fuse_w= (const float*)d_in[33];
  const float* fuse_b= (const float*)d_in[34];
  const float* out_w = (const float*)d_in[35];
  const float* out_b = (const float*)d_in[36];
  float* dout = (float*)d_out;
  (void)in_sizes; (void)n_in; (void)out_size; (void)ws_size;

  char* base = (char*)d_ws;
  size_t off = 0;
  auto alloc = [&](size_t bytes)->char*{
    off = (off + 255) & ~(size_t)255;
    char* r = base + off; off += bytes; return r;
  };
  int* csr_ptr  = (int*)alloc((size_t)(NN+1)*4);
  int* csr_fill = (int*)alloc((size_t)NN*4);
  int* csr_src  = (int*)alloc((size_t)NET*4);
  int* sel      = (int*)alloc((size_t)NK*4);
  int* node2k   = (int*)alloc((size_t)NN*4);
  float* score  = (float*)alloc((size_t)NN*4);
  float* h_a    = (float*)alloc((size_t)NN*128*4);
  float* h_b    = (float*)alloc((size_t)NN*128*4);
  float* hfeat  = (float*)alloc((size_t)NN*512*4);
  float* sum_s  = (float*)alloc((size_t)NN*4*4);
  float* sum_d  = (float*)alloc((size_t)NN*4*4);
  float* alpha  = (float*)alloc((size_t)NET*4*4);
  float* xp     = (float*)alloc((size_t)NK*128*4);
  float* sA     = (float*)alloc((size_t)NK*16*4);
  float* tbuf   = (float*)alloc((size_t)NK*16*4);
  float* deg    = (float*)alloc((size_t)NK*4);
  float* acc    = (float*)alloc((size_t)ACC_FLOATS*4);
  float* hh_g   = (float*)alloc((size_t)8192*4);

  k_init<<<256, 256, 0, stream>>>(csr_fill, node2k, tbuf, deg, acc);
  k_count<<<(NET+255)/256, 256, 0, stream>>>(ei, csr_fill);
  k_scan<<<1, 1024, 0, stream>>>(csr_fill, csr_ptr, csr_fill);
  k_fill<<<(NET+255)/256, 256, 0, stream>>>(ei, csr_fill, csr_src);
  k_embed<<<(NN*32+255)/256, 256, 0, stream>>>(x, node_emb, (float4*)h_a);

  float* hin = h_a; float* hout = h_b;
  for (int l=0;l<3;l++){
    k_gemm<<<dim3(NN/64, 512/64), 256, 0, stream>>>(hin, W[l], hfeat);
    k_attnsum<<<NN, 64, 0, stream>>>(hfeat, As_[l], Ad_[l], sum_s, sum_d);
    k_edges<<<(NN*NH+255)/256, 256, 0, stream>>>(csr_ptr, csr_src, sum_s, sum_d, alpha);
    k_agg<<<NN, 128, 0, stream>>>(csr_ptr, csr_src, alpha, hfeat, Bb[l], hout);
    float* tmp=hin; hin=hout; hout=tmp;
  }
  // hin = final node features
  k_sag<<<NN, 128, 0, stream>>>(csr_ptr, csr_src, hin, wrel, brel, wroot, score);
  k_topk<<<1, 1024, 0, stream>>>(score, sel);
  k_gatherx<<<NK, 128, 0, stream>>>(sel, score, hin, xp, node2k);
  k_assign<<<NK, 64, 0, stream>>>(xp, dmon_w, dmon_b, sA);
  k_edgepool<<<(NE+255)/256, 256, 0, stream>>>(ei, node2k, sA, tbuf, deg);
  k_outx<<<16, 256, 0, stream>>>(sA, xp, acc);
  k_dmred<<<16, 256, 0, stream>>>(sA, tbuf, deg, acc);
  k_finloss<<<1, 256, 0, stream>>>(acc, dout);
  k_selu<<<8, 256, 0, stream>>>(acc);
  k_hh<<<32, 256, 0, stream>>>(acc, Wt, hh_g);
  k_head<<<1, 256, 0, stream>>>(hh_g, acc, att_s, att_d, btb, gate_w, gate_b,
                                trans_w, trans_b, task, task_emb, task_w, task_b,
                                fuse_w, fuse_b, out_w, out_b, dout);
}

// Round 3
// 795.155 us; speedup vs baseline: 1.4895x; 1.2399x over previous
//
#include <hip/hip_runtime.h>
#include <hip/hip_bf16.h>
#include <math.h>

// Problem constants
constexpr int NN  = 16000;          // nodes
constexpr int NE  = 256000;         // edges (original)
constexpr int NET = NE + NN;        // edges incl. self loops
constexpr int NK  = 4000;           // top-k
constexpr int NH  = 4;              // heads
constexpr int ND  = 128;            // dim
constexpr int NCL = 16;             // clusters

// acc buffer sub-offsets (floats)
constexpr int A_ADJ    = 0;     // 256  raw s^T adj s
constexpr int A_SS     = 256;   // 256  s^T s
constexpr int A_CSUM   = 512;   // 16   sum_n s[n,c]
constexpr int A_V      = 528;   // 16   sum_n s[n,c]*deg[n]
constexpr int A_DEGSUM = 544;   // 1
constexpr int A_OUTX   = 560;   // 2048 s^T xp (later selu'd in place)
constexpr int A_ADJN   = 2608;  // 256  normalized adjacency
constexpr int ACC_FLOATS = 3072;

__device__ inline unsigned fkey(float f){
  unsigned u = __float_as_uint(f);
  return (u & 0x80000000u) ? ~u : (u | 0x80000000u);
}

// ---------------- init ----------------
__global__ void k_init(int* cnt, int* node2k, float* tbuf, float* deg, float* acc){
  int i = blockIdx.x*blockDim.x + threadIdx.x;
  int stride = gridDim.x*blockDim.x;
  for (int j=i; j<NN; j+=stride){ cnt[j]=0; node2k[j]=-1; }
  for (int j=i; j<NK*NCL; j+=stride) tbuf[j]=0.f;
  for (int j=i; j<NK; j+=stride) deg[j]=0.f;
  for (int j=i; j<ACC_FLOATS; j+=stride) acc[j]=0.f;
}

// ---------------- CSR build ----------------
__global__ void k_count(const int* __restrict__ ei, int* __restrict__ cnt){
  int e = blockIdx.x*blockDim.x + threadIdx.x;
  if (e >= NET) return;
  int d = (e < NE) ? ei[NE+e] : (e-NE);
  atomicAdd(&cnt[d], 1);
}

// hierarchical scan: 16 elems/thread serial + one 1024-wide block scan (20 barriers)
__global__ __launch_bounds__(1024) void k_scan(int* cnt, int* ptr, int* fill){
  __shared__ int sums[1024];
  int t = threadIdx.x;
  constexpr int PER = 16;            // 1024*16 = 16384 >= NN
  int base = t*PER;
  int v[PER];
  int run = 0;
  #pragma unroll
  for (int i=0;i<PER;i++){
    int idx = base+i;
    int c = (idx<NN)? cnt[idx] : 0;
    v[i] = run; run += c;
  }
  sums[t] = run;
  __syncthreads();
  for (int o=1;o<1024;o<<=1){
    int add = (t>=o)? sums[t-o] : 0;
    __syncthreads();
    sums[t] += add;
    __syncthreads();
  }
  int ex = sums[t] - run;            // exclusive prefix of this thread's chunk
  #pragma unroll
  for (int i=0;i<PER;i++){
    int idx = base+i;
    if (idx<NN){ int p = ex+v[i]; ptr[idx]=p; fill[idx]=p; }
  }
  if (t==1023) ptr[NN]=sums[1023];
}

__global__ void k_fill(const int* __restrict__ ei, int* cur, int* csrc){
  int e = blockIdx.x*blockDim.x + threadIdx.x;
  if (e >= NET) return;
  int s, d;
  if (e < NE){ s = ei[e]; d = ei[NE+e]; } else { s = e-NE; d = e-NE; }
  int pos = atomicAdd(&cur[d], 1);
  csrc[pos] = s;
}

// ---------------- embedding ----------------
__global__ void k_embed(const int* __restrict__ x, const float* __restrict__ emb,
                        float4* __restrict__ h){
  int i = blockIdx.x*blockDim.x + threadIdx.x;
  if (i >= NN*32) return;
  int n = i >> 5, q = i & 31;
  h[i] = ((const float4*)emb)[(size_t)x[n]*32 + q];
}

// ---------------- fp32 GEMM: C[M,512] = A[M,128] @ B[512,128]^T ----------------
__global__ __launch_bounds__(256) void k_gemm(const float* __restrict__ A,
                                              const float* __restrict__ B,
                                              float* __restrict__ C){
  __shared__ float As[64*68];
  __shared__ float Bs[64*68];
  int tid = threadIdx.x;
  int m0 = blockIdx.x*64, n0 = blockIdx.y*64;
  int ty = tid>>4, tx = tid&15;
  float cacc[4][4] = {};
  for (int kk=0; kk<128; kk+=64){
    #pragma unroll
    for (int i=0;i<4;i++){
      int idx = tid + i*256;       // 0..1023
      int r = idx>>4, q = idx&15;  // row, float4-col
      float4 av = *(const float4*)&A[(size_t)(m0+r)*128 + kk + q*4];
      float* da = &As[r*68 + q*4];
      da[0]=av.x; da[1]=av.y; da[2]=av.z; da[3]=av.w;
      float4 bv = *(const float4*)&B[(size_t)(n0+r)*128 + kk + q*4];
      float* db = &Bs[r*68 + q*4];
      db[0]=bv.x; db[1]=bv.y; db[2]=bv.z; db[3]=bv.w;
    }
    __syncthreads();
    #pragma unroll 4
    for (int k=0;k<64;k+=4){
      float4 b0 = *(const float4*)&Bs[(tx    )*68 + k];
      float4 b1 = *(const float4*)&Bs[(tx+16 )*68 + k];
      float4 b2 = *(const float4*)&Bs[(tx+32 )*68 + k];
      float4 b3 = *(const float4*)&Bs[(tx+48 )*68 + k];
      #pragma unroll
      for (int i=0;i<4;i++){
        float4 a = *(const float4*)&As[(ty+16*i)*68 + k];
        cacc[i][0] += a.x*b0.x + a.y*b0.y + a.z*b0.z + a.w*b0.w;
        cacc[i][1] += a.x*b1.x + a.y*b1.y + a.z*b1.z + a.w*b1.w;
        cacc[i][2] += a.x*b2.x + a.y*b2.y + a.z*b2.z + a.w*b2.w;
        cacc[i][3] += a.x*b3.x + a.y*b3.y + a.z*b3.z + a.w*b3.w;
      }
    }
    __syncthreads();
  }
  #pragma unroll
  for (int i=0;i<4;i++)
    #pragma unroll
    for (int j=0;j<4;j++)
      C[(size_t)(m0+ty+16*i)*512 + n0+tx+16*j] = cacc[i][j];
}

// ---------------- attention per-node sums ----------------
__global__ void k_attnsum(const float* __restrict__ hf, const float* __restrict__ as_,
                          const float* __restrict__ ad_, float* __restrict__ sum_s,
                          float* __restrict__ sum_d){
  int n = blockIdx.x, lane = threadIdx.x;   // 64 threads
  const float* row = hf + (size_t)n*512;
  for (int h=0;h<4;h++){
    float x0 = row[h*128+lane], x1 = row[h*128+64+lane];
    float ps = x0*as_[h*128+lane] + x1*as_[h*128+64+lane];
    float pd = x0*ad_[h*128+lane] + x1*ad_[h*128+64+lane];
    #pragma unroll
    for (int off=32; off>0; off>>=1){ ps += __shfl_down(ps,off); pd += __shfl_down(pd,off); }
    if (lane==0){ sum_s[n*4+h]=ps; sum_d[n*4+h]=pd; }
  }
}

// ---------------- edge softmax (per dst,head), 2 passes; scaling deferred ----------------
__global__ void k_edges(const int* __restrict__ ptr, const int* __restrict__ csrc,
                        const float* __restrict__ sum_s, const float* __restrict__ sum_d,
                        float* __restrict__ alpha, float* __restrict__ inv_den){
  int idx = blockIdx.x*blockDim.x + threadIdx.x;
  if (idx >= NN*NH) return;
  int n = idx >> 2, h = idx & 3;
  int b0 = ptr[n], b1 = ptr[n+1];
  float sd = sum_d[n*4+h];
  float mx = -1e30f;
  for (int j=b0;j<b1;j++){
    float v = sum_s[csrc[j]*4+h] + sd;
    v = v > 0.f ? v : 0.2f*v;
    alpha[(size_t)j*4+h] = v;
    mx = fmaxf(mx, v);
  }
  float den = 0.f;
  for (int j=b0;j<b1;j++){
    float e = __expf(alpha[(size_t)j*4+h] - mx);
    alpha[(size_t)j*4+h] = e;
    den += e;
  }
  inv_den[(size_t)n*4+h] = 1.f/(den + 1e-16f);
}

// ---------------- weighted aggregation + head-mean + bias + relu ----------------
__global__ void k_agg(const int* __restrict__ ptr, const int* __restrict__ csrc,
                      const float* __restrict__ alpha, const float* __restrict__ inv_den,
                      const float* __restrict__ hf, const float* __restrict__ bias,
                      float* __restrict__ hout){
  int n = blockIdx.x; int t = threadIdx.x;  // 128 threads
  int b0 = ptr[n], b1 = ptr[n+1];
  float a0=0.f, a1=0.f, a2=0.f, a3=0.f;
  for (int j=b0;j<b1;j++){
    int s = csrc[j];
    float4 al = *(const float4*)&alpha[(size_t)j*4];
    const float* hr = hf + (size_t)s*512;
    a0 += al.x*hr[t];     a1 += al.y*hr[128+t];
    a2 += al.z*hr[256+t]; a3 += al.w*hr[384+t];
  }
  float4 idv = *(const float4*)&inv_den[(size_t)n*4];
  float acc = a0*idv.x + a1*idv.y + a2*idv.z + a3*idv.w;
  hout[(size_t)n*128+t] = fmaxf(0.25f*acc + bias[t], 0.f);
}

// ---------------- SAG score ----------------
__global__ void k_sag(const int* __restrict__ ptr, const int* __restrict__ csrc,
                      const float* __restrict__ h, const float* __restrict__ wrel,
                      const float* __restrict__ brel, const float* __restrict__ wroot,
                      float* __restrict__ score){
  int n = blockIdx.x; int t = threadIdx.x; // 128
  int b0 = ptr[n], b1 = ptr[n+1];
  float agg = 0.f;
  for (int j=b0;j<b1;j++){
    int s = csrc[j];
    if (s != n) agg += h[(size_t)s*128 + t];   // skip the added self loop
  }
  float part = agg*wrel[t] + h[(size_t)n*128+t]*wroot[t];
  #pragma unroll
  for (int o=32;o>0;o>>=1) part += __shfl_down(part, o);
  __shared__ float r2[2];
  if ((t&63)==0) r2[t>>6]=part;
  __syncthreads();
  if (t==0) score[n] = r2[0]+r2[1]+brel[0];
}

// ---------------- fused single-block radix top-k ----------------
__global__ __launch_bounds__(1024) void k_topk(const float* __restrict__ score,
                                               int* __restrict__ sel){
  __shared__ int hist[256];
  __shared__ unsigned sh_prefix;
  __shared__ int sh_rem;
  __shared__ int cntGT, cntEQ;
  __shared__ int ties[256];
  int t = threadIdx.x;
  if (t==0){ sh_prefix=0u; sh_rem=NK; cntGT=0; cntEQ=0; }
  __syncthreads();
  for (int p=0;p<4;p++){
    int shift = 24-8*p;
    if (t<256) hist[t]=0;
    __syncthreads();
    unsigned prefix = sh_prefix;
    for (int i=t;i<NN;i+=1024){
      unsigned u = fkey(score[i]);
      bool ok = (p==0) || ((u>>(shift+8)) == (prefix>>(shift+8)));
      if (ok) atomicAdd(&hist[(u>>shift)&255],1);
    }
    __syncthreads();
    if (t==0){
      int rem = sh_rem;
      unsigned pre = sh_prefix;
      for (int b=255;b>=0;b--){
        int c=hist[b];
        if (rem>c) rem-=c; else { pre |= ((unsigned)b)<<shift; break; }
      }
      sh_rem=rem; sh_prefix=pre;
    }
    __syncthreads();
  }
  unsigned Tu = sh_prefix;
  for (int i=t;i<NN;i+=1024){
    unsigned u = fkey(score[i]);
    if (u>Tu){ int p2=atomicAdd(&cntGT,1); sel[p2]=i; }
    else if (u==Tu){ int p2=atomicAdd(&cntEQ,1); if (p2<256) ties[p2]=i; }
  }
  __syncthreads();
  if (t==0){
    int base=cntGT, rem=sh_rem, nt=min(cntEQ,256);
    for (int r=0;r<rem;r++){
      int best=0x7fffffff, bi=-1;
      for (int q=0;q<nt;q++){ int v=ties[q]; if (v>=0 && v<best){best=v;bi=q;} }
      sel[base+r] = (bi>=0)? best : 0;
      if (bi>=0) ties[bi]=-1;
    }
  }
}

// ---------------- xp gather + node2k ----------------
__global__ void k_gatherx(const int* __restrict__ sel, const float* __restrict__ score,
                          const float* __restrict__ h, float* __restrict__ xp,
                          int* __restrict__ node2k){
  int k = blockIdx.x; int t = threadIdx.x; // 128
  int n = sel[k];
  if (t==0) node2k[n] = k;
  float g = tanhf(score[n]);
  xp[(size_t)k*128+t] = h[(size_t)n*128+t]*g;
}

// ---------------- DMoN assignment softmax ----------------
__global__ void k_assign(const float* __restrict__ xp, const float* __restrict__ dw,
                         const float* __restrict__ db, float* __restrict__ sA){
  int k = blockIdx.x; int lane = threadIdx.x; // 64
  __shared__ float logits[16];
  float x0 = xp[(size_t)k*128+lane], x1 = xp[(size_t)k*128+64+lane];
  for (int c=0;c<16;c++){
    float p = x0*dw[c*128+lane] + x1*dw[c*128+64+lane];
    #pragma unroll
    for (int off=32;off>0;off>>=1) p += __shfl_down(p,off);
    if (lane==0) logits[c] = p + db[c];
  }
  __syncthreads();
  if (lane<16){
    float mx=-1e30f;
    for (int c=0;c<16;c++) mx = fmaxf(mx, logits[c]);
    float s=0.f;
    for (int c=0;c<16;c++) s += __expf(logits[c]-mx);
    sA[(size_t)k*16+lane] = __expf(logits[lane]-mx)/s;
  }
}

// ---------------- pooled adjacency: t[ni,:] += s[nj,:], deg[nj]+=1 ----------------
__global__ void k_edgepool(const int* __restrict__ ei, const int* __restrict__ node2k,
                           const float* __restrict__ sA, float* __restrict__ tbuf,
                           float* __restrict__ deg){
  int e = blockIdx.x*blockDim.x + threadIdx.x;
  if (e >= NE) return;
  int ni = node2k[ei[e]];
  int nj = node2k[ei[NE+e]];
  if (ni >= 0 && nj >= 0){
    atomicAdd(&deg[nj], 1.f);
    const float* sr = &sA[(size_t)nj*16];
    float* tr = &tbuf[(size_t)ni*16];
    #pragma unroll
    for (int c=0;c<16;c++) atomicAdd(&tr[c], sr[c]);
  }
}

// ---------------- fused pooled reductions: out_x = s^T xp  +  DMoN sums ----------------
// 32 blocks x 125 rows, staged 25 rows per barrier-pair; register accumulators.
constexpr int P_BLOCKS = 32;
constexpr int P_ROWS   = NK / P_BLOCKS;   // 125
constexpr int P_CHUNK  = 25;

__global__ __launch_bounds__(256) void k_pool(const float* __restrict__ sA,
                                              const float* __restrict__ xp,
                                              const float* __restrict__ tb,
                                              const float* __restrict__ deg,
                                              float* __restrict__ acc){
  __shared__ float sv[P_CHUNK*16];
  __shared__ float tv[P_CHUNK*16];
  __shared__ float dv[P_CHUNK];
  __shared__ float xv[P_CHUNK*128];
  int t = threadIdx.x;
  int c = t>>4, d = t&15;
  float loc[8] = {0,0,0,0,0,0,0,0};
  float a_adj=0.f, a_ss=0.f, a_cs=0.f, a_v=0.f, a_dg=0.f;
  int r0 = blockIdx.x*P_ROWS;
  for (int ch=0; ch<P_ROWS; ch+=P_CHUNK){
    int base = r0+ch;
    for (int i=t;i<P_CHUNK*16;i+=256){
      sv[i] = sA[(size_t)(base+(i>>4))*16 + (i&15)];
      tv[i] = tb[(size_t)(base+(i>>4))*16 + (i&15)];
    }
    for (int i=t;i<P_CHUNK*128;i+=256)
      xv[i] = xp[(size_t)(base+(i>>7))*128 + (i&127)];
    if (t<P_CHUNK) dv[t]=deg[base+t];
    __syncthreads();
    for (int r=0;r<P_CHUNK;r++){
      float sc = sv[r*16+c];
      a_adj += sc*tv[r*16+d];
      a_ss  += sc*sv[r*16+d];
      if (d==0){ a_cs += sc; a_v += sc*dv[r]; }
      if (t==0) a_dg += dv[r];
      #pragma unroll
      for (int j=0;j<8;j++){
        int o=t+j*256;
        loc[j] += sv[r*16+(o>>7)]*xv[r*128+(o&127)];
      }
    }
    __syncthreads();
  }
  atomicAdd(&acc[A_ADJ + t], a_adj);
  atomicAdd(&acc[A_SS + t], a_ss);
  if (d==0){ atomicAdd(&acc[A_CSUM+c], a_cs); atomicAdd(&acc[A_V+c], a_v); }
  if (t==0) atomicAdd(&acc[A_DEGSUM], a_dg);
  #pragma unroll
  for (int j=0;j<8;j++) atomicAdd(&acc[A_OUTX + t + j*256], loc[j]);
}

__device__ float block_sum_256(float v, float* red){
  int t = threadIdx.x;
  red[t]=v; __syncthreads();
  #pragma unroll
  for (int o=128;o>0;o>>=1){ if (t<o) red[t]+=red[t+o]; __syncthreads(); }
  float r = red[0]; __syncthreads();
  return r;
}

// ---------------- losses + normalized adjacency ----------------
__global__ __launch_bounds__(256) void k_finloss(float* __restrict__ acc, float* __restrict__ dout){
  __shared__ float red[256];
  __shared__ float dsv[16];
  int t = threadIdx.x;
  int c = t>>4, dcol = t&15;
  float m = 0.5f*acc[A_DEGSUM];
  float ssv = acc[A_SS+t];
  float tr    = block_sum_256((t<16)? acc[A_ADJ + t*16 + t] : 0.f, red);
  float sumv2 = block_sum_256((t<16)? acc[A_V+t]*acc[A_V+t] : 0.f, red);
  float ss2   = block_sum_256(ssv*ssv, red);
  float cs2   = block_sum_256((t<16)? acc[A_CSUM+t]*acc[A_CSUM+t] : 0.f, red);
  float ssn = sqrtf(ss2);
  float term = ssv/ssn - ((c==dcol)? 0.25f : 0.f);
  float ortho2 = block_sum_256(term*term, red);
  if (t==0){
    float spectral = -(tr - sumv2/(2.f*m))/(2.f*m);
    float ortho = sqrtf(ortho2);
    float cluster = sqrtf(cs2)/(float)NK*4.f - 1.f;
    dout[1] = spectral + ortho + cluster;
  }
  // normalized adjacency
  float z = (c==dcol)? 0.f : acc[A_ADJ+t];
  red[t]=z; __syncthreads();
  for (int o=8;o>0;o>>=1){ if (dcol<o) red[t]+=red[t+o]; __syncthreads(); }
  if (dcol==0) dsv[c]=sqrtf(red[c*16])+1e-15f;
  __syncthreads();
  acc[A_ADJN+t] = z/(dsv[c]*dsv[dcol]);
}

// ---------------- selu on out_x ----------------
__global__ void k_selu(float* __restrict__ acc){
  int i = blockIdx.x*blockDim.x + threadIdx.x;
  if (i >= 2048) return;
  float x = acc[A_OUTX+i];
  float s = (x > 0.f)? x : 1.6732632423543772f*expm1f(x);
  acc[A_OUTX+i] = 1.0507009873554805f*s;
}

// ---------------- hh = selu(out_x) @ Wt^T ----------------
__global__ void k_hh(const float* __restrict__ acc, const float* __restrict__ Wt,
                     float* __restrict__ hh){
  int of = blockIdx.x*256 + threadIdx.x; // 0..8191
  int c = of >> 9, o = of & 511;
  const float* sx = acc + A_OUTX + c*128;
  const float* w = Wt + (size_t)o*128;
  float s=0.f;
  for (int k=0;k<128;k++) s += sx[k]*w[k];
  hh[of] = s;
}

// ---------------- dense GAT head + readout ----------------
__global__ __launch_bounds__(256) void k_head(
    const float* __restrict__ hh_g, const float* __restrict__ acc,
    const float* __restrict__ att_s, const float* __restrict__ att_d,
    const float* __restrict__ bt, const float* __restrict__ gate_w,
    const float* __restrict__ gate_b, const float* __restrict__ trans_w,
    const float* __restrict__ trans_b, const int* __restrict__ task,
    const float* __restrict__ task_emb, const float* __restrict__ task_w,
    const float* __restrict__ task_b, const float* __restrict__ fuse_w,
    const float* __restrict__ fuse_b, const float* __restrict__ out_w,
    const float* __restrict__ out_b, float* __restrict__ dout){
  __shared__ float hh[8192];
  __shared__ float al[1024];     // [i][j][h] = [(i*16+j)*4+h]
  __shared__ float asrc[64], adst[64];
  __shared__ float dg[2048];
  __shared__ float gate[16];
  __shared__ float gvec[128];
  __shared__ float ro[128], te[128], fu[128];
  __shared__ float red[256];
  int t = threadIdx.x;
  for (int i=t;i<8192;i+=256) hh[i]=hh_g[i];
  __syncthreads();
  if (t<128){
    int j = t>>3; int h = (t>>1)&3; int w = t&1;
    const float* hr = &hh[j*512 + h*128];
    const float* a = (w? att_d : att_s) + h*128;
    float s=0.f;
    for (int k2=0;k2<128;k2++) s += hr[k2]*a[k2];
    if (w) adst[j*4+h]=s; else asrc[j*4+h]=s;
  }
  __syncthreads();
  for (int idx=t; idx<1024; idx+=256){
    int h = idx&3, j=(idx>>2)&15, i=idx>>6;
    float v = asrc[j*4+h] + adst[i*4+h];
    v = v>0.f? v : 0.2f*v;
    float adjl = (i==j)? 1.f : acc[A_ADJN + i*16+j];
    al[idx] = (adjl==0.f)? -1e30f : v;
  }
  __syncthreads();
  if (t<64){
    int i=t>>2, h=t&3;
    float mx=-1e30f;
    for (int j=0;j<16;j++) mx = fmaxf(mx, al[(i*16+j)*4+h]);
    float sum=0.f;
    for (int j=0;j<16;j++){ float e=__expf(al[(i*16+j)*4+h]-mx); al[(i*16+j)*4+h]=e; sum+=e; }
    float inv = 1.f/sum;
    for (int j=0;j<16;j++) al[(i*16+j)*4+h]*=inv;
  }
  __syncthreads();
  for (int idx=t; idx<2048; idx+=256){
    int i=idx>>7, d=idx&127;
    float s=0.f;
    for (int h=0;h<4;h++)
      for (int j=0;j<16;j++)
        s += al[(i*16+j)*4+h]*hh[j*512+h*128+d];
    dg[idx] = fmaxf(0.25f*s + bt[d], 0.f);
  }
  __syncthreads();
  if (t<16){
    float s=0.f;
    for (int d2=0;d2<128;d2++) s += dg[t*128+d2]*gate_w[d2];
    red[t] = s + gate_b[0];
  }
  __syncthreads();
  if (t<16){
    float mx=-1e30f; for (int i=0;i<16;i++) mx=fmaxf(mx,red[i]);
    float s=0.f; for (int i=0;i<16;i++) s+=__expf(red[i]-mx);
    gate[t]=__expf(red[t]-mx)/s;
  }
  __syncthreads();
  if (t<128){
    float s=0.f;
    for (int i=0;i<16;i++) s += gate[i]*dg[i*128+t];
    gvec[t]=s;
  }
  __syncthreads();
  if (t<128){
    float s=0.f;
    for (int k2=0;k2<128;k2++) s += gvec[k2]*trans_w[t*128+k2];
    ro[t]=s+trans_b[t];
    int tk = task[0];
    float s2=0.f;
    for (int k2=0;k2<128;k2++) s2 += task_emb[(size_t)tk*128+k2]*task_w[t*128+k2];
    te[t]=fmaxf(s2+task_b[t],0.f);
  }
  __syncthreads();
  if (t<128){
    float s=0.f;
    for (int k2=0;k2<128;k2++) s += ro[k2]*fuse_w[t*256+k2] + te[k2]*fuse_w[t*256+128+k2];
    fu[t]=fmaxf(s+fuse_b[t],0.f);
  }
  __syncthreads();
  float v = (t<128)? fu[t]*out_w[t] : 0.f;
  red[t]=v; __syncthreads();
  for (int o=128;o>0;o>>=1){ if (t<o) red[t]+=red[t+o]; __syncthreads(); }
  if (t==0) dout[0]=red[0]+out_b[0];
}

// ================= launcher =================
extern "C" void kernel_launch(void* const* d_in, const int* in_sizes, int n_in,
                              void* d_out, int out_size, void* d_ws, size_t ws_size,
                              hipStream_t stream){
  const int* x        = (const int*)d_in[0];
  const int* ei       = (const int*)d_in[1];
  const int* task     = (const int*)d_in[3];
  const float* node_emb = (const float*)d_in[4];
  const float* task_emb = (const float*)d_in[5];
  const float* W[3]  = {(const float*)d_in[6],  (const float*)d_in[10], (const float*)d_in[14]};
  const float* As_[3]= {(const float*)d_in[7],  (const float*)d_in[11], (const float*)d_in[15]};
  const float* Ad_[3]= {(const float*)d_in[8],  (const float*)d_in[12], (const float*)d_in[16]};
  const float* Bb[3] = {(const float*)d_in[9],  (const float*)d_in[13], (const float*)d_in[17]};
  const float* wrel  = (const float*)d_in[18];
  const float* brel  = (const float*)d_in[19];
  const float* wroot = (const float*)d_in[20];
  const float* dmon_w= (const float*)d_in[21];
  const float* dmon_b= (const float*)d_in[22];
  const float* Wt    = (const float*)d_in[23];
  const float* att_s = (const float*)d_in[24];
  const float* att_d = (const float*)d_in[25];
  const float* btb   = (const float*)d_in[26];
  const float* gate_w= (const float*)d_in[27];
  const float* gate_b= (const float*)d_in[28];
  const float* trans_w=(const float*)d_in[29];
  const float* trans_b=(const float*)d_in[30];
  const float* task_w= (const float*)d_in[31];
  const float* task_b= (const float*)d_in[32];
  const float* fuse_w= (const float*)d_in[33];
  const float* fuse_b= (const float*)d_in[34];
  const float* out_w = (const float*)d_in[35];
  const float* out_b = (const float*)d_in[36];
  float* dout = (float*)d_out;
  (void)in_sizes; (void)n_in; (void)out_size; (void)ws_size;

  char* base = (char*)d_ws;
  size_t off = 0;
  auto alloc = [&](size_t bytes)->char*{
    off = (off + 255) & ~(size_t)255;
    char* r = base + off; off += bytes; return r;
  };
  int* csr_ptr  = (int*)alloc((size_t)(NN+1)*4);
  int* csr_fill = (int*)alloc((size_t)NN*4);
  int* csr_src  = (int*)alloc((size_t)NET*4);
  int* sel      = (int*)alloc((size_t)NK*4);
  int* node2k   = (int*)alloc((size_t)NN*4);
  float* score  = (float*)alloc((size_t)NN*4);
  float* h_a    = (float*)alloc((size_t)NN*128*4);
  float* h_b    = (float*)alloc((size_t)NN*128*4);
  float* hfeat  = (float*)alloc((size_t)NN*512*4);
  float* sum_s  = (float*)alloc((size_t)NN*4*4);
  float* sum_d  = (float*)alloc((size_t)NN*4*4);
  float* inv_den= (float*)alloc((size_t)NN*4*4);
  float* alpha  = (float*)alloc((size_t)NET*4*4);
  float* xp     = (float*)alloc((size_t)NK*128*4);
  float* sA     = (float*)alloc((size_t)NK*16*4);
  float* tbuf   = (float*)alloc((size_t)NK*16*4);
  float* deg    = (float*)alloc((size_t)NK*4);
  float* acc    = (float*)alloc((size_t)ACC_FLOATS*4);
  float* hh_g   = (float*)alloc((size_t)8192*4);

  k_init<<<256, 256, 0, stream>>>(csr_fill, node2k, tbuf, deg, acc);
  k_count<<<(NET+255)/256, 256, 0, stream>>>(ei, csr_fill);
  k_scan<<<1, 1024, 0, stream>>>(csr_fill, csr_ptr, csr_fill);
  k_fill<<<(NET+255)/256, 256, 0, stream>>>(ei, csr_fill, csr_src);
  k_embed<<<(NN*32+255)/256, 256, 0, stream>>>(x, node_emb, (float4*)h_a);

  float* hin = h_a; float* hout = h_b;
  for (int l=0;l<3;l++){
    k_gemm<<<dim3(NN/64, 512/64), 256, 0, stream>>>(hin, W[l], hfeat);
    k_attnsum<<<NN, 64, 0, stream>>>(hfeat, As_[l], Ad_[l], sum_s, sum_d);
    k_edges<<<(NN*NH+255)/256, 256, 0, stream>>>(csr_ptr, csr_src, sum_s, sum_d, alpha, inv_den);
    k_agg<<<NN, 128, 0, stream>>>(csr_ptr, csr_src, alpha, inv_den, hfeat, Bb[l], hout);
    float* tmp=hin; hin=hout; hout=tmp;
  }
  // hin = final node features
  k_sag<<<NN, 128, 0, stream>>>(csr_ptr, csr_src, hin, wrel, brel, wroot, score);
  k_topk<<<1, 1024, 0, stream>>>(score, sel);
  k_gatherx<<<NK, 128, 0, stream>>>(sel, score, hin, xp, node2k);
  k_assign<<<NK, 64, 0, stream>>>(xp, dmon_w, dmon_b, sA);
  k_edgepool<<<(NE+255)/256, 256, 0, stream>>>(ei, node2k, sA, tbuf, deg);
  k_pool<<<P_BLOCKS, 256, 0, stream>>>(sA, xp, tbuf, deg, acc);
  k_finloss<<<1, 256, 0, stream>>>(acc, dout);
  k_selu<<<8, 256, 0, stream>>>(acc);
  k_hh<<<32, 256, 0, stream>>>(acc, Wt, hh_g);
  k_head<<<1, 256, 0, stream>>>(hh_g, acc, att_s, att_d, btb, gate_w, gate_b,
                                trans_w, trans_b, task, task_emb, task_w, task_b,
                                fuse_w, fuse_b, out_w, out_b, dout);
}

// Round 4
// 745.213 us; speedup vs baseline: 1.5893x; 1.0670x over previous
//
#include <hip/hip_runtime.h>
#include <hip/hip_bf16.h>
#include <math.h>

// Problem constants
constexpr int NN  = 16000;          // nodes
constexpr int NE  = 256000;         // edges (original)
constexpr int NET = NE + NN;        // edges incl. self loops
constexpr int NK  = 4000;           // top-k
constexpr int NH  = 4;              // heads
constexpr int ND  = 128;            // dim
constexpr int NCL = 16;             // clusters

// acc buffer sub-offsets (floats)
constexpr int A_ADJ    = 0;     // 256  raw s^T adj s
constexpr int A_SS     = 256;   // 256  s^T s
constexpr int A_CSUM   = 512;   // 16   sum_n s[n,c]
constexpr int A_V      = 528;   // 16   sum_n s[n,c]*deg[n]
constexpr int A_DEGSUM = 544;   // 1
constexpr int A_OUTX   = 560;   // 2048 s^T xp (later selu'd in place)
constexpr int A_ADJN   = 2608;  // 256  normalized adjacency
constexpr int ACC_FLOATS = 3072;

__device__ inline unsigned fkey(float f){
  unsigned u = __float_as_uint(f);
  return (u & 0x80000000u) ? ~u : (u | 0x80000000u);
}

// ---------------- init ----------------
__global__ void k_init(int* cnt, int* node2k, float* tbuf, float* deg, float* acc){
  int i = blockIdx.x*blockDim.x + threadIdx.x;
  int stride = gridDim.x*blockDim.x;
  for (int j=i; j<NN; j+=stride){ cnt[j]=0; node2k[j]=-1; }
  for (int j=i; j<NK*NCL; j+=stride) tbuf[j]=0.f;
  for (int j=i; j<NK; j+=stride) deg[j]=0.f;
  for (int j=i; j<ACC_FLOATS; j+=stride) acc[j]=0.f;
}

// ---------------- CSR build ----------------
__global__ void k_count(const int* __restrict__ ei, int* __restrict__ cnt){
  int e = blockIdx.x*blockDim.x + threadIdx.x;
  if (e >= NET) return;
  int d = (e < NE) ? ei[NE+e] : (e-NE);
  atomicAdd(&cnt[d], 1);
}

// hierarchical scan: 16 elems/thread serial + one 1024-wide block scan
__global__ __launch_bounds__(1024) void k_scan(int* cnt, int* ptr, int* fill){
  __shared__ int sums[1024];
  int t = threadIdx.x;
  constexpr int PER = 16;            // 1024*16 = 16384 >= NN
  int base = t*PER;
  int v[PER];
  int run = 0;
  #pragma unroll
  for (int i=0;i<PER;i++){
    int idx = base+i;
    int c = (idx<NN)? cnt[idx] : 0;
    v[i] = run; run += c;
  }
  sums[t] = run;
  __syncthreads();
  for (int o=1;o<1024;o<<=1){
    int add = (t>=o)? sums[t-o] : 0;
    __syncthreads();
    sums[t] += add;
    __syncthreads();
  }
  int ex = sums[t] - run;
  #pragma unroll
  for (int i=0;i<PER;i++){
    int idx = base+i;
    if (idx<NN){ int p = ex+v[i]; ptr[idx]=p; fill[idx]=p; }
  }
  if (t==1023) ptr[NN]=sums[1023];
}

__global__ void k_fill(const int* __restrict__ ei, int* cur, int* csrc){
  int e = blockIdx.x*blockDim.x + threadIdx.x;
  if (e >= NET) return;
  int s, d;
  if (e < NE){ s = ei[e]; d = ei[NE+e]; } else { s = e-NE; d = e-NE; }
  int pos = atomicAdd(&cur[d], 1);
  csrc[pos] = s;
}

// ---------------- embedding ----------------
__global__ void k_embed(const int* __restrict__ x, const float* __restrict__ emb,
                        float4* __restrict__ h){
  int i = blockIdx.x*blockDim.x + threadIdx.x;
  if (i >= NN*32) return;
  int n = i >> 5, q = i & 31;
  h[i] = ((const float4*)emb)[(size_t)x[n]*32 + q];
}

// ---------------- per-layer attention-vector prep ----------------
// u_s[h][k] = sum_d a_s[h,d] * W[h*128+d, k]   (and same for a_d)
// usd layout: [0..511] = u_s (h*128+k), [512..1023] = u_d
__global__ __launch_bounds__(512) void k_prep(const float* __restrict__ W,
                                              const float* __restrict__ as_,
                                              const float* __restrict__ ad_,
                                              float* __restrict__ usd){
  int t = threadIdx.x;            // 512
  int h = t>>7, k = t&127;
  float ss=0.f, sd=0.f;
  for (int d=0; d<128; d++){
    float w = W[(size_t)(h*128+d)*128 + k];
    ss += as_[h*128+d]*w;
    sd += ad_[h*128+d]*w;
  }
  usd[t] = ss;
  usd[512+t] = sd;
}

// ---------------- attention logit sums: sum_s[n,h] = u_s[h]·h_n ----------------
__global__ void k_attnsum(const float* __restrict__ hin, const float* __restrict__ usd,
                          float* __restrict__ sum_s, float* __restrict__ sum_d){
  int n = blockIdx.x, lane = threadIdx.x;   // 64 threads
  const float* row = hin + (size_t)n*128;
  float x0 = row[lane], x1 = row[64+lane];
  for (int h=0;h<4;h++){
    float ps = x0*usd[h*128+lane]     + x1*usd[h*128+64+lane];
    float pd = x0*usd[512+h*128+lane] + x1*usd[512+h*128+64+lane];
    #pragma unroll
    for (int off=32; off>0; off>>=1){ ps += __shfl_down(ps,off); pd += __shfl_down(pd,off); }
    if (lane==0){ sum_s[n*4+h]=ps; sum_d[n*4+h]=pd; }
  }
}

// ---------------- edge softmax (per dst,head), 2 passes; scaling deferred ----------------
__global__ void k_edges(const int* __restrict__ ptr, const int* __restrict__ csrc,
                        const float* __restrict__ sum_s, const float* __restrict__ sum_d,
                        float* __restrict__ alpha, float* __restrict__ inv_den){
  int idx = blockIdx.x*blockDim.x + threadIdx.x;
  if (idx >= NN*NH) return;
  int n = idx >> 2, h = idx & 3;
  int b0 = ptr[n], b1 = ptr[n+1];
  float sd = sum_d[n*4+h];
  float mx = -1e30f;
  for (int j=b0;j<b1;j++){
    float v = sum_s[csrc[j]*4+h] + sd;
    v = v > 0.f ? v : 0.2f*v;
    alpha[(size_t)j*4+h] = v;
    mx = fmaxf(mx, v);
  }
  float den = 0.f;
  for (int j=b0;j<b1;j++){
    float e = __expf(alpha[(size_t)j*4+h] - mx);
    alpha[(size_t)j*4+h] = e;
    den += e;
  }
  inv_den[(size_t)n*4+h] = 1.f/(den + 1e-16f);
}

// ---------------- input-space aggregation: agg[n,h*128+t] = 0.25*idv_h*Σ_j α_jh h_src[t] ----
__global__ void k_agg(const int* __restrict__ ptr, const int* __restrict__ csrc,
                      const float* __restrict__ alpha, const float* __restrict__ inv_den,
                      const float* __restrict__ hin, float* __restrict__ agg){
  int n = blockIdx.x; int t = threadIdx.x;  // 128 threads
  int b0 = ptr[n], b1 = ptr[n+1];
  float a0=0.f, a1=0.f, a2=0.f, a3=0.f;
  for (int j=b0;j<b1;j++){
    int s = csrc[j];
    float4 al = *(const float4*)&alpha[(size_t)j*4];
    float v = hin[(size_t)s*128 + t];
    a0 += al.x*v; a1 += al.y*v; a2 += al.z*v; a3 += al.w*v;
  }
  float4 idv = *(const float4*)&inv_den[(size_t)n*4];
  float* o = agg + (size_t)n*512;
  o[t]     = 0.25f*idv.x*a0;
  o[128+t] = 0.25f*idv.y*a1;
  o[256+t] = 0.25f*idv.z*a2;
  o[384+t] = 0.25f*idv.w*a3;
}

// ---------------- head-transform GEMM: hout[n,d] = relu(Σ_{h,k} W[h*128+d,k]·agg[n,h*128+k] + b[d]) ----
// C[16000,128] = A[16000,512] @ B2^T, B2[d, h*128+k] = W[h*128+d, k]
__global__ __launch_bounds__(256) void k_gemm(const float* __restrict__ A,
                                              const float* __restrict__ W,
                                              const float* __restrict__ bias,
                                              float* __restrict__ C){
  __shared__ float As[64*68];
  __shared__ float Bs[64*68];
  int tid = threadIdx.x;
  int m0 = blockIdx.x*64, n0 = blockIdx.y*64;
  int ty = tid>>4, tx = tid&15;
  float cacc[4][4] = {};
  for (int kk=0; kk<512; kk+=64){
    int h = kk>>7, kb = kk&127;
    #pragma unroll
    for (int i=0;i<4;i++){
      int idx = tid + i*256;       // 0..1023
      int r = idx>>4, q = idx&15;  // row, float4-col
      float4 av = *(const float4*)&A[(size_t)(m0+r)*512 + kk + q*4];
      float* da = &As[r*68 + q*4];
      da[0]=av.x; da[1]=av.y; da[2]=av.z; da[3]=av.w;
      // B2[n0+r, kk+q*4 ..] = W[h*128 + n0 + r, kb + q*4 ..]
      float4 bv = *(const float4*)&W[(size_t)(h*128 + n0 + r)*128 + kb + q*4];
      float* db = &Bs[r*68 + q*4];
      db[0]=bv.x; db[1]=bv.y; db[2]=bv.z; db[3]=bv.w;
    }
    __syncthreads();
    #pragma unroll 4
    for (int k=0;k<64;k+=4){
      float4 b0 = *(const float4*)&Bs[(tx    )*68 + k];
      float4 b1 = *(const float4*)&Bs[(tx+16 )*68 + k];
      float4 b2 = *(const float4*)&Bs[(tx+32 )*68 + k];
      float4 b3 = *(const float4*)&Bs[(tx+48 )*68 + k];
      #pragma unroll
      for (int i=0;i<4;i++){
        float4 a = *(const float4*)&As[(ty+16*i)*68 + k];
        cacc[i][0] += a.x*b0.x + a.y*b0.y + a.z*b0.z + a.w*b0.w;
        cacc[i][1] += a.x*b1.x + a.y*b1.y + a.z*b1.z + a.w*b1.w;
        cacc[i][2] += a.x*b2.x + a.y*b2.y + a.z*b2.z + a.w*b2.w;
        cacc[i][3] += a.x*b3.x + a.y*b3.y + a.z*b3.z + a.w*b3.w;
      }
    }
    __syncthreads();
  }
  #pragma unroll
  for (int i=0;i<4;i++)
    #pragma unroll
    for (int j=0;j<4;j++){
      int d = n0+tx+16*j;
      C[(size_t)(m0+ty+16*i)*128 + d] = fmaxf(cacc[i][j] + bias[d], 0.f);
    }
}

// ---------------- SAG score ----------------
__global__ void k_sag(const int* __restrict__ ptr, const int* __restrict__ csrc,
                      const float* __restrict__ h, const float* __restrict__ wrel,
                      const float* __restrict__ brel, const float* __restrict__ wroot,
                      float* __restrict__ score){
  int n = blockIdx.x; int t = threadIdx.x; // 128
  int b0 = ptr[n], b1 = ptr[n+1];
  float agg = 0.f;
  for (int j=b0;j<b1;j++){
    int s = csrc[j];
    if (s != n) agg += h[(size_t)s*128 + t];   // skip the added self loop
  }
  float part = agg*wrel[t] + h[(size_t)n*128+t]*wroot[t];
  #pragma unroll
  for (int o=32;o>0;o>>=1) part += __shfl_down(part, o);
  __shared__ float r2[2];
  if ((t&63)==0) r2[t>>6]=part;
  __syncthreads();
  if (t==0) score[n] = r2[0]+r2[1]+brel[0];
}

// ---------------- fused single-block radix top-k ----------------
__global__ __launch_bounds__(1024) void k_topk(const float* __restrict__ score,
                                               int* __restrict__ sel){
  __shared__ int hist[256];
  __shared__ unsigned sh_prefix;
  __shared__ int sh_rem;
  __shared__ int cntGT, cntEQ;
  __shared__ int ties[256];
  int t = threadIdx.x;
  if (t==0){ sh_prefix=0u; sh_rem=NK; cntGT=0; cntEQ=0; }
  __syncthreads();
  for (int p=0;p<4;p++){
    int shift = 24-8*p;
    if (t<256) hist[t]=0;
    __syncthreads();
    unsigned prefix = sh_prefix;
    for (int i=t;i<NN;i+=1024){
      unsigned u = fkey(score[i]);
      bool ok = (p==0) || ((u>>(shift+8)) == (prefix>>(shift+8)));
      if (ok) atomicAdd(&hist[(u>>shift)&255],1);
    }
    __syncthreads();
    if (t==0){
      int rem = sh_rem;
      unsigned pre = sh_prefix;
      for (int b=255;b>=0;b--){
        int c=hist[b];
        if (rem>c) rem-=c; else { pre |= ((unsigned)b)<<shift; break; }
      }
      sh_rem=rem; sh_prefix=pre;
    }
    __syncthreads();
  }
  unsigned Tu = sh_prefix;
  for (int i=t;i<NN;i+=1024){
    unsigned u = fkey(score[i]);
    if (u>Tu){ int p2=atomicAdd(&cntGT,1); sel[p2]=i; }
    else if (u==Tu){ int p2=atomicAdd(&cntEQ,1); if (p2<256) ties[p2]=i; }
  }
  __syncthreads();
  if (t==0){
    int base=cntGT, rem=sh_rem, nt=min(cntEQ,256);
    for (int r=0;r<rem;r++){
      int best=0x7fffffff, bi=-1;
      for (int q=0;q<nt;q++){ int v=ties[q]; if (v>=0 && v<best){best=v;bi=q;} }
      sel[base+r] = (bi>=0)? best : 0;
      if (bi>=0) ties[bi]=-1;
    }
  }
}

// ---------------- xp gather + node2k ----------------
__global__ void k_gatherx(const int* __restrict__ sel, const float* __restrict__ score,
                          const float* __restrict__ h, float* __restrict__ xp,
                          int* __restrict__ node2k){
  int k = blockIdx.x; int t = threadIdx.x; // 128
  int n = sel[k];
  if (t==0) node2k[n] = k;
  float g = tanhf(score[n]);
  xp[(size_t)k*128+t] = h[(size_t)n*128+t]*g;
}

// ---------------- DMoN assignment softmax ----------------
__global__ void k_assign(const float* __restrict__ xp, const float* __restrict__ dw,
                         const float* __restrict__ db, float* __restrict__ sA){
  int k = blockIdx.x; int lane = threadIdx.x; // 64
  __shared__ float logits[16];
  float x0 = xp[(size_t)k*128+lane], x1 = xp[(size_t)k*128+64+lane];
  for (int c=0;c<16;c++){
    float p = x0*dw[c*128+lane] + x1*dw[c*128+64+lane];
    #pragma unroll
    for (int off=32;off>0;off>>=1) p += __shfl_down(p,off);
    if (lane==0) logits[c] = p + db[c];
  }
  __syncthreads();
  if (lane<16){
    float mx=-1e30f;
    for (int c=0;c<16;c++) mx = fmaxf(mx, logits[c]);
    float s=0.f;
    for (int c=0;c<16;c++) s += __expf(logits[c]-mx);
    sA[(size_t)k*16+lane] = __expf(logits[lane]-mx)/s;
  }
}

// ---------------- pooled adjacency: t[ni,:] += s[nj,:], deg[nj]+=1 ----------------
__global__ void k_edgepool(const int* __restrict__ ei, const int* __restrict__ node2k,
                           const float* __restrict__ sA, float* __restrict__ tbuf,
                           float* __restrict__ deg){
  int e = blockIdx.x*blockDim.x + threadIdx.x;
  if (e >= NE) return;
  int ni = node2k[ei[e]];
  int nj = node2k[ei[NE+e]];
  if (ni >= 0 && nj >= 0){
    atomicAdd(&deg[nj], 1.f);
    const float* sr = &sA[(size_t)nj*16];
    float* tr = &tbuf[(size_t)ni*16];
    #pragma unroll
    for (int c=0;c<16;c++) atomicAdd(&tr[c], sr[c]);
  }
}

// ---------------- fused pooled reductions ----------------
constexpr int P_BLOCKS = 32;
constexpr int P_ROWS   = NK / P_BLOCKS;   // 125
constexpr int P_CHUNK  = 25;

__global__ __launch_bounds__(256) void k_pool(const float* __restrict__ sA,
                                              const float* __restrict__ xp,
                                              const float* __restrict__ tb,
                                              const float* __restrict__ deg,
                                              float* __restrict__ acc){
  __shared__ float sv[P_CHUNK*16];
  __shared__ float tv[P_CHUNK*16];
  __shared__ float dv[P_CHUNK];
  __shared__ float xv[P_CHUNK*128];
  int t = threadIdx.x;
  int c = t>>4, d = t&15;
  float loc[8] = {0,0,0,0,0,0,0,0};
  float a_adj=0.f, a_ss=0.f, a_cs=0.f, a_v=0.f, a_dg=0.f;
  int r0 = blockIdx.x*P_ROWS;
  for (int ch=0; ch<P_ROWS; ch+=P_CHUNK){
    int base = r0+ch;
    for (int i=t;i<P_CHUNK*16;i+=256){
      sv[i] = sA[(size_t)(base+(i>>4))*16 + (i&15)];
      tv[i] = tb[(size_t)(base+(i>>4))*16 + (i&15)];
    }
    for (int i=t;i<P_CHUNK*128;i+=256)
      xv[i] = xp[(size_t)(base+(i>>7))*128 + (i&127)];
    if (t<P_CHUNK) dv[t]=deg[base+t];
    __syncthreads();
    for (int r=0;r<P_CHUNK;r++){
      float sc = sv[r*16+c];
      a_adj += sc*tv[r*16+d];
      a_ss  += sc*sv[r*16+d];
      if (d==0){ a_cs += sc; a_v += sc*dv[r]; }
      if (t==0) a_dg += dv[r];
      #pragma unroll
      for (int j=0;j<8;j++){
        int o=t+j*256;
        loc[j] += sv[r*16+(o>>7)]*xv[r*128+(o&127)];
      }
    }
    __syncthreads();
  }
  atomicAdd(&acc[A_ADJ + t], a_adj);
  atomicAdd(&acc[A_SS + t], a_ss);
  if (d==0){ atomicAdd(&acc[A_CSUM+c], a_cs); atomicAdd(&acc[A_V+c], a_v); }
  if (t==0) atomicAdd(&acc[A_DEGSUM], a_dg);
  #pragma unroll
  for (int j=0;j<8;j++) atomicAdd(&acc[A_OUTX + t + j*256], loc[j]);
}

__device__ float block_sum_256(float v, float* red){
  int t = threadIdx.x;
  red[t]=v; __syncthreads();
  #pragma unroll
  for (int o=128;o>0;o>>=1){ if (t<o) red[t]+=red[t+o]; __syncthreads(); }
  float r = red[0]; __syncthreads();
  return r;
}

// ---------------- losses + normalized adjacency ----------------
__global__ __launch_bounds__(256) void k_finloss(float* __restrict__ acc, float* __restrict__ dout){
  __shared__ float red[256];
  __shared__ float dsv[16];
  int t = threadIdx.x;
  int c = t>>4, dcol = t&15;
  float m = 0.5f*acc[A_DEGSUM];
  float ssv = acc[A_SS+t];
  float tr    = block_sum_256((t<16)? acc[A_ADJ + t*16 + t] : 0.f, red);
  float sumv2 = block_sum_256((t<16)? acc[A_V+t]*acc[A_V+t] : 0.f, red);
  float ss2   = block_sum_256(ssv*ssv, red);
  float cs2   = block_sum_256((t<16)? acc[A_CSUM+t]*acc[A_CSUM+t] : 0.f, red);
  float ssn = sqrtf(ss2);
  float term = ssv/ssn - ((c==dcol)? 0.25f : 0.f);
  float ortho2 = block_sum_256(term*term, red);
  if (t==0){
    float spectral = -(tr - sumv2/(2.f*m))/(2.f*m);
    float ortho = sqrtf(ortho2);
    float cluster = sqrtf(cs2)/(float)NK*4.f - 1.f;
    dout[1] = spectral + ortho + cluster;
  }
  // normalized adjacency
  float z = (c==dcol)? 0.f : acc[A_ADJ+t];
  red[t]=z; __syncthreads();
  for (int o=8;o>0;o>>=1){ if (dcol<o) red[t]+=red[t+o]; __syncthreads(); }
  if (dcol==0) dsv[c]=sqrtf(red[c*16])+1e-15f;
  __syncthreads();
  acc[A_ADJN+t] = z/(dsv[c]*dsv[dcol]);
}

// ---------------- selu on out_x ----------------
__global__ void k_selu(float* __restrict__ acc){
  int i = blockIdx.x*blockDim.x + threadIdx.x;
  if (i >= 2048) return;
  float x = acc[A_OUTX+i];
  float s = (x > 0.f)? x : 1.6732632423543772f*expm1f(x);
  acc[A_OUTX+i] = 1.0507009873554805f*s;
}

// ---------------- hh = selu(out_x) @ Wt^T ----------------
__global__ void k_hh(const float* __restrict__ acc, const float* __restrict__ Wt,
                     float* __restrict__ hh){
  int of = blockIdx.x*256 + threadIdx.x; // 0..8191
  int c = of >> 9, o = of & 511;
  const float* sx = acc + A_OUTX + c*128;
  const float* w = Wt + (size_t)o*128;
  float s=0.f;
  for (int k=0;k<128;k++) s += sx[k]*w[k];
  hh[of] = s;
}

// ---------------- dense GAT head + readout ----------------
__global__ __launch_bounds__(256) void k_head(
    const float* __restrict__ hh_g, const float* __restrict__ acc,
    const float* __restrict__ att_s, const float* __restrict__ att_d,
    const float* __restrict__ bt, const float* __restrict__ gate_w,
    const float* __restrict__ gate_b, const float* __restrict__ trans_w,
    const float* __restrict__ trans_b, const int* __restrict__ task,
    const float* __restrict__ task_emb, const float* __restrict__ task_w,
    const float* __restrict__ task_b, const float* __restrict__ fuse_w,
    const float* __restrict__ fuse_b, const float* __restrict__ out_w,
    const float* __restrict__ out_b, float* __restrict__ dout){
  __shared__ float hh[8192];
  __shared__ float al[1024];     // [i][j][h] = [(i*16+j)*4+h]
  __shared__ float asrc[64], adst[64];
  __shared__ float dg[2048];
  __shared__ float gate[16];
  __shared__ float gvec[128];
  __shared__ float ro[128], te[128], fu[128];
  __shared__ float red[256];
  int t = threadIdx.x;
  for (int i=t;i<8192;i+=256) hh[i]=hh_g[i];
  __syncthreads();
  if (t<128){
    int j = t>>3; int h = (t>>1)&3; int w = t&1;
    const float* hr = &hh[j*512 + h*128];
    const float* a = (w? att_d : att_s) + h*128;
    float s=0.f;
    for (int k2=0;k2<128;k2++) s += hr[k2]*a[k2];
    if (w) adst[j*4+h]=s; else asrc[j*4+h]=s;
  }
  __syncthreads();
  for (int idx=t; idx<1024; idx+=256){
    int h = idx&3, j=(idx>>2)&15, i=idx>>6;
    float v = asrc[j*4+h] + adst[i*4+h];
    v = v>0.f? v : 0.2f*v;
    float adjl = (i==j)? 1.f : acc[A_ADJN + i*16+j];
    al[idx] = (adjl==0.f)? -1e30f : v;
  }
  __syncthreads();
  if (t<64){
    int i=t>>2, h=t&3;
    float mx=-1e30f;
    for (int j=0;j<16;j++) mx = fmaxf(mx, al[(i*16+j)*4+h]);
    float sum=0.f;
    for (int j=0;j<16;j++){ float e=__expf(al[(i*16+j)*4+h]-mx); al[(i*16+j)*4+h]=e; sum+=e; }
    float inv = 1.f/sum;
    for (int j=0;j<16;j++) al[(i*16+j)*4+h]*=inv;
  }
  __syncthreads();
  for (int idx=t; idx<2048; idx+=256){
    int i=idx>>7, d=idx&127;
    float s=0.f;
    for (int h=0;h<4;h++)
      for (int j=0;j<16;j++)
        s += al[(i*16+j)*4+h]*hh[j*512+h*128+d];
    dg[idx] = fmaxf(0.25f*s + bt[d], 0.f);
  }
  __syncthreads();
  if (t<16){
    float s=0.f;
    for (int d2=0;d2<128;d2++) s += dg[t*128+d2]*gate_w[d2];
    red[t] = s + gate_b[0];
  }
  __syncthreads();
  if (t<16){
    float mx=-1e30f; for (int i=0;i<16;i++) mx=fmaxf(mx,red[i]);
    float s=0.f; for (int i=0;i<16;i++) s+=__expf(red[i]-mx);
    gate[t]=__expf(red[t]-mx)/s;
  }
  __syncthreads();
  if (t<128){
    float s=0.f;
    for (int i=0;i<16;i++) s += gate[i]*dg[i*128+t];
    gvec[t]=s;
  }
  __syncthreads();
  if (t<128){
    float s=0.f;
    for (int k2=0;k2<128;k2++) s += gvec[k2]*trans_w[t*128+k2];
    ro[t]=s+trans_b[t];
    int tk = task[0];
    float s2=0.f;
    for (int k2=0;k2<128;k2++) s2 += task_emb[(size_t)tk*128+k2]*task_w[t*128+k2];
    te[t]=fmaxf(s2+task_b[t],0.f);
  }
  __syncthreads();
  if (t<128){
    float s=0.f;
    for (int k2=0;k2<128;k2++) s += ro[k2]*fuse_w[t*256+k2] + te[k2]*fuse_w[t*256+128+k2];
    fu[t]=fmaxf(s+fuse_b[t],0.f);
  }
  __syncthreads();
  float v = (t<128)? fu[t]*out_w[t] : 0.f;
  red[t]=v; __syncthreads();
  for (int o=128;o>0;o>>=1){ if (t<o) red[t]+=red[t+o]; __syncthreads(); }
  if (t==0) dout[0]=red[0]+out_b[0];
}

// ================= launcher =================
extern "C" void kernel_launch(void* const* d_in, const int* in_sizes, int n_in,
                              void* d_out, int out_size, void* d_ws, size_t ws_size,
                              hipStream_t stream){
  const int* x        = (const int*)d_in[0];
  const int* ei       = (const int*)d_in[1];
  const int* task     = (const int*)d_in[3];
  const float* node_emb = (const float*)d_in[4];
  const float* task_emb = (const float*)d_in[5];
  const float* W[3]  = {(const float*)d_in[6],  (const float*)d_in[10], (const float*)d_in[14]};
  const float* As_[3]= {(const float*)d_in[7],  (const float*)d_in[11], (const float*)d_in[15]};
  const float* Ad_[3]= {(const float*)d_in[8],  (const float*)d_in[12], (const float*)d_in[16]};
  const float* Bb[3] = {(const float*)d_in[9],  (const float*)d_in[13], (const float*)d_in[17]};
  const float* wrel  = (const float*)d_in[18];
  const float* brel  = (const float*)d_in[19];
  const float* wroot = (const float*)d_in[20];
  const float* dmon_w= (const float*)d_in[21];
  const float* dmon_b= (const float*)d_in[22];
  const float* Wt    = (const float*)d_in[23];
  const float* att_s = (const float*)d_in[24];
  const float* att_d = (const float*)d_in[25];
  const float* btb   = (const float*)d_in[26];
  const float* gate_w= (const float*)d_in[27];
  const float* gate_b= (const float*)d_in[28];
  const float* trans_w=(const float*)d_in[29];
  const float* trans_b=(const float*)d_in[30];
  const float* task_w= (const float*)d_in[31];
  const float* task_b= (const float*)d_in[32];
  const float* fuse_w= (const float*)d_in[33];
  const float* fuse_b= (const float*)d_in[34];
  const float* out_w = (const float*)d_in[35];
  const float* out_b = (const float*)d_in[36];
  float* dout = (float*)d_out;
  (void)in_sizes; (void)n_in; (void)out_size; (void)ws_size;

  char* base = (char*)d_ws;
  size_t off = 0;
  auto alloc = [&](size_t bytes)->char*{
    off = (off + 255) & ~(size_t)255;
    char* r = base + off; off += bytes; return r;
  };
  int* csr_ptr  = (int*)alloc((size_t)(NN+1)*4);
  int* csr_fill = (int*)alloc((size_t)NN*4);
  int* csr_src  = (int*)alloc((size_t)NET*4);
  int* sel      = (int*)alloc((size_t)NK*4);
  int* node2k   = (int*)alloc((size_t)NN*4);
  float* score  = (float*)alloc((size_t)NN*4);
  float* h_a    = (float*)alloc((size_t)NN*128*4);
  float* h_b    = (float*)alloc((size_t)NN*128*4);
  float* aggbuf = (float*)alloc((size_t)NN*512*4);
  float* usd    = (float*)alloc((size_t)1024*4);
  float* sum_s  = (float*)alloc((size_t)NN*4*4);
  float* sum_d  = (float*)alloc((size_t)NN*4*4);
  float* inv_den= (float*)alloc((size_t)NN*4*4);
  float* alpha  = (float*)alloc((size_t)NET*4*4);
  float* xp     = (float*)alloc((size_t)NK*128*4);
  float* sA     = (float*)alloc((size_t)NK*16*4);
  float* tbuf   = (float*)alloc((size_t)NK*16*4);
  float* deg    = (float*)alloc((size_t)NK*4);
  float* acc    = (float*)alloc((size_t)ACC_FLOATS*4);
  float* hh_g   = (float*)alloc((size_t)8192*4);

  k_init<<<256, 256, 0, stream>>>(csr_fill, node2k, tbuf, deg, acc);
  k_count<<<(NET+255)/256, 256, 0, stream>>>(ei, csr_fill);
  k_scan<<<1, 1024, 0, stream>>>(csr_fill, csr_ptr, csr_fill);
  k_fill<<<(NET+255)/256, 256, 0, stream>>>(ei, csr_fill, csr_src);
  k_embed<<<(NN*32+255)/256, 256, 0, stream>>>(x, node_emb, (float4*)h_a);

  float* hin = h_a; float* hout = h_b;
  for (int l=0;l<3;l++){
    k_prep<<<1, 512, 0, stream>>>(W[l], As_[l], Ad_[l], usd);
    k_attnsum<<<NN, 64, 0, stream>>>(hin, usd, sum_s, sum_d);
    k_edges<<<(NN*NH+255)/256, 256, 0, stream>>>(csr_ptr, csr_src, sum_s, sum_d, alpha, inv_den);
    k_agg<<<NN, 128, 0, stream>>>(csr_ptr, csr_src, alpha, inv_den, hin, aggbuf);
    k_gemm<<<dim3(NN/64, 2), 256, 0, stream>>>(aggbuf, W[l], Bb[l], hout);
    float* tmp=hin; hin=hout; hout=tmp;
  }
  // hin = final node features
  k_sag<<<NN, 128, 0, stream>>>(csr_ptr, csr_src, hin, wrel, brel, wroot, score);
  k_topk<<<1, 1024, 0, stream>>>(score, sel);
  k_gatherx<<<NK, 128, 0, stream>>>(sel, score, hin, xp, node2k);
  k_assign<<<NK, 64, 0, stream>>>(xp, dmon_w, dmon_b, sA);
  k_edgepool<<<(NE+255)/256, 256, 0, stream>>>(ei, node2k, sA, tbuf, deg);
  k_pool<<<P_BLOCKS, 256, 0, stream>>>(sA, xp, tbuf, deg, acc);
  k_finloss<<<1, 256, 0, stream>>>(acc, dout);
  k_selu<<<8, 256, 0, stream>>>(acc);
  k_hh<<<32, 256, 0, stream>>>(acc, Wt, hh_g);
  k_head<<<1, 256, 0, stream>>>(hh_g, acc, att_s, att_d, btb, gate_w, gate_b,
                                trans_w, trans_b, task, task_emb, task_w, task_b,
                                fuse_w, fuse_b, out_w, out_b, dout);
}

// Round 5
// 738.010 us; speedup vs baseline: 1.6048x; 1.0098x over previous
//
#include <hip/hip_runtime.h>
#include <hip/hip_bf16.h>
#include <math.h>

// Problem constants
constexpr int NN  = 16000;          // nodes
constexpr int NE  = 256000;         // edges (original)
constexpr int NET = NE + NN;        // edges incl. self loops
constexpr int NK  = 4000;           // top-k
constexpr int NH  = 4;              // heads
constexpr int ND  = 128;            // dim
constexpr int NCL = 16;             // clusters

// acc buffer sub-offsets (floats)
constexpr int A_ADJ    = 0;     // 256  raw s^T adj s
constexpr int A_SS     = 256;   // 256  s^T s
constexpr int A_CSUM   = 512;   // 16   sum_n s[n,c]
constexpr int A_V      = 528;   // 16   sum_n s[n,c]*deg[n]
constexpr int A_DEGSUM = 544;   // 1
constexpr int A_OUTX   = 560;   // 2048 s^T xp (later selu'd in place)
constexpr int A_ADJN   = 2608;  // 256  normalized adjacency
constexpr int ACC_FLOATS = 3072;

__device__ inline unsigned fkey(float f){
  unsigned u = __float_as_uint(f);
  return (u & 0x80000000u) ? ~u : (u | 0x80000000u);
}

// ---------------- init ----------------
__global__ void k_init(int* cnt, int* node2k, float* tbuf, float* deg, float* acc){
  int i = blockIdx.x*blockDim.x + threadIdx.x;
  int stride = gridDim.x*blockDim.x;
  for (int j=i; j<NN; j+=stride){ cnt[j]=0; node2k[j]=-1; }
  for (int j=i; j<NK*NCL; j+=stride) tbuf[j]=0.f;
  for (int j=i; j<NK; j+=stride) deg[j]=0.f;
  for (int j=i; j<ACC_FLOATS; j+=stride) acc[j]=0.f;
}

// ---------------- CSR build ----------------
__global__ void k_count(const int* __restrict__ ei, int* __restrict__ cnt){
  int e = blockIdx.x*blockDim.x + threadIdx.x;
  if (e >= NET) return;
  int d = (e < NE) ? ei[NE+e] : (e-NE);
  atomicAdd(&cnt[d], 1);
}

// hierarchical scan: 16 elems/thread serial + one 1024-wide block scan
__global__ __launch_bounds__(1024) void k_scan(int* cnt, int* ptr, int* fill){
  __shared__ int sums[1024];
  int t = threadIdx.x;
  constexpr int PER = 16;            // 1024*16 = 16384 >= NN
  int base = t*PER;
  int v[PER];
  int run = 0;
  #pragma unroll
  for (int i=0;i<PER;i++){
    int idx = base+i;
    int c = (idx<NN)? cnt[idx] : 0;
    v[i] = run; run += c;
  }
  sums[t] = run;
  __syncthreads();
  for (int o=1;o<1024;o<<=1){
    int add = (t>=o)? sums[t-o] : 0;
    __syncthreads();
    sums[t] += add;
    __syncthreads();
  }
  int ex = sums[t] - run;
  #pragma unroll
  for (int i=0;i<PER;i++){
    int idx = base+i;
    if (idx<NN){ int p = ex+v[i]; ptr[idx]=p; fill[idx]=p; }
  }
  if (t==1023) ptr[NN]=sums[1023];
}

__global__ void k_fill(const int* __restrict__ ei, int* cur, int* csrc){
  int e = blockIdx.x*blockDim.x + threadIdx.x;
  if (e >= NET) return;
  int s, d;
  if (e < NE){ s = ei[e]; d = ei[NE+e]; } else { s = e-NE; d = e-NE; }
  int pos = atomicAdd(&cur[d], 1);
  csrc[pos] = s;
}

// ---------------- embedding ----------------
__global__ void k_embed(const int* __restrict__ x, const float* __restrict__ emb,
                        float4* __restrict__ h){
  int i = blockIdx.x*blockDim.x + threadIdx.x;
  if (i >= NN*32) return;
  int n = i >> 5, q = i & 31;
  h[i] = ((const float4*)emb)[(size_t)x[n]*32 + q];
}

// ---------------- per-layer attention-vector prep ----------------
// u_s[h][k] = sum_d a_s[h,d] * W[h*128+d, k]   (and same for a_d)
__global__ __launch_bounds__(512) void k_prep(const float* __restrict__ W,
                                              const float* __restrict__ as_,
                                              const float* __restrict__ ad_,
                                              float* __restrict__ usd){
  int t = threadIdx.x;            // 512
  int h = t>>7, k = t&127;
  float ss=0.f, sd=0.f;
  for (int d=0; d<128; d++){
    float w = W[(size_t)(h*128+d)*128 + k];
    ss += as_[h*128+d]*w;
    sd += ad_[h*128+d]*w;
  }
  usd[t] = ss;
  usd[512+t] = sd;
}

// ---------------- attention logit sums: sum_s[n,h] = u_s[h]·h_n ----------------
__global__ void k_attnsum(const float* __restrict__ hin, const float* __restrict__ usd,
                          float* __restrict__ sum_s, float* __restrict__ sum_d){
  int n = blockIdx.x, lane = threadIdx.x;   // 64 threads
  const float* row = hin + (size_t)n*128;
  float x0 = row[lane], x1 = row[64+lane];
  for (int h=0;h<4;h++){
    float ps = x0*usd[h*128+lane]     + x1*usd[h*128+64+lane];
    float pd = x0*usd[512+h*128+lane] + x1*usd[512+h*128+64+lane];
    #pragma unroll
    for (int off=32; off>0; off>>=1){ ps += __shfl_down(ps,off); pd += __shfl_down(pd,off); }
    if (lane==0){ sum_s[n*4+h]=ps; sum_d[n*4+h]=pd; }
  }
}

// ---------------- edge softmax (per dst,head), 2 passes; scaling deferred ----------------
__global__ void k_edges(const int* __restrict__ ptr, const int* __restrict__ csrc,
                        const float* __restrict__ sum_s, const float* __restrict__ sum_d,
                        float* __restrict__ alpha, float* __restrict__ inv_den){
  int idx = blockIdx.x*blockDim.x + threadIdx.x;
  if (idx >= NN*NH) return;
  int n = idx >> 2, h = idx & 3;
  int b0 = ptr[n], b1 = ptr[n+1];
  float sd = sum_d[n*4+h];
  float mx = -1e30f;
  for (int j=b0;j<b1;j++){
    float v = sum_s[csrc[j]*4+h] + sd;
    v = v > 0.f ? v : 0.2f*v;
    alpha[(size_t)j*4+h] = v;
    mx = fmaxf(mx, v);
  }
  float den = 0.f;
  for (int j=b0;j<b1;j++){
    float e = __expf(alpha[(size_t)j*4+h] - mx);
    alpha[(size_t)j*4+h] = e;
    den += e;
  }
  inv_den[(size_t)n*4+h] = 1.f/(den + 1e-16f);
}

// ---------------- input-space aggregation ----------------
__global__ void k_agg(const int* __restrict__ ptr, const int* __restrict__ csrc,
                      const float* __restrict__ alpha, const float* __restrict__ inv_den,
                      const float* __restrict__ hin, float* __restrict__ agg){
  int n = blockIdx.x; int t = threadIdx.x;  // 128 threads
  int b0 = ptr[n], b1 = ptr[n+1];
  float a0=0.f, a1=0.f, a2=0.f, a3=0.f;
  for (int j=b0;j<b1;j++){
    int s = csrc[j];
    float4 al = *(const float4*)&alpha[(size_t)j*4];
    float v = hin[(size_t)s*128 + t];
    a0 += al.x*v; a1 += al.y*v; a2 += al.z*v; a3 += al.w*v;
  }
  float4 idv = *(const float4*)&inv_den[(size_t)n*4];
  float* o = agg + (size_t)n*512;
  o[t]     = 0.25f*idv.x*a0;
  o[128+t] = 0.25f*idv.y*a1;
  o[256+t] = 0.25f*idv.z*a2;
  o[384+t] = 0.25f*idv.w*a3;
}

// ---------------- head-transform GEMM ----------------
__global__ __launch_bounds__(256) void k_gemm(const float* __restrict__ A,
                                              const float* __restrict__ W,
                                              const float* __restrict__ bias,
                                              float* __restrict__ C){
  __shared__ float As[64*68];
  __shared__ float Bs[64*68];
  int tid = threadIdx.x;
  int m0 = blockIdx.x*64, n0 = blockIdx.y*64;
  int ty = tid>>4, tx = tid&15;
  float cacc[4][4] = {};
  for (int kk=0; kk<512; kk+=64){
    int h = kk>>7, kb = kk&127;
    #pragma unroll
    for (int i=0;i<4;i++){
      int idx = tid + i*256;       // 0..1023
      int r = idx>>4, q = idx&15;  // row, float4-col
      float4 av = *(const float4*)&A[(size_t)(m0+r)*512 + kk + q*4];
      float* da = &As[r*68 + q*4];
      da[0]=av.x; da[1]=av.y; da[2]=av.z; da[3]=av.w;
      float4 bv = *(const float4*)&W[(size_t)(h*128 + n0 + r)*128 + kb + q*4];
      float* db = &Bs[r*68 + q*4];
      db[0]=bv.x; db[1]=bv.y; db[2]=bv.z; db[3]=bv.w;
    }
    __syncthreads();
    #pragma unroll 4
    for (int k=0;k<64;k+=4){
      float4 b0 = *(const float4*)&Bs[(tx    )*68 + k];
      float4 b1 = *(const float4*)&Bs[(tx+16 )*68 + k];
      float4 b2 = *(const float4*)&Bs[(tx+32 )*68 + k];
      float4 b3 = *(const float4*)&Bs[(tx+48 )*68 + k];
      #pragma unroll
      for (int i=0;i<4;i++){
        float4 a = *(const float4*)&As[(ty+16*i)*68 + k];
        cacc[i][0] += a.x*b0.x + a.y*b0.y + a.z*b0.z + a.w*b0.w;
        cacc[i][1] += a.x*b1.x + a.y*b1.y + a.z*b1.z + a.w*b1.w;
        cacc[i][2] += a.x*b2.x + a.y*b2.y + a.z*b2.z + a.w*b2.w;
        cacc[i][3] += a.x*b3.x + a.y*b3.y + a.z*b3.z + a.w*b3.w;
      }
    }
    __syncthreads();
  }
  #pragma unroll
  for (int i=0;i<4;i++)
    #pragma unroll
    for (int j=0;j<4;j++){
      int d = n0+tx+16*j;
      C[(size_t)(m0+ty+16*i)*128 + d] = fmaxf(cacc[i][j] + bias[d], 0.f);
    }
}

// ---------------- SAG score (algebraic: scalar per node) ----------------
__global__ void k_pq(const float* __restrict__ h, const float* __restrict__ wrel,
                     const float* __restrict__ wroot, float* __restrict__ p,
                     float* __restrict__ q){
  int n = blockIdx.x; int lane = threadIdx.x; // 64
  const float* row = h+(size_t)n*128;
  float a = row[lane]*wrel[lane] + row[64+lane]*wrel[64+lane];
  float b = row[lane]*wroot[lane] + row[64+lane]*wroot[64+lane];
  #pragma unroll
  for (int o=32;o>0;o>>=1){ a += __shfl_down(a,o); b += __shfl_down(b,o); }
  if (lane==0){ p[n]=a; q[n]=b; }
}

__global__ void k_sagscore(const int* __restrict__ ptr, const int* __restrict__ csrc,
                           const float* __restrict__ p, const float* __restrict__ q,
                           const float* __restrict__ brel, float* __restrict__ score){
  int n = blockIdx.x*blockDim.x + threadIdx.x;
  if (n >= NN) return;
  int b0=ptr[n], b1=ptr[n+1];
  float s=0.f;
  for (int j=b0;j<b1;j++){ int sj=csrc[j]; if (sj!=n) s+=p[sj]; }
  score[n] = s + q[n] + brel[0];
}

// ---------------- fused single-block radix top-k, wave-aggregated atomics ----------------
__global__ __launch_bounds__(1024) void k_topk(const float* __restrict__ score,
                                               int* __restrict__ sel){
  __shared__ int hist[8*257];     // 8 padded replicas (stride 257 -> bank-spread)
  __shared__ int hmerge[256];
  __shared__ unsigned sh_prefix;
  __shared__ int sh_rem;
  __shared__ int cntGT, cntEQ;
  __shared__ int ties[256];
  int t = threadIdx.x;
  int lane = t & 63;
  int rep = t >> 7;               // 0..7 (2 waves per replica)
  if (t==0){ sh_prefix=0u; sh_rem=NK; cntGT=0; cntEQ=0; }
  __syncthreads();
  for (int p=0;p<4;p++){
    int shift = 24-8*p;
    for (int i=t;i<8*257;i+=1024) hist[i]=0;
    __syncthreads();
    unsigned prefix = sh_prefix;
    for (int i=t;i<NN;i+=1024){
      unsigned u = fkey(score[i]);
      bool ok = (p==0) || ((u>>(shift+8)) == (prefix>>(shift+8)));
      int b = (int)((u>>shift)&255u);
      unsigned long long act = __ballot(ok);
      if (act){
        int leader = (int)(__ffsll((long long)act)-1);
        int bl = __shfl(b, leader);
        unsigned long long same = __ballot(ok && b==bl);
        if (same==act){
          // whole-wave same bin (dominant case): one atomic per wave
          if (lane==leader) atomicAdd(&hist[rep*257+bl], (int)__popcll(act));
        } else if (ok){
          atomicAdd(&hist[rep*257+b], 1);
        }
      }
    }
    __syncthreads();
    if (t<256){
      int v=0;
      #pragma unroll
      for (int r=0;r<8;r++) v += hist[r*257+t];
      hmerge[t]=v;
    }
    __syncthreads();
    if (t==0){
      int rem = sh_rem;
      unsigned pre = sh_prefix;
      for (int b=255;b>=0;b--){
        int c=hmerge[b];
        if (rem>c) rem-=c; else { pre |= ((unsigned)b)<<shift; break; }
      }
      sh_rem=rem; sh_prefix=pre;
    }
    __syncthreads();
  }
  unsigned Tu = sh_prefix;
  for (int i=t;i<NN;i+=1024){
    unsigned u = fkey(score[i]);
    bool g = (u>Tu), e = (u==Tu);
    unsigned long long mg = __ballot(g);
    if (mg){
      int leader = (int)(__ffsll((long long)mg)-1);
      int base = 0;
      if (lane==leader) base = atomicAdd(&cntGT, (int)__popcll(mg));
      base = __shfl(base, leader);
      if (g){
        int pos = base + (int)__popcll(mg & ((1ull<<lane)-1ull));
        sel[pos] = i;
      }
    }
    unsigned long long me = __ballot(e);
    if (me){
      int leader = (int)(__ffsll((long long)me)-1);
      int base = 0;
      if (lane==leader) base = atomicAdd(&cntEQ, (int)__popcll(me));
      base = __shfl(base, leader);
      if (e){
        int pos = base + (int)__popcll(me & ((1ull<<lane)-1ull));
        if (pos<256) ties[pos] = i;
      }
    }
  }
  __syncthreads();
  if (t==0){
    int base=cntGT, rem=sh_rem, nt=min(cntEQ,256);
    for (int r=0;r<rem;r++){
      int best=0x7fffffff, bi=-1;
      for (int q2=0;q2<nt;q2++){ int v=ties[q2]; if (v>=0 && v<best){best=v;bi=q2;} }
      sel[base+r] = (bi>=0)? best : 0;
      if (bi>=0) ties[bi]=-1;
    }
  }
}

// ---------------- xp gather + node2k ----------------
__global__ void k_gatherx(const int* __restrict__ sel, const float* __restrict__ score,
                          const float* __restrict__ h, float* __restrict__ xp,
                          int* __restrict__ node2k){
  int k = blockIdx.x; int t = threadIdx.x; // 128
  int n = sel[k];
  if (t==0) node2k[n] = k;
  float g = tanhf(score[n]);
  xp[(size_t)k*128+t] = h[(size_t)n*128+t]*g;
}

// ---------------- DMoN assignment softmax ----------------
__global__ void k_assign(const float* __restrict__ xp, const float* __restrict__ dw,
                         const float* __restrict__ db, float* __restrict__ sA){
  int k = blockIdx.x; int lane = threadIdx.x; // 64
  __shared__ float logits[16];
  float x0 = xp[(size_t)k*128+lane], x1 = xp[(size_t)k*128+64+lane];
  for (int c=0;c<16;c++){
    float p = x0*dw[c*128+lane] + x1*dw[c*128+64+lane];
    #pragma unroll
    for (int off=32;off>0;off>>=1) p += __shfl_down(p,off);
    if (lane==0) logits[c] = p + db[c];
  }
  __syncthreads();
  if (lane<16){
    float mx=-1e30f;
    for (int c=0;c<16;c++) mx = fmaxf(mx, logits[c]);
    float s=0.f;
    for (int c=0;c<16;c++) s += __expf(logits[c]-mx);
    sA[(size_t)k*16+lane] = __expf(logits[lane]-mx)/s;
  }
}

// ---------------- pooled adjacency: t[ni,:] += s[nj,:], deg[nj]+=1 ----------------
__global__ void k_edgepool(const int* __restrict__ ei, const int* __restrict__ node2k,
                           const float* __restrict__ sA, float* __restrict__ tbuf,
                           float* __restrict__ deg){
  int e = blockIdx.x*blockDim.x + threadIdx.x;
  if (e >= NE) return;
  int ni = node2k[ei[e]];
  int nj = node2k[ei[NE+e]];
  if (ni >= 0 && nj >= 0){
    atomicAdd(&deg[nj], 1.f);
    const float* sr = &sA[(size_t)nj*16];
    float* tr = &tbuf[(size_t)ni*16];
    #pragma unroll
    for (int c=0;c<16;c++) atomicAdd(&tr[c], sr[c]);
  }
}

// ---------------- fused pooled reductions ----------------
constexpr int P_BLOCKS = 32;
constexpr int P_ROWS   = NK / P_BLOCKS;   // 125
constexpr int P_CHUNK  = 25;

__global__ __launch_bounds__(256) void k_pool(const float* __restrict__ sA,
                                              const float* __restrict__ xp,
                                              const float* __restrict__ tb,
                                              const float* __restrict__ deg,
                                              float* __restrict__ acc){
  __shared__ float sv[P_CHUNK*16];
  __shared__ float tv[P_CHUNK*16];
  __shared__ float dv[P_CHUNK];
  __shared__ float xv[P_CHUNK*128];
  int t = threadIdx.x;
  int c = t>>4, d = t&15;
  float loc[8] = {0,0,0,0,0,0,0,0};
  float a_adj=0.f, a_ss=0.f, a_cs=0.f, a_v=0.f, a_dg=0.f;
  int r0 = blockIdx.x*P_ROWS;
  for (int ch=0; ch<P_ROWS; ch+=P_CHUNK){
    int base = r0+ch;
    for (int i=t;i<P_CHUNK*16;i+=256){
      sv[i] = sA[(size_t)(base+(i>>4))*16 + (i&15)];
      tv[i] = tb[(size_t)(base+(i>>4))*16 + (i&15)];
    }
    for (int i=t;i<P_CHUNK*128;i+=256)
      xv[i] = xp[(size_t)(base+(i>>7))*128 + (i&127)];
    if (t<P_CHUNK) dv[t]=deg[base+t];
    __syncthreads();
    for (int r=0;r<P_CHUNK;r++){
      float sc = sv[r*16+c];
      a_adj += sc*tv[r*16+d];
      a_ss  += sc*sv[r*16+d];
      if (d==0){ a_cs += sc; a_v += sc*dv[r]; }
      if (t==0) a_dg += dv[r];
      #pragma unroll
      for (int j=0;j<8;j++){
        int o=t+j*256;
        loc[j] += sv[r*16+(o>>7)]*xv[r*128+(o&127)];
      }
    }
    __syncthreads();
  }
  atomicAdd(&acc[A_ADJ + t], a_adj);
  atomicAdd(&acc[A_SS + t], a_ss);
  if (d==0){ atomicAdd(&acc[A_CSUM+c], a_cs); atomicAdd(&acc[A_V+c], a_v); }
  if (t==0) atomicAdd(&acc[A_DEGSUM], a_dg);
  #pragma unroll
  for (int j=0;j<8;j++) atomicAdd(&acc[A_OUTX + t + j*256], loc[j]);
}

__device__ float block_sum_256(float v, float* red){
  int t = threadIdx.x;
  red[t]=v; __syncthreads();
  #pragma unroll
  for (int o=128;o>0;o>>=1){ if (t<o) red[t]+=red[t+o]; __syncthreads(); }
  float r = red[0]; __syncthreads();
  return r;
}

// ---------------- losses + normalized adjacency ----------------
__global__ __launch_bounds__(256) void k_finloss(float* __restrict__ acc, float* __restrict__ dout){
  __shared__ float red[256];
  __shared__ float dsv[16];
  int t = threadIdx.x;
  int c = t>>4, dcol = t&15;
  float m = 0.5f*acc[A_DEGSUM];
  float ssv = acc[A_SS+t];
  float tr    = block_sum_256((t<16)? acc[A_ADJ + t*16 + t] : 0.f, red);
  float sumv2 = block_sum_256((t<16)? acc[A_V+t]*acc[A_V+t] : 0.f, red);
  float ss2   = block_sum_256(ssv*ssv, red);
  float cs2   = block_sum_256((t<16)? acc[A_CSUM+t]*acc[A_CSUM+t] : 0.f, red);
  float ssn = sqrtf(ss2);
  float term = ssv/ssn - ((c==dcol)? 0.25f : 0.f);
  float ortho2 = block_sum_256(term*term, red);
  if (t==0){
    float spectral = -(tr - sumv2/(2.f*m))/(2.f*m);
    float ortho = sqrtf(ortho2);
    float cluster = sqrtf(cs2)/(float)NK*4.f - 1.f;
    dout[1] = spectral + ortho + cluster;
  }
  // normalized adjacency
  float z = (c==dcol)? 0.f : acc[A_ADJ+t];
  red[t]=z; __syncthreads();
  for (int o=8;o>0;o>>=1){ if (dcol<o) red[t]+=red[t+o]; __syncthreads(); }
  if (dcol==0) dsv[c]=sqrtf(red[c*16])+1e-15f;
  __syncthreads();
  acc[A_ADJN+t] = z/(dsv[c]*dsv[dcol]);
}

// ---------------- selu on out_x ----------------
__global__ void k_selu(float* __restrict__ acc){
  int i = blockIdx.x*blockDim.x + threadIdx.x;
  if (i >= 2048) return;
  float x = acc[A_OUTX+i];
  float s = (x > 0.f)? x : 1.6732632423543772f*expm1f(x);
  acc[A_OUTX+i] = 1.0507009873554805f*s;
}

// ---------------- hh = selu(out_x) @ Wt^T ----------------
__global__ void k_hh(const float* __restrict__ acc, const float* __restrict__ Wt,
                     float* __restrict__ hh){
  int of = blockIdx.x*256 + threadIdx.x; // 0..8191
  int c = of >> 9, o = of & 511;
  const float* sx = acc + A_OUTX + c*128;
  const float* w = Wt + (size_t)o*128;
  float s=0.f;
  for (int k=0;k<128;k++) s += sx[k]*w[k];
  hh[of] = s;
}

// ---------------- dense GAT head + readout ----------------
__global__ __launch_bounds__(256) void k_head(
    const float* __restrict__ hh_g, const float* __restrict__ acc,
    const float* __restrict__ att_s, const float* __restrict__ att_d,
    const float* __restrict__ bt, const float* __restrict__ gate_w,
    const float* __restrict__ gate_b, const float* __restrict__ trans_w,
    const float* __restrict__ trans_b, const int* __restrict__ task,
    const float* __restrict__ task_emb, const float* __restrict__ task_w,
    const float* __restrict__ task_b, const float* __restrict__ fuse_w,
    const float* __restrict__ fuse_b, const float* __restrict__ out_w,
    const float* __restrict__ out_b, float* __restrict__ dout){
  __shared__ float hh[8192];
  __shared__ float al[1024];     // [i][j][h] = [(i*16+j)*4+h]
  __shared__ float asrc[64], adst[64];
  __shared__ float dg[2048];
  __shared__ float gate[16];
  __shared__ float gvec[128];
  __shared__ float ro[128], te[128], fu[128];
  __shared__ float red[256];
  int t = threadIdx.x;
  for (int i=t;i<8192;i+=256) hh[i]=hh_g[i];
  __syncthreads();
  if (t<128){
    int j = t>>3; int h = (t>>1)&3; int w = t&1;
    const float* hr = &hh[j*512 + h*128];
    const float* a = (w? att_d : att_s) + h*128;
    float s=0.f;
    for (int k2=0;k2<128;k2++) s += hr[k2]*a[k2];
    if (w) adst[j*4+h]=s; else asrc[j*4+h]=s;
  }
  __syncthreads();
  for (int idx=t; idx<1024; idx+=256){
    int h = idx&3, j=(idx>>2)&15, i=idx>>6;
    float v = asrc[j*4+h] + adst[i*4+h];
    v = v>0.f? v : 0.2f*v;
    float adjl = (i==j)? 1.f : acc[A_ADJN + i*16+j];
    al[idx] = (adjl==0.f)? -1e30f : v;
  }
  __syncthreads();
  if (t<64){
    int i=t>>2, h=t&3;
    float mx=-1e30f;
    for (int j=0;j<16;j++) mx = fmaxf(mx, al[(i*16+j)*4+h]);
    float sum=0.f;
    for (int j=0;j<16;j++){ float e=__expf(al[(i*16+j)*4+h]-mx); al[(i*16+j)*4+h]=e; sum+=e; }
    float inv = 1.f/sum;
    for (int j=0;j<16;j++) al[(i*16+j)*4+h]*=inv;
  }
  __syncthreads();
  for (int idx=t; idx<2048; idx+=256){
    int i=idx>>7, d=idx&127;
    float s=0.f;
    for (int h=0;h<4;h++)
      for (int j=0;j<16;j++)
        s += al[(i*16+j)*4+h]*hh[j*512+h*128+d];
    dg[idx] = fmaxf(0.25f*s + bt[d], 0.f);
  }
  __syncthreads();
  if (t<16){
    float s=0.f;
    for (int d2=0;d2<128;d2++) s += dg[t*128+d2]*gate_w[d2];
    red[t] = s + gate_b[0];
  }
  __syncthreads();
  if (t<16){
    float mx=-1e30f; for (int i=0;i<16;i++) mx=fmaxf(mx,red[i]);
    float s=0.f; for (int i=0;i<16;i++) s+=__expf(red[i]-mx);
    gate[t]=__expf(red[t]-mx)/s;
  }
  __syncthreads();
  if (t<128){
    float s=0.f;
    for (int i=0;i<16;i++) s += gate[i]*dg[i*128+t];
    gvec[t]=s;
  }
  __syncthreads();
  if (t<128){
    float s=0.f;
    for (int k2=0;k2<128;k2++) s += gvec[k2]*trans_w[t*128+k2];
    ro[t]=s+trans_b[t];
    int tk = task[0];
    float s2=0.f;
    for (int k2=0;k2<128;k2++) s2 += task_emb[(size_t)tk*128+k2]*task_w[t*128+k2];
    te[t]=fmaxf(s2+task_b[t],0.f);
  }
  __syncthreads();
  if (t<128){
    float s=0.f;
    for (int k2=0;k2<128;k2++) s += ro[k2]*fuse_w[t*256+k2] + te[k2]*fuse_w[t*256+128+k2];
    fu[t]=fmaxf(s+fuse_b[t],0.f);
  }
  __syncthreads();
  float v = (t<128)? fu[t]*out_w[t] : 0.f;
  red[t]=v; __syncthreads();
  for (int o=128;o>0;o>>=1){ if (t<o) red[t]+=red[t+o]; __syncthreads(); }
  if (t==0) dout[0]=red[0]+out_b[0];
}

// ================= launcher =================
extern "C" void kernel_launch(void* const* d_in, const int* in_sizes, int n_in,
                              void* d_out, int out_size, void* d_ws, size_t ws_size,
                              hipStream_t stream){
  const int* x        = (const int*)d_in[0];
  const int* ei       = (const int*)d_in[1];
  const int* task     = (const int*)d_in[3];
  const float* node_emb = (const float*)d_in[4];
  const float* task_emb = (const float*)d_in[5];
  const float* W[3]  = {(const float*)d_in[6],  (const float*)d_in[10], (const float*)d_in[14]};
  const float* As_[3]= {(const float*)d_in[7],  (const float*)d_in[11], (const float*)d_in[15]};
  const float* Ad_[3]= {(const float*)d_in[8],  (const float*)d_in[12], (const float*)d_in[16]};
  const float* Bb[3] = {(const float*)d_in[9],  (const float*)d_in[13], (const float*)d_in[17]};
  const float* wrel  = (const float*)d_in[18];
  const float* brel  = (const float*)d_in[19];
  const float* wroot = (const float*)d_in[20];
  const float* dmon_w= (const float*)d_in[21];
  const float* dmon_b= (const float*)d_in[22];
  const float* Wt    = (const float*)d_in[23];
  const float* att_s = (const float*)d_in[24];
  const float* att_d = (const float*)d_in[25];
  const float* btb   = (const float*)d_in[26];
  const float* gate_w= (const float*)d_in[27];
  const float* gate_b= (const float*)d_in[28];
  const float* trans_w=(const float*)d_in[29];
  const float* trans_b=(const float*)d_in[30];
  const float* task_w= (const float*)d_in[31];
  const float* task_b= (const float*)d_in[32];
  const float* fuse_w= (const float*)d_in[33];
  const float* fuse_b= (const float*)d_in[34];
  const float* out_w = (const float*)d_in[35];
  const float* out_b = (const float*)d_in[36];
  float* dout = (float*)d_out;
  (void)in_sizes; (void)n_in; (void)out_size; (void)ws_size;

  char* base = (char*)d_ws;
  size_t off = 0;
  auto alloc = [&](size_t bytes)->char*{
    off = (off + 255) & ~(size_t)255;
    char* r = base + off; off += bytes; return r;
  };
  int* csr_ptr  = (int*)alloc((size_t)(NN+1)*4);
  int* csr_fill = (int*)alloc((size_t)NN*4);
  int* csr_src  = (int*)alloc((size_t)NET*4);
  int* sel      = (int*)alloc((size_t)NK*4);
  int* node2k   = (int*)alloc((size_t)NN*4);
  float* score  = (float*)alloc((size_t)NN*4);
  float* pbuf   = (float*)alloc((size_t)NN*4);
  float* qbuf   = (float*)alloc((size_t)NN*4);
  float* h_a    = (float*)alloc((size_t)NN*128*4);
  float* h_b    = (float*)alloc((size_t)NN*128*4);
  float* aggbuf = (float*)alloc((size_t)NN*512*4);
  float* usd    = (float*)alloc((size_t)1024*4);
  float* sum_s  = (float*)alloc((size_t)NN*4*4);
  float* sum_d  = (float*)alloc((size_t)NN*4*4);
  float* inv_den= (float*)alloc((size_t)NN*4*4);
  float* alpha  = (float*)alloc((size_t)NET*4*4);
  float* xp     = (float*)alloc((size_t)NK*128*4);
  float* sA     = (float*)alloc((size_t)NK*16*4);
  float* tbuf   = (float*)alloc((size_t)NK*16*4);
  float* deg    = (float*)alloc((size_t)NK*4);
  float* acc    = (float*)alloc((size_t)ACC_FLOATS*4);
  float* hh_g   = (float*)alloc((size_t)8192*4);

  k_init<<<256, 256, 0, stream>>>(csr_fill, node2k, tbuf, deg, acc);
  k_count<<<(NET+255)/256, 256, 0, stream>>>(ei, csr_fill);
  k_scan<<<1, 1024, 0, stream>>>(csr_fill, csr_ptr, csr_fill);
  k_fill<<<(NET+255)/256, 256, 0, stream>>>(ei, csr_fill, csr_src);
  k_embed<<<(NN*32+255)/256, 256, 0, stream>>>(x, node_emb, (float4*)h_a);

  float* hin = h_a; float* hout = h_b;
  for (int l=0;l<3;l++){
    k_prep<<<1, 512, 0, stream>>>(W[l], As_[l], Ad_[l], usd);
    k_attnsum<<<NN, 64, 0, stream>>>(hin, usd, sum_s, sum_d);
    k_edges<<<(NN*NH+255)/256, 256, 0, stream>>>(csr_ptr, csr_src, sum_s, sum_d, alpha, inv_den);
    k_agg<<<NN, 128, 0, stream>>>(csr_ptr, csr_src, alpha, inv_den, hin, aggbuf);
    k_gemm<<<dim3(NN/64, 2), 256, 0, stream>>>(aggbuf, W[l], Bb[l], hout);
    float* tmp=hin; hin=hout; hout=tmp;
  }
  // hin = final node features
  k_pq<<<NN, 64, 0, stream>>>(hin, wrel, wroot, pbuf, qbuf);
  k_sagscore<<<(NN+255)/256, 256, 0, stream>>>(csr_ptr, csr_src, pbuf, qbuf, brel, score);
  k_topk<<<1, 1024, 0, stream>>>(score, sel);
  k_gatherx<<<NK, 128, 0, stream>>>(sel, score, hin, xp, node2k);
  k_assign<<<NK, 64, 0, stream>>>(xp, dmon_w, dmon_b, sA);
  k_edgepool<<<(NE+255)/256, 256, 0, stream>>>(ei, node2k, sA, tbuf, deg);
  k_pool<<<P_BLOCKS, 256, 0, stream>>>(sA, xp, tbuf, deg, acc);
  k_finloss<<<1, 256, 0, stream>>>(acc, dout);
  k_selu<<<8, 256, 0, stream>>>(acc);
  k_hh<<<32, 256, 0, stream>>>(acc, Wt, hh_g);
  k_head<<<1, 256, 0, stream>>>(hh_g, acc, att_s, att_d, btb, gate_w, gate_b,
                                trans_w, trans_b, task, task_emb, task_w, task_b,
                                fuse_w, fuse_b, out_w, out_b, dout);
}

// Round 6
// 698.772 us; speedup vs baseline: 1.6949x; 1.0562x over previous
//
#include <hip/hip_runtime.h>
#include <hip/hip_bf16.h>
#include <math.h>

// Problem constants
constexpr int NN  = 16000;          // nodes
constexpr int NE  = 256000;         // edges (original)
constexpr int NET = NE + NN;        // edges incl. self loops
constexpr int NK  = 4000;           // top-k
constexpr int NH  = 4;              // heads
constexpr int ND  = 128;            // dim
constexpr int NCL = 16;             // clusters

// acc buffer sub-offsets (floats)
constexpr int A_ADJ    = 0;     // 256  raw s^T adj s
constexpr int A_SS     = 256;   // 256  s^T s
constexpr int A_CSUM   = 512;   // 16   sum_n s[n,c]
constexpr int A_V      = 528;   // 16   sum_n s[n,c]*deg[n]
constexpr int A_DEGSUM = 544;   // 1
constexpr int A_OUTX   = 560;   // 2048 s^T xp (selu'd in k_finloss)
constexpr int A_ADJN   = 2608;  // 256  normalized adjacency
constexpr int ACC_FLOATS = 3072;

__device__ inline unsigned fkey(float f){
  unsigned u = __float_as_uint(f);
  return (u & 0x80000000u) ? ~u : (u | 0x80000000u);
}

// ---------------- init ----------------
__global__ void k_init(int* cnt, int* node2k, float* tbuf, float* deg, float* acc){
  int i = blockIdx.x*blockDim.x + threadIdx.x;
  int stride = gridDim.x*blockDim.x;
  for (int j=i; j<NN; j+=stride){ cnt[j]=0; node2k[j]=-1; }
  for (int j=i; j<NK*NCL; j+=stride) tbuf[j]=0.f;
  for (int j=i; j<NK; j+=stride) deg[j]=0.f;
  for (int j=i; j<ACC_FLOATS; j+=stride) acc[j]=0.f;
}

// ---------------- CSR build ----------------
__global__ void k_count(const int* __restrict__ ei, int* __restrict__ cnt){
  int e = blockIdx.x*blockDim.x + threadIdx.x;
  if (e >= NET) return;
  int d = (e < NE) ? ei[NE+e] : (e-NE);
  atomicAdd(&cnt[d], 1);
}

// hierarchical scan: 16 elems/thread serial + one 1024-wide block scan
__global__ __launch_bounds__(1024) void k_scan(int* cnt, int* ptr, int* fill){
  __shared__ int sums[1024];
  int t = threadIdx.x;
  constexpr int PER = 16;            // 1024*16 = 16384 >= NN
  int base = t*PER;
  int v[PER];
  int run = 0;
  #pragma unroll
  for (int i=0;i<PER;i++){
    int idx = base+i;
    int c = (idx<NN)? cnt[idx] : 0;
    v[i] = run; run += c;
  }
  sums[t] = run;
  __syncthreads();
  for (int o=1;o<1024;o<<=1){
    int add = (t>=o)? sums[t-o] : 0;
    __syncthreads();
    sums[t] += add;
    __syncthreads();
  }
  int ex = sums[t] - run;
  #pragma unroll
  for (int i=0;i<PER;i++){
    int idx = base+i;
    if (idx<NN){ int p = ex+v[i]; ptr[idx]=p; fill[idx]=p; }
  }
  if (t==1023) ptr[NN]=sums[1023];
}

__global__ void k_fill(const int* __restrict__ ei, int* cur, int* csrc){
  int e = blockIdx.x*blockDim.x + threadIdx.x;
  if (e >= NET) return;
  int s, d;
  if (e < NE){ s = ei[e]; d = ei[NE+e]; } else { s = e-NE; d = e-NE; }
  int pos = atomicAdd(&cur[d], 1);
  csrc[pos] = s;
}

// ---------------- embedding ----------------
__global__ void k_embed(const int* __restrict__ x, const float* __restrict__ emb,
                        float4* __restrict__ h){
  int i = blockIdx.x*blockDim.x + threadIdx.x;
  if (i >= NN*32) return;
  int n = i >> 5, q = i & 31;
  h[i] = ((const float4*)emb)[(size_t)x[n]*32 + q];
}

// ---------------- per-layer attention-vector prep ----------------
__global__ __launch_bounds__(512) void k_prep(const float* __restrict__ W,
                                              const float* __restrict__ as_,
                                              const float* __restrict__ ad_,
                                              float* __restrict__ usd){
  int t = threadIdx.x;            // 512
  int h = t>>7, k = t&127;
  float ss=0.f, sd=0.f;
  for (int d=0; d<128; d++){
    float w = W[(size_t)(h*128+d)*128 + k];
    ss += as_[h*128+d]*w;
    sd += ad_[h*128+d]*w;
  }
  usd[t] = ss;
  usd[512+t] = sd;
}

// ---------------- attention logit sums ----------------
__global__ void k_attnsum(const float* __restrict__ hin, const float* __restrict__ usd,
                          float* __restrict__ sum_s, float* __restrict__ sum_d){
  int n = blockIdx.x, lane = threadIdx.x;   // 64 threads
  const float* row = hin + (size_t)n*128;
  float x0 = row[lane], x1 = row[64+lane];
  for (int h=0;h<4;h++){
    float ps = x0*usd[h*128+lane]     + x1*usd[h*128+64+lane];
    float pd = x0*usd[512+h*128+lane] + x1*usd[512+h*128+64+lane];
    #pragma unroll
    for (int off=32; off>0; off>>=1){ ps += __shfl_down(ps,off); pd += __shfl_down(pd,off); }
    if (lane==0){ sum_s[n*4+h]=ps; sum_d[n*4+h]=pd; }
  }
}

// ---------------- edge softmax (per dst,head) ----------------
__global__ void k_edges(const int* __restrict__ ptr, const int* __restrict__ csrc,
                        const float* __restrict__ sum_s, const float* __restrict__ sum_d,
                        float* __restrict__ alpha, float* __restrict__ inv_den){
  int idx = blockIdx.x*blockDim.x + threadIdx.x;
  if (idx >= NN*NH) return;
  int n = idx >> 2, h = idx & 3;
  int b0 = ptr[n], b1 = ptr[n+1];
  float sd = sum_d[n*4+h];
  float mx = -1e30f;
  for (int j=b0;j<b1;j++){
    float v = sum_s[csrc[j]*4+h] + sd;
    v = v > 0.f ? v : 0.2f*v;
    alpha[(size_t)j*4+h] = v;
    mx = fmaxf(mx, v);
  }
  float den = 0.f;
  for (int j=b0;j<b1;j++){
    float e = __expf(alpha[(size_t)j*4+h] - mx);
    alpha[(size_t)j*4+h] = e;
    den += e;
  }
  inv_den[(size_t)n*4+h] = 1.f/(den + 1e-16f);
}

// ---------------- input-space aggregation ----------------
__global__ void k_agg(const int* __restrict__ ptr, const int* __restrict__ csrc,
                      const float* __restrict__ alpha, const float* __restrict__ inv_den,
                      const float* __restrict__ hin, float* __restrict__ agg){
  int n = blockIdx.x; int t = threadIdx.x;  // 128 threads
  int b0 = ptr[n], b1 = ptr[n+1];
  float a0=0.f, a1=0.f, a2=0.f, a3=0.f;
  for (int j=b0;j<b1;j++){
    int s = csrc[j];
    float4 al = *(const float4*)&alpha[(size_t)j*4];
    float v = hin[(size_t)s*128 + t];
    a0 += al.x*v; a1 += al.y*v; a2 += al.z*v; a3 += al.w*v;
  }
  float4 idv = *(const float4*)&inv_den[(size_t)n*4];
  float* o = agg + (size_t)n*512;
  o[t]     = 0.25f*idv.x*a0;
  o[128+t] = 0.25f*idv.y*a1;
  o[256+t] = 0.25f*idv.z*a2;
  o[384+t] = 0.25f*idv.w*a3;
}

// ---------------- head-transform GEMM ----------------
__global__ __launch_bounds__(256) void k_gemm(const float* __restrict__ A,
                                              const float* __restrict__ W,
                                              const float* __restrict__ bias,
                                              float* __restrict__ C){
  __shared__ float As[64*68];
  __shared__ float Bs[64*68];
  int tid = threadIdx.x;
  int m0 = blockIdx.x*64, n0 = blockIdx.y*64;
  int ty = tid>>4, tx = tid&15;
  float cacc[4][4] = {};
  for (int kk=0; kk<512; kk+=64){
    int h = kk>>7, kb = kk&127;
    #pragma unroll
    for (int i=0;i<4;i++){
      int idx = tid + i*256;       // 0..1023
      int r = idx>>4, q = idx&15;  // row, float4-col
      float4 av = *(const float4*)&A[(size_t)(m0+r)*512 + kk + q*4];
      float* da = &As[r*68 + q*4];
      da[0]=av.x; da[1]=av.y; da[2]=av.z; da[3]=av.w;
      float4 bv = *(const float4*)&W[(size_t)(h*128 + n0 + r)*128 + kb + q*4];
      float* db = &Bs[r*68 + q*4];
      db[0]=bv.x; db[1]=bv.y; db[2]=bv.z; db[3]=bv.w;
    }
    __syncthreads();
    #pragma unroll 4
    for (int k=0;k<64;k+=4){
      float4 b0 = *(const float4*)&Bs[(tx    )*68 + k];
      float4 b1 = *(const float4*)&Bs[(tx+16 )*68 + k];
      float4 b2 = *(const float4*)&Bs[(tx+32 )*68 + k];
      float4 b3 = *(const float4*)&Bs[(tx+48 )*68 + k];
      #pragma unroll
      for (int i=0;i<4;i++){
        float4 a = *(const float4*)&As[(ty+16*i)*68 + k];
        cacc[i][0] += a.x*b0.x + a.y*b0.y + a.z*b0.z + a.w*b0.w;
        cacc[i][1] += a.x*b1.x + a.y*b1.y + a.z*b1.z + a.w*b1.w;
        cacc[i][2] += a.x*b2.x + a.y*b2.y + a.z*b2.z + a.w*b2.w;
        cacc[i][3] += a.x*b3.x + a.y*b3.y + a.z*b3.z + a.w*b3.w;
      }
    }
    __syncthreads();
  }
  #pragma unroll
  for (int i=0;i<4;i++)
    #pragma unroll
    for (int j=0;j<4;j++){
      int d = n0+tx+16*j;
      C[(size_t)(m0+ty+16*i)*128 + d] = fmaxf(cacc[i][j] + bias[d], 0.f);
    }
}

// ---------------- SAG score (algebraic: scalar per node) ----------------
__global__ void k_pq(const float* __restrict__ h, const float* __restrict__ wrel,
                     const float* __restrict__ wroot, float* __restrict__ p,
                     float* __restrict__ q){
  int n = blockIdx.x; int lane = threadIdx.x; // 64
  const float* row = h+(size_t)n*128;
  float a = row[lane]*wrel[lane] + row[64+lane]*wrel[64+lane];
  float b = row[lane]*wroot[lane] + row[64+lane]*wroot[64+lane];
  #pragma unroll
  for (int o=32;o>0;o>>=1){ a += __shfl_down(a,o); b += __shfl_down(b,o); }
  if (lane==0){ p[n]=a; q[n]=b; }
}

__global__ void k_sagscore(const int* __restrict__ ptr, const int* __restrict__ csrc,
                           const float* __restrict__ p, const float* __restrict__ q,
                           const float* __restrict__ brel, float* __restrict__ score){
  int n = blockIdx.x*blockDim.x + threadIdx.x;
  if (n >= NN) return;
  int b0=ptr[n], b1=ptr[n+1];
  float s=0.f;
  for (int j=b0;j<b1;j++){ int sj=csrc[j]; if (sj!=n) s+=p[sj]; }
  score[n] = s + q[n] + brel[0];
}

// ---------------- fused single-block radix top-k ----------------
// Keys register-resident (one global sweep); 4 histogram passes + select
// entirely from registers/LDS; wave-level suffix-scan threshold find.
__global__ __launch_bounds__(1024) void k_topk(const float* __restrict__ score,
                                               int* __restrict__ sel){
  __shared__ int hist[8*257];     // 8 padded replicas
  __shared__ int hmerge[256];
  __shared__ unsigned sh_prefix;
  __shared__ int sh_rem;
  __shared__ int cntGT, cntEQ;
  __shared__ int ties[256];
  int t = threadIdx.x;
  int lane = t & 63;
  int rep = t >> 7;               // 0..7
  unsigned keys[16];
  #pragma unroll
  for (int j=0;j<16;j++){
    int i = t + j*1024;
    keys[j] = (i<NN) ? fkey(score[i]) : 0u;   // phantom=0 never wins (real keys >> 0)
  }
  if (t==0){ sh_prefix=0u; sh_rem=NK; cntGT=0; cntEQ=0; }
  __syncthreads();
  for (int p=0;p<4;p++){
    int shift = 24-8*p;
    for (int i=t;i<8*257;i+=1024) hist[i]=0;
    __syncthreads();
    unsigned prefix = sh_prefix;
    #pragma unroll
    for (int j=0;j<16;j++){
      bool val = (j<15) || (t < (NN - 15*1024));
      unsigned u = keys[j];
      bool ok = val && ((p==0) || ((u>>(shift+8)) == (prefix>>(shift+8))));
      int b = (int)((u>>shift)&255u);
      unsigned long long act = __ballot(ok);
      if (act){
        int leader = (int)(__ffsll((long long)act)-1);
        int bl = __shfl(b, leader);
        unsigned long long same = __ballot(ok && b==bl);
        if (same==act){
          if (lane==leader) atomicAdd(&hist[rep*257+bl], (int)__popcll(act));
        } else if (ok){
          atomicAdd(&hist[rep*257+b], 1);
        }
      }
    }
    __syncthreads();
    if (t<256){
      int v=0;
      #pragma unroll
      for (int r=0;r<8;r++) v += hist[r*257+t];
      hmerge[t]=v;
    }
    __syncthreads();
    // wave 0: suffix scan over 256 bins (lane l owns bins [4*(63-l) .. +3])
    if (t<64){
      int l = t;
      int b0 = 4*(63-l);
      int c3 = hmerge[b0+3], c2 = hmerge[b0+2], c1 = hmerge[b0+1], c0 = hmerge[b0];
      int gs = c0+c1+c2+c3;
      int incl = gs;
      #pragma unroll
      for (int o=1;o<64;o<<=1){
        int v = __shfl_up(incl, o);
        if (l>=o) incl += v;
      }
      int excl = incl - gs;         // keys in bins above this group
      int rem = sh_rem;
      int rl = rem - excl;
      if (rl > 0 && rl <= gs){
        unsigned pre = sh_prefix;
        // walk bins descending within group
        if (rl > c3){ rl -= c3;
          if (rl > c2){ rl -= c2;
            if (rl > c1){ rl -= c1;
              sh_prefix = pre | ((unsigned)b0<<shift);     sh_rem = rl;
            } else { sh_prefix = pre | ((unsigned)(b0+1)<<shift); sh_rem = rl; }
          } else { sh_prefix = pre | ((unsigned)(b0+2)<<shift);   sh_rem = rl; }
        } else { sh_prefix = pre | ((unsigned)(b0+3)<<shift);     sh_rem = rl; }
      }
    }
    __syncthreads();
  }
  unsigned Tu = sh_prefix;
  #pragma unroll
  for (int j=0;j<16;j++){
    int i = t + j*1024;
    bool val = (i<NN);
    unsigned u = keys[j];
    bool g = val && (u>Tu), e = val && (u==Tu);
    unsigned long long mg = __ballot(g);
    if (mg){
      int leader = (int)(__ffsll((long long)mg)-1);
      int base = 0;
      if (lane==leader) base = atomicAdd(&cntGT, (int)__popcll(mg));
      base = __shfl(base, leader);
      if (g){
        int pos = base + (int)__popcll(mg & ((1ull<<lane)-1ull));
        sel[pos] = i;
      }
    }
    unsigned long long me = __ballot(e);
    if (me){
      int leader = (int)(__ffsll((long long)me)-1);
      int base = 0;
      if (lane==leader) base = atomicAdd(&cntEQ, (int)__popcll(me));
      base = __shfl(base, leader);
      if (e){
        int pos = base + (int)__popcll(me & ((1ull<<lane)-1ull));
        if (pos<256) ties[pos] = i;
      }
    }
  }
  __syncthreads();
  if (t==0){
    int base=cntGT, rem=sh_rem, nt=min(cntEQ,256);
    for (int r=0;r<rem;r++){
      int best=0x7fffffff, bi=-1;
      for (int q2=0;q2<nt;q2++){ int v=ties[q2]; if (v>=0 && v<best){best=v;bi=q2;} }
      sel[base+r] = (bi>=0)? best : 0;
      if (bi>=0) ties[bi]=-1;
    }
  }
}

// ---------------- xp gather + node2k ----------------
__global__ void k_gatherx(const int* __restrict__ sel, const float* __restrict__ score,
                          const float* __restrict__ h, float* __restrict__ xp,
                          int* __restrict__ node2k){
  int k = blockIdx.x; int t = threadIdx.x; // 128
  int n = sel[k];
  if (t==0) node2k[n] = k;
  float g = tanhf(score[n]);
  xp[(size_t)k*128+t] = h[(size_t)n*128+t]*g;
}

// ---------------- DMoN assignment softmax ----------------
__global__ void k_assign(const float* __restrict__ xp, const float* __restrict__ dw,
                         const float* __restrict__ db, float* __restrict__ sA){
  int k = blockIdx.x; int lane = threadIdx.x; // 64
  __shared__ float logits[16];
  float x0 = xp[(size_t)k*128+lane], x1 = xp[(size_t)k*128+64+lane];
  for (int c=0;c<16;c++){
    float p = x0*dw[c*128+lane] + x1*dw[c*128+64+lane];
    #pragma unroll
    for (int off=32;off>0;off>>=1) p += __shfl_down(p,off);
    if (lane==0) logits[c] = p + db[c];
  }
  __syncthreads();
  if (lane<16){
    float mx=-1e30f;
    for (int c=0;c<16;c++) mx = fmaxf(mx, logits[c]);
    float s=0.f;
    for (int c=0;c<16;c++) s += __expf(logits[c]-mx);
    sA[(size_t)k*16+lane] = __expf(logits[lane]-mx)/s;
  }
}

// ---------------- pooled adjacency ----------------
__global__ void k_edgepool(const int* __restrict__ ei, const int* __restrict__ node2k,
                           const float* __restrict__ sA, float* __restrict__ tbuf,
                           float* __restrict__ deg){
  int e = blockIdx.x*blockDim.x + threadIdx.x;
  if (e >= NE) return;
  int ni = node2k[ei[e]];
  int nj = node2k[ei[NE+e]];
  if (ni >= 0 && nj >= 0){
    atomicAdd(&deg[nj], 1.f);
    const float* sr = &sA[(size_t)nj*16];
    float* tr = &tbuf[(size_t)ni*16];
    #pragma unroll
    for (int c=0;c<16;c++) atomicAdd(&tr[c], sr[c]);
  }
}

// ---------------- fused pooled reductions ----------------
constexpr int P_BLOCKS = 32;
constexpr int P_ROWS   = NK / P_BLOCKS;   // 125
constexpr int P_CHUNK  = 25;

__global__ __launch_bounds__(256) void k_pool(const float* __restrict__ sA,
                                              const float* __restrict__ xp,
                                              const float* __restrict__ tb,
                                              const float* __restrict__ deg,
                                              float* __restrict__ acc){
  __shared__ float sv[P_CHUNK*16];
  __shared__ float tv[P_CHUNK*16];
  __shared__ float dv[P_CHUNK];
  __shared__ float xv[P_CHUNK*128];
  int t = threadIdx.x;
  int c = t>>4, d = t&15;
  float loc[8] = {0,0,0,0,0,0,0,0};
  float a_adj=0.f, a_ss=0.f, a_cs=0.f, a_v=0.f, a_dg=0.f;
  int r0 = blockIdx.x*P_ROWS;
  for (int ch=0; ch<P_ROWS; ch+=P_CHUNK){
    int base = r0+ch;
    for (int i=t;i<P_CHUNK*16;i+=256){
      sv[i] = sA[(size_t)(base+(i>>4))*16 + (i&15)];
      tv[i] = tb[(size_t)(base+(i>>4))*16 + (i&15)];
    }
    for (int i=t;i<P_CHUNK*128;i+=256)
      xv[i] = xp[(size_t)(base+(i>>7))*128 + (i&127)];
    if (t<P_CHUNK) dv[t]=deg[base+t];
    __syncthreads();
    for (int r=0;r<P_CHUNK;r++){
      float sc = sv[r*16+c];
      a_adj += sc*tv[r*16+d];
      a_ss  += sc*sv[r*16+d];
      if (d==0){ a_cs += sc; a_v += sc*dv[r]; }
      if (t==0) a_dg += dv[r];
      #pragma unroll
      for (int j=0;j<8;j++){
        int o=t+j*256;
        loc[j] += sv[r*16+(o>>7)]*xv[r*128+(o&127)];
      }
    }
    __syncthreads();
  }
  atomicAdd(&acc[A_ADJ + t], a_adj);
  atomicAdd(&acc[A_SS + t], a_ss);
  if (d==0){ atomicAdd(&acc[A_CSUM+c], a_cs); atomicAdd(&acc[A_V+c], a_v); }
  if (t==0) atomicAdd(&acc[A_DEGSUM], a_dg);
  #pragma unroll
  for (int j=0;j<8;j++) atomicAdd(&acc[A_OUTX + t + j*256], loc[j]);
}

__device__ float block_sum_256(float v, float* red){
  int t = threadIdx.x;
  red[t]=v; __syncthreads();
  #pragma unroll
  for (int o=128;o>0;o>>=1){ if (t<o) red[t]+=red[t+o]; __syncthreads(); }
  float r = red[0]; __syncthreads();
  return r;
}

// ---------------- losses + normalized adjacency + selu(out_x) ----------------
__global__ __launch_bounds__(256) void k_finloss(float* __restrict__ acc, float* __restrict__ dout){
  __shared__ float red[256];
  __shared__ float dsv[16];
  int t = threadIdx.x;
  int c = t>>4, dcol = t&15;
  float m = 0.5f*acc[A_DEGSUM];
  float ssv = acc[A_SS+t];
  float tr    = block_sum_256((t<16)? acc[A_ADJ + t*16 + t] : 0.f, red);
  float sumv2 = block_sum_256((t<16)? acc[A_V+t]*acc[A_V+t] : 0.f, red);
  float ss2   = block_sum_256(ssv*ssv, red);
  float cs2   = block_sum_256((t<16)? acc[A_CSUM+t]*acc[A_CSUM+t] : 0.f, red);
  float ssn = sqrtf(ss2);
  float term = ssv/ssn - ((c==dcol)? 0.25f : 0.f);
  float ortho2 = block_sum_256(term*term, red);
  if (t==0){
    float spectral = -(tr - sumv2/(2.f*m))/(2.f*m);
    float ortho = sqrtf(ortho2);
    float cluster = sqrtf(cs2)/(float)NK*4.f - 1.f;
    dout[1] = spectral + ortho + cluster;
  }
  // normalized adjacency
  float z = (c==dcol)? 0.f : acc[A_ADJ+t];
  red[t]=z; __syncthreads();
  for (int o=8;o>0;o>>=1){ if (dcol<o) red[t]+=red[t+o]; __syncthreads(); }
  if (dcol==0) dsv[c]=sqrtf(red[c*16])+1e-15f;
  __syncthreads();
  acc[A_ADJN+t] = z/(dsv[c]*dsv[dcol]);
  // selu on out_x (2048 elems, 8 per thread; disjoint, no sync needed)
  #pragma unroll
  for (int j=0;j<8;j++){
    int idx = t + j*256;
    float xv = acc[A_OUTX+idx];
    float s2 = (xv > 0.f)? xv : 1.6732632423543772f*expm1f(xv);
    acc[A_OUTX+idx] = 1.0507009873554805f*s2;
  }
}

// ---------------- hh = selu(out_x) @ Wt^T ----------------
__global__ void k_hh(const float* __restrict__ acc, const float* __restrict__ Wt,
                     float* __restrict__ hh){
  int of = blockIdx.x*256 + threadIdx.x; // 0..8191
  int c = of >> 9, o = of & 511;
  const float* sx = acc + A_OUTX + c*128;
  const float* w = Wt + (size_t)o*128;
  float s=0.f;
  for (int k=0;k<128;k++) s += sx[k]*w[k];
  hh[of] = s;
}

// ---------------- dense GAT head + readout ----------------
__global__ __launch_bounds__(256) void k_head(
    const float* __restrict__ hh_g, const float* __restrict__ acc,
    const float* __restrict__ att_s, const float* __restrict__ att_d,
    const float* __restrict__ bt, const float* __restrict__ gate_w,
    const float* __restrict__ gate_b, const float* __restrict__ trans_w,
    const float* __restrict__ trans_b, const int* __restrict__ task,
    const float* __restrict__ task_emb, const float* __restrict__ task_w,
    const float* __restrict__ task_b, const float* __restrict__ fuse_w,
    const float* __restrict__ fuse_b, const float* __restrict__ out_w,
    const float* __restrict__ out_b, float* __restrict__ dout){
  __shared__ float hh[8192];
  __shared__ float al[1024];     // [i][j][h]
  __shared__ float asrc[64], adst[64];
  __shared__ float dg[2048];
  __shared__ float gate[16];
  __shared__ float gvec[128];
  __shared__ float ro[128], te[128], fu[128];
  __shared__ float red[256];
  int t = threadIdx.x;
  for (int i=t;i<8192;i+=256) hh[i]=hh_g[i];
  __syncthreads();
  if (t<128){
    int j = t>>3; int h = (t>>1)&3; int w = t&1;
    const float* hr = &hh[j*512 + h*128];
    const float* a = (w? att_d : att_s) + h*128;
    float s=0.f;
    for (int k2=0;k2<128;k2++) s += hr[k2]*a[k2];
    if (w) adst[j*4+h]=s; else asrc[j*4+h]=s;
  }
  __syncthreads();
  for (int idx=t; idx<1024; idx+=256){
    int h = idx&3, j=(idx>>2)&15, i=idx>>6;
    float v = asrc[j*4+h] + adst[i*4+h];
    v = v>0.f? v : 0.2f*v;
    float adjl = (i==j)? 1.f : acc[A_ADJN + i*16+j];
    al[idx] = (adjl==0.f)? -1e30f : v;
  }
  __syncthreads();
  if (t<64){
    int i=t>>2, h=t&3;
    float mx=-1e30f;
    for (int j=0;j<16;j++) mx = fmaxf(mx, al[(i*16+j)*4+h]);
    float sum=0.f;
    for (int j=0;j<16;j++){ float e=__expf(al[(i*16+j)*4+h]-mx); al[(i*16+j)*4+h]=e; sum+=e; }
    float inv = 1.f/sum;
    for (int j=0;j<16;j++) al[(i*16+j)*4+h]*=inv;
  }
  __syncthreads();
  for (int idx=t; idx<2048; idx+=256){
    int i=idx>>7, d=idx&127;
    float s=0.f;
    for (int h=0;h<4;h++)
      for (int j=0;j<16;j++)
        s += al[(i*16+j)*4+h]*hh[j*512+h*128+d];
    dg[idx] = fmaxf(0.25f*s + bt[d], 0.f);
  }
  __syncthreads();
  if (t<16){
    float s=0.f;
    for (int d2=0;d2<128;d2++) s += dg[t*128+d2]*gate_w[d2];
    red[t] = s + gate_b[0];
  }
  __syncthreads();
  if (t<16){
    float mx=-1e30f; for (int i=0;i<16;i++) mx=fmaxf(mx,red[i]);
    float s=0.f; for (int i=0;i<16;i++) s+=__expf(red[i]-mx);
    gate[t]=__expf(red[t]-mx)/s;
  }
  __syncthreads();
  if (t<128){
    float s=0.f;
    for (int i=0;i<16;i++) s += gate[i]*dg[i*128+t];
    gvec[t]=s;
  }
  __syncthreads();
  if (t<128){
    float s=0.f;
    for (int k2=0;k2<128;k2++) s += gvec[k2]*trans_w[t*128+k2];
    ro[t]=s+trans_b[t];
    int tk = task[0];
    float s2=0.f;
    for (int k2=0;k2<128;k2++) s2 += task_emb[(size_t)tk*128+k2]*task_w[t*128+k2];
    te[t]=fmaxf(s2+task_b[t],0.f);
  }
  __syncthreads();
  if (t<128){
    float s=0.f;
    for (int k2=0;k2<128;k2++) s += ro[k2]*fuse_w[t*256+k2] + te[k2]*fuse_w[t*256+128+k2];
    fu[t]=fmaxf(s+fuse_b[t],0.f);
  }
  __syncthreads();
  float v = (t<128)? fu[t]*out_w[t] : 0.f;
  red[t]=v; __syncthreads();
  for (int o=128;o>0;o>>=1){ if (t<o) red[t]+=red[t+o]; __syncthreads(); }
  if (t==0) dout[0]=red[0]+out_b[0];
}

// ================= launcher =================
extern "C" void kernel_launch(void* const* d_in, const int* in_sizes, int n_in,
                              void* d_out, int out_size, void* d_ws, size_t ws_size,
                              hipStream_t stream){
  const int* x        = (const int*)d_in[0];
  const int* ei       = (const int*)d_in[1];
  const int* task     = (const int*)d_in[3];
  const float* node_emb = (const float*)d_in[4];
  const float* task_emb = (const float*)d_in[5];
  const float* W[3]  = {(const float*)d_in[6],  (const float*)d_in[10], (const float*)d_in[14]};
  const float* As_[3]= {(const float*)d_in[7],  (const float*)d_in[11], (const float*)d_in[15]};
  const float* Ad_[3]= {(const float*)d_in[8],  (const float*)d_in[12], (const float*)d_in[16]};
  const float* Bb[3] = {(const float*)d_in[9],  (const float*)d_in[13], (const float*)d_in[17]};
  const float* wrel  = (const float*)d_in[18];
  const float* brel  = (const float*)d_in[19];
  const float* wroot = (const float*)d_in[20];
  const float* dmon_w= (const float*)d_in[21];
  const float* dmon_b= (const float*)d_in[22];
  const float* Wt    = (const float*)d_in[23];
  const float* att_s = (const float*)d_in[24];
  const float* att_d = (const float*)d_in[25];
  const float* btb   = (const float*)d_in[26];
  const float* gate_w= (const float*)d_in[27];
  const float* gate_b= (const float*)d_in[28];
  const float* trans_w=(const float*)d_in[29];
  const float* trans_b=(const float*)d_in[30];
  const float* task_w= (const float*)d_in[31];
  const float* task_b= (const float*)d_in[32];
  const float* fuse_w= (const float*)d_in[33];
  const float* fuse_b= (const float*)d_in[34];
  const float* out_w = (const float*)d_in[35];
  const float* out_b = (const float*)d_in[36];
  float* dout = (float*)d_out;
  (void)in_sizes; (void)n_in; (void)out_size; (void)ws_size;

  char* base = (char*)d_ws;
  size_t off = 0;
  auto alloc = [&](size_t bytes)->char*{
    off = (off + 255) & ~(size_t)255;
    char* r = base + off; off += bytes; return r;
  };
  int* csr_ptr  = (int*)alloc((size_t)(NN+1)*4);
  int* csr_fill = (int*)alloc((size_t)NN*4);
  int* csr_src  = (int*)alloc((size_t)NET*4);
  int* sel      = (int*)alloc((size_t)NK*4);
  int* node2k   = (int*)alloc((size_t)NN*4);
  float* score  = (float*)alloc((size_t)NN*4);
  float* pbuf   = (float*)alloc((size_t)NN*4);
  float* qbuf   = (float*)alloc((size_t)NN*4);
  float* h_a    = (float*)alloc((size_t)NN*128*4);
  float* h_b    = (float*)alloc((size_t)NN*128*4);
  float* aggbuf = (float*)alloc((size_t)NN*512*4);
  float* usd    = (float*)alloc((size_t)1024*4);
  float* sum_s  = (float*)alloc((size_t)NN*4*4);
  float* sum_d  = (float*)alloc((size_t)NN*4*4);
  float* inv_den= (float*)alloc((size_t)NN*4*4);
  float* alpha  = (float*)alloc((size_t)NET*4*4);
  float* xp     = (float*)alloc((size_t)NK*128*4);
  float* sA     = (float*)alloc((size_t)NK*16*4);
  float* tbuf   = (float*)alloc((size_t)NK*16*4);
  float* deg    = (float*)alloc((size_t)NK*4);
  float* acc    = (float*)alloc((size_t)ACC_FLOATS*4);
  float* hh_g   = (float*)alloc((size_t)8192*4);

  k_init<<<256, 256, 0, stream>>>(csr_fill, node2k, tbuf, deg, acc);
  k_count<<<(NET+255)/256, 256, 0, stream>>>(ei, csr_fill);
  k_scan<<<1, 1024, 0, stream>>>(csr_fill, csr_ptr, csr_fill);
  k_fill<<<(NET+255)/256, 256, 0, stream>>>(ei, csr_fill, csr_src);
  k_embed<<<(NN*32+255)/256, 256, 0, stream>>>(x, node_emb, (float4*)h_a);

  float* hin = h_a; float* hout = h_b;
  for (int l=0;l<3;l++){
    k_prep<<<1, 512, 0, stream>>>(W[l], As_[l], Ad_[l], usd);
    k_attnsum<<<NN, 64, 0, stream>>>(hin, usd, sum_s, sum_d);
    k_edges<<<(NN*NH+255)/256, 256, 0, stream>>>(csr_ptr, csr_src, sum_s, sum_d, alpha, inv_den);
    k_agg<<<NN, 128, 0, stream>>>(csr_ptr, csr_src, alpha, inv_den, hin, aggbuf);
    k_gemm<<<dim3(NN/64, 2), 256, 0, stream>>>(aggbuf, W[l], Bb[l], hout);
    float* tmp=hin; hin=hout; hout=tmp;
  }
  // hin = final node features
  k_pq<<<NN, 64, 0, stream>>>(hin, wrel, wroot, pbuf, qbuf);
  k_sagscore<<<(NN+255)/256, 256, 0, stream>>>(csr_ptr, csr_src, pbuf, qbuf, brel, score);
  k_topk<<<1, 1024, 0, stream>>>(score, sel);
  k_gatherx<<<NK, 128, 0, stream>>>(sel, score, hin, xp, node2k);
  k_assign<<<NK, 64, 0, stream>>>(xp, dmon_w, dmon_b, sA);
  k_edgepool<<<(NE+255)/256, 256, 0, stream>>>(ei, node2k, sA, tbuf, deg);
  k_pool<<<P_BLOCKS, 256, 0, stream>>>(sA, xp, tbuf, deg, acc);
  k_finloss<<<1, 256, 0, stream>>>(acc, dout);
  k_hh<<<32, 256, 0, stream>>>(acc, Wt, hh_g);
  k_head<<<1, 256, 0, stream>>>(hh_g, acc, att_s, att_d, btb, gate_w, gate_b,
                                trans_w, trans_b, task, task_emb, task_w, task_b,
                                fuse_w, fuse_b, out_w, out_b, dout);
}

// Round 7
// 587.447 us; speedup vs baseline: 2.0161x; 1.1895x over previous
//
#include <hip/hip_runtime.h>
#include <hip/hip_bf16.h>
#include <math.h>

// Problem constants
constexpr int NN  = 16000;          // nodes
constexpr int NE  = 256000;         // edges (original)
constexpr int NET = NE + NN;        // edges incl. self loops
constexpr int NK  = 4000;           // top-k
constexpr int NH  = 4;              // heads
constexpr int ND  = 128;            // dim
constexpr int NCL = 16;             // clusters

// acc buffer sub-offsets (floats)
constexpr int A_ADJ    = 0;     // 256  raw s^T adj s
constexpr int A_SS     = 256;   // 256  s^T s
constexpr int A_CSUM   = 512;   // 16   sum_n s[n,c]
constexpr int A_V      = 528;   // 16   sum_n s[n,c]*deg[n]
constexpr int A_DEGSUM = 544;   // 1
constexpr int A_OUTX   = 560;   // 2048 s^T xp (selu'd in k_finloss)
constexpr int A_ADJN   = 2608;  // 256  normalized adjacency
constexpr int ACC_FLOATS = 3072;

typedef short sh8 __attribute__((ext_vector_type(8)));
typedef float f32x4 __attribute__((ext_vector_type(4)));

__device__ inline unsigned fkey(float f){
  unsigned u = __float_as_uint(f);
  return (u & 0x80000000u) ? ~u : (u | 0x80000000u);
}

__device__ inline unsigned short f2bf(float f){
  unsigned u = __float_as_uint(f);
  unsigned r = u + 0x7FFFu + ((u>>16)&1u);   // round-to-nearest-even
  return (unsigned short)(r>>16);
}

// ---------------- init ----------------
__global__ void k_init(int* cnt, int* node2k, float* tbuf, float* deg, float* acc){
  int i = blockIdx.x*blockDim.x + threadIdx.x;
  int stride = gridDim.x*blockDim.x;
  for (int j=i; j<NN; j+=stride){ cnt[j]=0; node2k[j]=-1; }
  for (int j=i; j<NK*NCL; j+=stride) tbuf[j]=0.f;
  for (int j=i; j<NK; j+=stride) deg[j]=0.f;
  for (int j=i; j<ACC_FLOATS; j+=stride) acc[j]=0.f;
}

// ---------------- CSR build ----------------
__global__ void k_count(const int* __restrict__ ei, int* __restrict__ cnt){
  int e = blockIdx.x*blockDim.x + threadIdx.x;
  if (e >= NET) return;
  int d = (e < NE) ? ei[NE+e] : (e-NE);
  atomicAdd(&cnt[d], 1);
}

// hierarchical scan: 16 elems/thread serial + one 1024-wide block scan
__global__ __launch_bounds__(1024) void k_scan(int* cnt, int* ptr, int* fill){
  __shared__ int sums[1024];
  int t = threadIdx.x;
  constexpr int PER = 16;            // 1024*16 = 16384 >= NN
  int base = t*PER;
  int v[PER];
  int run = 0;
  #pragma unroll
  for (int i=0;i<PER;i++){
    int idx = base+i;
    int c = (idx<NN)? cnt[idx] : 0;
    v[i] = run; run += c;
  }
  sums[t] = run;
  __syncthreads();
  for (int o=1;o<1024;o<<=1){
    int add = (t>=o)? sums[t-o] : 0;
    __syncthreads();
    sums[t] += add;
    __syncthreads();
  }
  int ex = sums[t] - run;
  #pragma unroll
  for (int i=0;i<PER;i++){
    int idx = base+i;
    if (idx<NN){ int p = ex+v[i]; ptr[idx]=p; fill[idx]=p; }
  }
  if (t==1023) ptr[NN]=sums[1023];
}

__global__ void k_fill(const int* __restrict__ ei, int* cur, int* csrc){
  int e = blockIdx.x*blockDim.x + threadIdx.x;
  if (e >= NET) return;
  int s, d;
  if (e < NE){ s = ei[e]; d = ei[NE+e]; } else { s = e-NE; d = e-NE; }
  int pos = atomicAdd(&cur[d], 1);
  csrc[pos] = s;
}

// ---------------- embedding ----------------
__global__ void k_embed(const int* __restrict__ x, const float* __restrict__ emb,
                        float4* __restrict__ h){
  int i = blockIdx.x*blockDim.x + threadIdx.x;
  if (i >= NN*32) return;
  int n = i >> 5, q = i & 31;
  h[i] = ((const float4*)emb)[(size_t)x[n]*32 + q];
}

// ---------------- per-layer attention-vector prep ----------------
__global__ __launch_bounds__(512) void k_prep(const float* __restrict__ W,
                                              const float* __restrict__ as_,
                                              const float* __restrict__ ad_,
                                              float* __restrict__ usd){
  int t = threadIdx.x;            // 512
  int h = t>>7, k = t&127;
  float ss=0.f, sd=0.f;
  for (int d=0; d<128; d++){
    float w = W[(size_t)(h*128+d)*128 + k];
    ss += as_[h*128+d]*w;
    sd += ad_[h*128+d]*w;
  }
  usd[t] = ss;
  usd[512+t] = sd;
}

// ---------------- pack W into MFMA-B-layout bf16 ----------------
// Blay[((c*16+kc)*64 + lane)*8 + j] = B2[d=c*16+(lane&15)][kk=kc*32+(lane>>4)*8+j]
// where B2[d][h*128+k] = W[h*128+d][k]
__global__ void k_prepw(const float* __restrict__ W, unsigned short* __restrict__ Blay){
  int idx = blockIdx.x*blockDim.x + threadIdx.x; // 8192
  if (idx >= 8192) return;
  int lane = idx&63, kc = (idx>>6)&15, c = idx>>10;
  int d = c*16 + (lane&15), q = lane>>4;
  sh8 v;
  #pragma unroll
  for (int j=0;j<8;j++){
    int kkg = kc*32 + q*8 + j;
    int h = kkg>>7, k = kkg&127;
    v[j] = (short)f2bf(W[(size_t)(h*128+d)*128 + k]);
  }
  *((sh8*)(Blay + (size_t)idx*8)) = v;
}

// ---------------- attention logit sums ----------------
__global__ void k_attnsum(const float* __restrict__ hin, const float* __restrict__ usd,
                          float* __restrict__ sum_s, float* __restrict__ sum_d){
  int n = blockIdx.x, lane = threadIdx.x;   // 64 threads
  const float* row = hin + (size_t)n*128;
  float x0 = row[lane], x1 = row[64+lane];
  for (int h=0;h<4;h++){
    float ps = x0*usd[h*128+lane]     + x1*usd[h*128+64+lane];
    float pd = x0*usd[512+h*128+lane] + x1*usd[512+h*128+64+lane];
    #pragma unroll
    for (int off=32; off>0; off>>=1){ ps += __shfl_down(ps,off); pd += __shfl_down(pd,off); }
    if (lane==0){ sum_s[n*4+h]=ps; sum_d[n*4+h]=pd; }
  }
}

// ---------------- edge softmax (per dst,head) ----------------
__global__ void k_edges(const int* __restrict__ ptr, const int* __restrict__ csrc,
                        const float* __restrict__ sum_s, const float* __restrict__ sum_d,
                        float* __restrict__ alpha, float* __restrict__ inv_den){
  int idx = blockIdx.x*blockDim.x + threadIdx.x;
  if (idx >= NN*NH) return;
  int n = idx >> 2, h = idx & 3;
  int b0 = ptr[n], b1 = ptr[n+1];
  float sd = sum_d[n*4+h];
  float mx = -1e30f;
  for (int j=b0;j<b1;j++){
    float v = sum_s[csrc[j]*4+h] + sd;
    v = v > 0.f ? v : 0.2f*v;
    alpha[(size_t)j*4+h] = v;
    mx = fmaxf(mx, v);
  }
  float den = 0.f;
  for (int j=b0;j<b1;j++){
    float e = __expf(alpha[(size_t)j*4+h] - mx);
    alpha[(size_t)j*4+h] = e;
    den += e;
  }
  inv_den[(size_t)n*4+h] = 1.f/(den + 1e-16f);
}

// ---------------- input-space aggregation (bf16 output for MFMA GEMM) ----------------
__global__ void k_agg(const int* __restrict__ ptr, const int* __restrict__ csrc,
                      const float* __restrict__ alpha, const float* __restrict__ inv_den,
                      const float* __restrict__ hin, unsigned short* __restrict__ agg){
  int n = blockIdx.x; int t = threadIdx.x;  // 128 threads
  int b0 = ptr[n], b1 = ptr[n+1];
  float a0=0.f, a1=0.f, a2=0.f, a3=0.f;
  for (int j=b0;j<b1;j++){
    int s = csrc[j];
    float4 al = *(const float4*)&alpha[(size_t)j*4];
    float v = hin[(size_t)s*128 + t];
    a0 += al.x*v; a1 += al.y*v; a2 += al.z*v; a3 += al.w*v;
  }
  float4 idv = *(const float4*)&inv_den[(size_t)n*4];
  unsigned short* o = agg + (size_t)n*512;
  o[t]     = f2bf(0.25f*idv.x*a0);
  o[128+t] = f2bf(0.25f*idv.y*a1);
  o[256+t] = f2bf(0.25f*idv.z*a2);
  o[384+t] = f2bf(0.25f*idv.w*a3);
}

// ---------------- MFMA head-transform GEMM: C[16000,128] = A[16000,512] @ B2^T ----
// 250 blocks x 4 waves; wave = 16 rows, full N=128 (8 col-tiles), K=512 (16 chunks).
// A fragments preloaded to registers; B fragments from L2 (Blay is 128 KB, hot).
__global__ __launch_bounds__(256) void k_gemmb(const unsigned short* __restrict__ A,
                                               const unsigned short* __restrict__ B,
                                               const float* __restrict__ bias,
                                               float* __restrict__ C){
  int tid = threadIdx.x;
  int w = tid>>6, lane = tid&63;
  int m0 = blockIdx.x*64 + w*16;
  int quad = lane>>4;
  int mrow = m0 + (lane&15);
  const sh8* arow = (const sh8*)(A + (size_t)mrow*512 + quad*8);
  sh8 af[16];
  #pragma unroll
  for (int kc=0;kc<16;kc++) af[kc] = arow[kc*4];   // +32 shorts per chunk
  f32x4 acc[8];
  #pragma unroll
  for (int c=0;c<8;c++) acc[c] = (f32x4){0.f,0.f,0.f,0.f};
  const sh8* bp = (const sh8*)B;
  #pragma unroll
  for (int kc=0;kc<16;kc++){
    #pragma unroll
    for (int c=0;c<8;c++){
      sh8 bf = bp[(c*16+kc)*64 + lane];
      acc[c] = __builtin_amdgcn_mfma_f32_16x16x32_bf16(af[kc], bf, acc[c], 0, 0, 0);
    }
  }
  #pragma unroll
  for (int c=0;c<8;c++){
    int d = c*16 + (lane&15);
    float bi = bias[d];
    #pragma unroll
    for (int r=0;r<4;r++){
      int m = m0 + quad*4 + r;
      C[(size_t)m*128 + d] = fmaxf(acc[c][r] + bi, 0.f);
    }
  }
}

// ---------------- SAG score (algebraic: scalar per node) ----------------
__global__ void k_pq(const float* __restrict__ h, const float* __restrict__ wrel,
                     const float* __restrict__ wroot, float* __restrict__ p,
                     float* __restrict__ q){
  int n = blockIdx.x; int lane = threadIdx.x; // 64
  const float* row = h+(size_t)n*128;
  float a = row[lane]*wrel[lane] + row[64+lane]*wrel[64+lane];
  float b = row[lane]*wroot[lane] + row[64+lane]*wroot[64+lane];
  #pragma unroll
  for (int o=32;o>0;o>>=1){ a += __shfl_down(a,o); b += __shfl_down(b,o); }
  if (lane==0){ p[n]=a; q[n]=b; }
}

__global__ void k_sagscore(const int* __restrict__ ptr, const int* __restrict__ csrc,
                           const float* __restrict__ p, const float* __restrict__ q,
                           const float* __restrict__ brel, float* __restrict__ score){
  int n = blockIdx.x*blockDim.x + threadIdx.x;
  if (n >= NN) return;
  int b0=ptr[n], b1=ptr[n+1];
  float s=0.f;
  for (int j=b0;j<b1;j++){ int sj=csrc[j]; if (sj!=n) s+=p[sj]; }
  score[n] = s + q[n] + brel[0];
}

// ---------------- fused single-block radix top-k (register-resident keys) ----------------
__global__ __launch_bounds__(1024) void k_topk(const float* __restrict__ score,
                                               int* __restrict__ sel){
  __shared__ int hist[8*257];     // 8 padded replicas
  __shared__ int hmerge[256];
  __shared__ unsigned sh_prefix;
  __shared__ int sh_rem;
  __shared__ int cntGT, cntEQ;
  __shared__ int ties[256];
  int t = threadIdx.x;
  int lane = t & 63;
  int rep = t >> 7;               // 0..7
  unsigned keys[16];
  #pragma unroll
  for (int j=0;j<16;j++){
    int i = t + j*1024;
    keys[j] = (i<NN) ? fkey(score[i]) : 0u;
  }
  if (t==0){ sh_prefix=0u; sh_rem=NK; cntGT=0; cntEQ=0; }
  __syncthreads();
  for (int p=0;p<4;p++){
    int shift = 24-8*p;
    for (int i=t;i<8*257;i+=1024) hist[i]=0;
    __syncthreads();
    unsigned prefix = sh_prefix;
    #pragma unroll
    for (int j=0;j<16;j++){
      bool val = (j<15) || (t < (NN - 15*1024));
      unsigned u = keys[j];
      bool ok = val && ((p==0) || ((u>>(shift+8)) == (prefix>>(shift+8))));
      int b = (int)((u>>shift)&255u);
      unsigned long long act = __ballot(ok);
      if (act){
        int leader = (int)(__ffsll((long long)act)-1);
        int bl = __shfl(b, leader);
        unsigned long long same = __ballot(ok && b==bl);
        if (same==act){
          if (lane==leader) atomicAdd(&hist[rep*257+bl], (int)__popcll(act));
        } else if (ok){
          atomicAdd(&hist[rep*257+b], 1);
        }
      }
    }
    __syncthreads();
    if (t<256){
      int v=0;
      #pragma unroll
      for (int r=0;r<8;r++) v += hist[r*257+t];
      hmerge[t]=v;
    }
    __syncthreads();
    if (t<64){
      int l = t;
      int b0 = 4*(63-l);
      int c3 = hmerge[b0+3], c2 = hmerge[b0+2], c1 = hmerge[b0+1], c0 = hmerge[b0];
      int gs = c0+c1+c2+c3;
      int incl = gs;
      #pragma unroll
      for (int o=1;o<64;o<<=1){
        int v = __shfl_up(incl, o);
        if (l>=o) incl += v;
      }
      int excl = incl - gs;
      int rem = sh_rem;
      int rl = rem - excl;
      if (rl > 0 && rl <= gs){
        unsigned pre = sh_prefix;
        if (rl > c3){ rl -= c3;
          if (rl > c2){ rl -= c2;
            if (rl > c1){ rl -= c1;
              sh_prefix = pre | ((unsigned)b0<<shift);     sh_rem = rl;
            } else { sh_prefix = pre | ((unsigned)(b0+1)<<shift); sh_rem = rl; }
          } else { sh_prefix = pre | ((unsigned)(b0+2)<<shift);   sh_rem = rl; }
        } else { sh_prefix = pre | ((unsigned)(b0+3)<<shift);     sh_rem = rl; }
      }
    }
    __syncthreads();
  }
  unsigned Tu = sh_prefix;
  #pragma unroll
  for (int j=0;j<16;j++){
    int i = t + j*1024;
    bool val = (i<NN);
    unsigned u = keys[j];
    bool g = val && (u>Tu), e = val && (u==Tu);
    unsigned long long mg = __ballot(g);
    if (mg){
      int leader = (int)(__ffsll((long long)mg)-1);
      int base = 0;
      if (lane==leader) base = atomicAdd(&cntGT, (int)__popcll(mg));
      base = __shfl(base, leader);
      if (g){
        int pos = base + (int)__popcll(mg & ((1ull<<lane)-1ull));
        sel[pos] = i;
      }
    }
    unsigned long long me = __ballot(e);
    if (me){
      int leader = (int)(__ffsll((long long)me)-1);
      int base = 0;
      if (lane==leader) base = atomicAdd(&cntEQ, (int)__popcll(me));
      base = __shfl(base, leader);
      if (e){
        int pos = base + (int)__popcll(me & ((1ull<<lane)-1ull));
        if (pos<256) ties[pos] = i;
      }
    }
  }
  __syncthreads();
  if (t==0){
    int base=cntGT, rem=sh_rem, nt=min(cntEQ,256);
    for (int r=0;r<rem;r++){
      int best=0x7fffffff, bi=-1;
      for (int q2=0;q2<nt;q2++){ int v=ties[q2]; if (v>=0 && v<best){best=v;bi=q2;} }
      sel[base+r] = (bi>=0)? best : 0;
      if (bi>=0) ties[bi]=-1;
    }
  }
}

// ---------------- xp gather + node2k ----------------
__global__ void k_gatherx(const int* __restrict__ sel, const float* __restrict__ score,
                          const float* __restrict__ h, float* __restrict__ xp,
                          int* __restrict__ node2k){
  int k = blockIdx.x; int t = threadIdx.x; // 128
  int n = sel[k];
  if (t==0) node2k[n] = k;
  float g = tanhf(score[n]);
  xp[(size_t)k*128+t] = h[(size_t)n*128+t]*g;
}

// ---------------- DMoN assignment softmax ----------------
__global__ void k_assign(const float* __restrict__ xp, const float* __restrict__ dw,
                         const float* __restrict__ db, float* __restrict__ sA){
  int k = blockIdx.x; int lane = threadIdx.x; // 64
  __shared__ float logits[16];
  float x0 = xp[(size_t)k*128+lane], x1 = xp[(size_t)k*128+64+lane];
  for (int c=0;c<16;c++){
    float p = x0*dw[c*128+lane] + x1*dw[c*128+64+lane];
    #pragma unroll
    for (int off=32;off>0;off>>=1) p += __shfl_down(p,off);
    if (lane==0) logits[c] = p + db[c];
  }
  __syncthreads();
  if (lane<16){
    float mx=-1e30f;
    for (int c=0;c<16;c++) mx = fmaxf(mx, logits[c]);
    float s=0.f;
    for (int c=0;c<16;c++) s += __expf(logits[c]-mx);
    sA[(size_t)k*16+lane] = __expf(logits[lane]-mx)/s;
  }
}

// ---------------- pooled adjacency ----------------
__global__ void k_edgepool(const int* __restrict__ ei, const int* __restrict__ node2k,
                           const float* __restrict__ sA, float* __restrict__ tbuf,
                           float* __restrict__ deg){
  int e = blockIdx.x*blockDim.x + threadIdx.x;
  if (e >= NE) return;
  int ni = node2k[ei[e]];
  int nj = node2k[ei[NE+e]];
  if (ni >= 0 && nj >= 0){
    atomicAdd(&deg[nj], 1.f);
    const float* sr = &sA[(size_t)nj*16];
    float* tr = &tbuf[(size_t)ni*16];
    #pragma unroll
    for (int c=0;c<16;c++) atomicAdd(&tr[c], sr[c]);
  }
}

// ---------------- fused pooled reductions ----------------
constexpr int P_BLOCKS = 32;
constexpr int P_ROWS   = NK / P_BLOCKS;   // 125
constexpr int P_CHUNK  = 25;

__global__ __launch_bounds__(256) void k_pool(const float* __restrict__ sA,
                                              const float* __restrict__ xp,
                                              const float* __restrict__ tb,
                                              const float* __restrict__ deg,
                                              float* __restrict__ acc){
  __shared__ float sv[P_CHUNK*16];
  __shared__ float tv[P_CHUNK*16];
  __shared__ float dv[P_CHUNK];
  __shared__ float xv[P_CHUNK*128];
  int t = threadIdx.x;
  int c = t>>4, d = t&15;
  float loc[8] = {0,0,0,0,0,0,0,0};
  float a_adj=0.f, a_ss=0.f, a_cs=0.f, a_v=0.f, a_dg=0.f;
  int r0 = blockIdx.x*P_ROWS;
  for (int ch=0; ch<P_ROWS; ch+=P_CHUNK){
    int base = r0+ch;
    for (int i=t;i<P_CHUNK*16;i+=256){
      sv[i] = sA[(size_t)(base+(i>>4))*16 + (i&15)];
      tv[i] = tb[(size_t)(base+(i>>4))*16 + (i&15)];
    }
    for (int i=t;i<P_CHUNK*128;i+=256)
      xv[i] = xp[(size_t)(base+(i>>7))*128 + (i&127)];
    if (t<P_CHUNK) dv[t]=deg[base+t];
    __syncthreads();
    for (int r=0;r<P_CHUNK;r++){
      float sc = sv[r*16+c];
      a_adj += sc*tv[r*16+d];
      a_ss  += sc*sv[r*16+d];
      if (d==0){ a_cs += sc; a_v += sc*dv[r]; }
      if (t==0) a_dg += dv[r];
      #pragma unroll
      for (int j=0;j<8;j++){
        int o=t+j*256;
        loc[j] += sv[r*16+(o>>7)]*xv[r*128+(o&127)];
      }
    }
    __syncthreads();
  }
  atomicAdd(&acc[A_ADJ + t], a_adj);
  atomicAdd(&acc[A_SS + t], a_ss);
  if (d==0){ atomicAdd(&acc[A_CSUM+c], a_cs); atomicAdd(&acc[A_V+c], a_v); }
  if (t==0) atomicAdd(&acc[A_DEGSUM], a_dg);
  #pragma unroll
  for (int j=0;j<8;j++) atomicAdd(&acc[A_OUTX + t + j*256], loc[j]);
}

__device__ float block_sum_256(float v, float* red){
  int t = threadIdx.x;
  red[t]=v; __syncthreads();
  #pragma unroll
  for (int o=128;o>0;o>>=1){ if (t<o) red[t]+=red[t+o]; __syncthreads(); }
  float r = red[0]; __syncthreads();
  return r;
}

// ---------------- losses + normalized adjacency + selu(out_x) ----------------
__global__ __launch_bounds__(256) void k_finloss(float* __restrict__ acc, float* __restrict__ dout){
  __shared__ float red[256];
  __shared__ float dsv[16];
  int t = threadIdx.x;
  int c = t>>4, dcol = t&15;
  float m = 0.5f*acc[A_DEGSUM];
  float ssv = acc[A_SS+t];
  float tr    = block_sum_256((t<16)? acc[A_ADJ + t*16 + t] : 0.f, red);
  float sumv2 = block_sum_256((t<16)? acc[A_V+t]*acc[A_V+t] : 0.f, red);
  float ss2   = block_sum_256(ssv*ssv, red);
  float cs2   = block_sum_256((t<16)? acc[A_CSUM+t]*acc[A_CSUM+t] : 0.f, red);
  float ssn = sqrtf(ss2);
  float term = ssv/ssn - ((c==dcol)? 0.25f : 0.f);
  float ortho2 = block_sum_256(term*term, red);
  if (t==0){
    float spectral = -(tr - sumv2/(2.f*m))/(2.f*m);
    float ortho = sqrtf(ortho2);
    float cluster = sqrtf(cs2)/(float)NK*4.f - 1.f;
    dout[1] = spectral + ortho + cluster;
  }
  float z = (c==dcol)? 0.f : acc[A_ADJ+t];
  red[t]=z; __syncthreads();
  for (int o=8;o>0;o>>=1){ if (dcol<o) red[t]+=red[t+o]; __syncthreads(); }
  if (dcol==0) dsv[c]=sqrtf(red[c*16])+1e-15f;
  __syncthreads();
  acc[A_ADJN+t] = z/(dsv[c]*dsv[dcol]);
  #pragma unroll
  for (int j=0;j<8;j++){
    int idx = t + j*256;
    float xv = acc[A_OUTX+idx];
    float s2 = (xv > 0.f)? xv : 1.6732632423543772f*expm1f(xv);
    acc[A_OUTX+idx] = 1.0507009873554805f*s2;
  }
}

// ---------------- hh = selu(out_x) @ Wt^T ----------------
__global__ void k_hh(const float* __restrict__ acc, const float* __restrict__ Wt,
                     float* __restrict__ hh){
  int of = blockIdx.x*256 + threadIdx.x; // 0..8191
  int c = of >> 9, o = of & 511;
  const float* sx = acc + A_OUTX + c*128;
  const float* w = Wt + (size_t)o*128;
  float s=0.f;
  for (int k=0;k<128;k++) s += sx[k]*w[k];
  hh[of] = s;
}

// ---------------- dense GAT head + readout ----------------
__global__ __launch_bounds__(256) void k_head(
    const float* __restrict__ hh_g, const float* __restrict__ acc,
    const float* __restrict__ att_s, const float* __restrict__ att_d,
    const float* __restrict__ bt, const float* __restrict__ gate_w,
    const float* __restrict__ gate_b, const float* __restrict__ trans_w,
    const float* __restrict__ trans_b, const int* __restrict__ task,
    const float* __restrict__ task_emb, const float* __restrict__ task_w,
    const float* __restrict__ task_b, const float* __restrict__ fuse_w,
    const float* __restrict__ fuse_b, const float* __restrict__ out_w,
    const float* __restrict__ out_b, float* __restrict__ dout){
  __shared__ float hh[8192];
  __shared__ float al[1024];
  __shared__ float asrc[64], adst[64];
  __shared__ float dg[2048];
  __shared__ float gate[16];
  __shared__ float gvec[128];
  __shared__ float ro[128], te[128], fu[128];
  __shared__ float red[256];
  int t = threadIdx.x;
  for (int i=t;i<8192;i+=256) hh[i]=hh_g[i];
  __syncthreads();
  if (t<128){
    int j = t>>3; int h = (t>>1)&3; int w = t&1;
    const float* hr = &hh[j*512 + h*128];
    const float* a = (w? att_d : att_s) + h*128;
    float s=0.f;
    for (int k2=0;k2<128;k2++) s += hr[k2]*a[k2];
    if (w) adst[j*4+h]=s; else asrc[j*4+h]=s;
  }
  __syncthreads();
  for (int idx=t; idx<1024; idx+=256){
    int h = idx&3, j=(idx>>2)&15, i=idx>>6;
    float v = asrc[j*4+h] + adst[i*4+h];
    v = v>0.f? v : 0.2f*v;
    float adjl = (i==j)? 1.f : acc[A_ADJN + i*16+j];
    al[idx] = (adjl==0.f)? -1e30f : v;
  }
  __syncthreads();
  if (t<64){
    int i=t>>2, h=t&3;
    float mx=-1e30f;
    for (int j=0;j<16;j++) mx = fmaxf(mx, al[(i*16+j)*4+h]);
    float sum=0.f;
    for (int j=0;j<16;j++){ float e=__expf(al[(i*16+j)*4+h]-mx); al[(i*16+j)*4+h]=e; sum+=e; }
    float inv = 1.f/sum;
    for (int j=0;j<16;j++) al[(i*16+j)*4+h]*=inv;
  }
  __syncthreads();
  for (int idx=t; idx<2048; idx+=256){
    int i=idx>>7, d=idx&127;
    float s=0.f;
    for (int h=0;h<4;h++)
      for (int j=0;j<16;j++)
        s += al[(i*16+j)*4+h]*hh[j*512+h*128+d];
    dg[idx] = fmaxf(0.25f*s + bt[d], 0.f);
  }
  __syncthreads();
  if (t<16){
    float s=0.f;
    for (int d2=0;d2<128;d2++) s += dg[t*128+d2]*gate_w[d2];
    red[t] = s + gate_b[0];
  }
  __syncthreads();
  if (t<16){
    float mx=-1e30f; for (int i=0;i<16;i++) mx=fmaxf(mx,red[i]);
    float s=0.f; for (int i=0;i<16;i++) s+=__expf(red[i]-mx);
    gate[t]=__expf(red[t]-mx)/s;
  }
  __syncthreads();
  if (t<128){
    float s=0.f;
    for (int i=0;i<16;i++) s += gate[i]*dg[i*128+t];
    gvec[t]=s;
  }
  __syncthreads();
  if (t<128){
    float s=0.f;
    for (int k2=0;k2<128;k2++) s += gvec[k2]*trans_w[t*128+k2];
    ro[t]=s+trans_b[t];
    int tk = task[0];
    float s2=0.f;
    for (int k2=0;k2<128;k2++) s2 += task_emb[(size_t)tk*128+k2]*task_w[t*128+k2];
    te[t]=fmaxf(s2+task_b[t],0.f);
  }
  __syncthreads();
  if (t<128){
    float s=0.f;
    for (int k2=0;k2<128;k2++) s += ro[k2]*fuse_w[t*256+k2] + te[k2]*fuse_w[t*256+128+k2];
    fu[t]=fmaxf(s+fuse_b[t],0.f);
  }
  __syncthreads();
  float v = (t<128)? fu[t]*out_w[t] : 0.f;
  red[t]=v; __syncthreads();
  for (int o=128;o>0;o>>=1){ if (t<o) red[t]+=red[t+o]; __syncthreads(); }
  if (t==0) dout[0]=red[0]+out_b[0];
}

// ================= launcher =================
extern "C" void kernel_launch(void* const* d_in, const int* in_sizes, int n_in,
                              void* d_out, int out_size, void* d_ws, size_t ws_size,
                              hipStream_t stream){
  const int* x        = (const int*)d_in[0];
  const int* ei       = (const int*)d_in[1];
  const int* task     = (const int*)d_in[3];
  const float* node_emb = (const float*)d_in[4];
  const float* task_emb = (const float*)d_in[5];
  const float* W[3]  = {(const float*)d_in[6],  (const float*)d_in[10], (const float*)d_in[14]};
  const float* As_[3]= {(const float*)d_in[7],  (const float*)d_in[11], (const float*)d_in[15]};
  const float* Ad_[3]= {(const float*)d_in[8],  (const float*)d_in[12], (const float*)d_in[16]};
  const float* Bb[3] = {(const float*)d_in[9],  (const float*)d_in[13], (const float*)d_in[17]};
  const float* wrel  = (const float*)d_in[18];
  const float* brel  = (const float*)d_in[19];
  const float* wroot = (const float*)d_in[20];
  const float* dmon_w= (const float*)d_in[21];
  const float* dmon_b= (const float*)d_in[22];
  const float* Wt    = (const float*)d_in[23];
  const float* att_s = (const float*)d_in[24];
  const float* att_d = (const float*)d_in[25];
  const float* btb   = (const float*)d_in[26];
  const float* gate_w= (const float*)d_in[27];
  const float* gate_b= (const float*)d_in[28];
  const float* trans_w=(const float*)d_in[29];
  const float* trans_b=(const float*)d_in[30];
  const float* task_w= (const float*)d_in[31];
  const float* task_b= (const float*)d_in[32];
  const float* fuse_w= (const float*)d_in[33];
  const float* fuse_b= (const float*)d_in[34];
  const float* out_w = (const float*)d_in[35];
  const float* out_b = (const float*)d_in[36];
  float* dout = (float*)d_out;
  (void)in_sizes; (void)n_in; (void)out_size; (void)ws_size;

  char* base = (char*)d_ws;
  size_t off = 0;
  auto alloc = [&](size_t bytes)->char*{
    off = (off + 255) & ~(size_t)255;
    char* r = base + off; off += bytes; return r;
  };
  int* csr_ptr  = (int*)alloc((size_t)(NN+1)*4);
  int* csr_fill = (int*)alloc((size_t)NN*4);
  int* csr_src  = (int*)alloc((size_t)NET*4);
  int* sel      = (int*)alloc((size_t)NK*4);
  int* node2k   = (int*)alloc((size_t)NN*4);
  float* score  = (float*)alloc((size_t)NN*4);
  float* pbuf   = (float*)alloc((size_t)NN*4);
  float* qbuf   = (float*)alloc((size_t)NN*4);
  float* h_a    = (float*)alloc((size_t)NN*128*4);
  float* h_b    = (float*)alloc((size_t)NN*128*4);
  unsigned short* aggb = (unsigned short*)alloc((size_t)NN*512*2);
  unsigned short* blay = (unsigned short*)alloc((size_t)8192*8*2);
  float* usd    = (float*)alloc((size_t)1024*4);
  float* sum_s  = (float*)alloc((size_t)NN*4*4);
  float* sum_d  = (float*)alloc((size_t)NN*4*4);
  float* inv_den= (float*)alloc((size_t)NN*4*4);
  float* alpha  = (float*)alloc((size_t)NET*4*4);
  float* xp     = (float*)alloc((size_t)NK*128*4);
  float* sA     = (float*)alloc((size_t)NK*16*4);
  float* tbuf   = (float*)alloc((size_t)NK*16*4);
  float* deg    = (float*)alloc((size_t)NK*4);
  float* acc    = (float*)alloc((size_t)ACC_FLOATS*4);
  float* hh_g   = (float*)alloc((size_t)8192*4);

  k_init<<<256, 256, 0, stream>>>(csr_fill, node2k, tbuf, deg, acc);
  k_count<<<(NET+255)/256, 256, 0, stream>>>(ei, csr_fill);
  k_scan<<<1, 1024, 0, stream>>>(csr_fill, csr_ptr, csr_fill);
  k_fill<<<(NET+255)/256, 256, 0, stream>>>(ei, csr_fill, csr_src);
  k_embed<<<(NN*32+255)/256, 256, 0, stream>>>(x, node_emb, (float4*)h_a);

  float* hin = h_a; float* hout = h_b;
  for (int l=0;l<3;l++){
    k_prep<<<1, 512, 0, stream>>>(W[l], As_[l], Ad_[l], usd);
    k_prepw<<<32, 256, 0, stream>>>(W[l], blay);
    k_attnsum<<<NN, 64, 0, stream>>>(hin, usd, sum_s, sum_d);
    k_edges<<<(NN*NH+255)/256, 256, 0, stream>>>(csr_ptr, csr_src, sum_s, sum_d, alpha, inv_den);
    k_agg<<<NN, 128, 0, stream>>>(csr_ptr, csr_src, alpha, inv_den, hin, aggb);
    k_gemmb<<<NN/64, 256, 0, stream>>>(aggb, blay, Bb[l], hout);
    float* tmp=hin; hin=hout; hout=tmp;
  }
  // hin = final node features
  k_pq<<<NN, 64, 0, stream>>>(hin, wrel, wroot, pbuf, qbuf);
  k_sagscore<<<(NN+255)/256, 256, 0, stream>>>(csr_ptr, csr_src, pbuf, qbuf, brel, score);
  k_topk<<<1, 1024, 0, stream>>>(score, sel);
  k_gatherx<<<NK, 128, 0, stream>>>(sel, score, hin, xp, node2k);
  k_assign<<<NK, 64, 0, stream>>>(xp, dmon_w, dmon_b, sA);
  k_edgepool<<<(NE+255)/256, 256, 0, stream>>>(ei, node2k, sA, tbuf, deg);
  k_pool<<<P_BLOCKS, 256, 0, stream>>>(sA, xp, tbuf, deg, acc);
  k_finloss<<<1, 256, 0, stream>>>(acc, dout);
  k_hh<<<32, 256, 0, stream>>>(acc, Wt, hh_g);
  k_head<<<1, 256, 0, stream>>>(hh_g, acc, att_s, att_d, btb, gate_w, gate_b,
                                trans_w, trans_b, task, task_emb, task_w, task_b,
                                fuse_w, fuse_b, out_w, out_b, dout);
}